// Round 1
// baseline (319.506 us; speedup 1.0000x reference)
//
#include <hip/hip_runtime.h>
#include <stdint.h>

typedef unsigned short u16;
typedef short s16x8 __attribute__((ext_vector_type(8)));
typedef float f32x4 __attribute__((ext_vector_type(4)));

#define BM 128
#define BN 128
#define BK 32
#define KPAD 40   // padded LDS row stride for the legacy (non-async) kernel

__device__ __forceinline__ float bf2f(u16 b) {
    union { unsigned int u; float f; } v; v.u = ((unsigned int)b) << 16; return v.f;
}
__device__ __forceinline__ u16 f2bf(float f) {
    union { float f; unsigned int u; } v; v.f = f;
    unsigned int u = v.u;
    u += 0x7fffu + ((u >> 16) & 1u);   // RNE
    return (u16)(u >> 16);
}
__device__ __forceinline__ void async_cp16(const u16* g, u16* l) {
    // global -> LDS direct copy, 16 B per lane; LDS dest = wave-uniform base + lane*16
    __builtin_amdgcn_global_load_lds((const __attribute__((address_space(1))) void*)g,
                                     (__attribute__((address_space(3))) void*)l, 16, 0, 0);
}

// ---------------- GroupNorm statistics: one block per (b,g), fp32 input ----------------
__global__ __launch_bounds__(256) void gn_stats(const float* __restrict__ x,
                                                float* __restrict__ mean,
                                                float* __restrict__ rstd) {
    const int bg = blockIdx.x;
    const float* p = x + (long)bg * 16 * 2048;     // 32768 fp32 per group
    float s = 0.f, ss = 0.f;
    for (int it = 0; it < 32; it++) {
        const float4 v = *reinterpret_cast<const float4*>(p + ((it * 256 + threadIdx.x) << 2));
        s += v.x + v.y + v.z + v.w;
        ss += v.x * v.x + v.y * v.y + v.z * v.z + v.w * v.w;
    }
    const int lane = threadIdx.x & 63, wave = threadIdx.x >> 6;
#pragma unroll
    for (int o = 32; o > 0; o >>= 1) { s += __shfl_down(s, o, 64); ss += __shfl_down(ss, o, 64); }
    __shared__ float rb[8];
    if (lane == 0) { rb[wave] = s; rb[4 + wave] = ss; }
    __syncthreads();
    if (threadIdx.x == 0) {
        float S = rb[0] + rb[1] + rb[2] + rb[3];
        float SS = rb[4] + rb[5] + rb[6] + rb[7];
        float mu = S * (1.f / 32768.f);
        float var = SS * (1.f / 32768.f) - mu * mu;
        mean[bg] = mu;
        rstd[bg] = rsqrtf(var + 1e-6f);
    }
}

// ---------- GroupNorm apply + transpose: fp32 x -> bf16 hnT[h, c] ----------
__global__ __launch_bounds__(256) void gn_apply_t(const float* __restrict__ x,
                                                  const float* __restrict__ gamma,
                                                  const float* __restrict__ beta,
                                                  const float* __restrict__ mean,
                                                  const float* __restrict__ rstd,
                                                  u16* __restrict__ hnT) {
    const int b = blockIdx.z, c0 = blockIdx.y * 64, h0 = blockIdx.x * 64;
    __shared__ __align__(16) u16 T[64][72];
    const int tid = threadIdx.x;
#pragma unroll
    for (int sidx = 0; sidx < 4; sidx++) {
        int ch = tid + sidx * 256;                 // 1024 float4-chunks
        int cc = ch >> 4, h4 = (ch & 15) * 4;
        int c = c0 + cc;
        float mu = mean[b * 32 + (c >> 4)], rs = rstd[b * 32 + (c >> 4)];
        float ga = gamma[c], be = beta[c];
        const float4 v = *reinterpret_cast<const float4*>(x + ((long)b * 512 + c) * 2048 + h0 + h4);
        ushort4 pk;
        pk.x = f2bf((v.x - mu) * rs * ga + be);
        pk.y = f2bf((v.y - mu) * rs * ga + be);
        pk.z = f2bf((v.z - mu) * rs * ga + be);
        pk.w = f2bf((v.w - mu) * rs * ga + be);
        *reinterpret_cast<ushort4*>(&T[cc][h4]) = pk;
    }
    __syncthreads();
#pragma unroll
    for (int sidx = 0; sidx < 2; sidx++) {
        int ch = tid + sidx * 256;                 // 512 uint4-chunks
        int hh = ch >> 3, c8 = (ch & 7) * 8;
        unsigned int o[4];
#pragma unroll
        for (int i = 0; i < 4; i++) {
            u16 lo = T[c8 + 2 * i][hh];
            u16 hi = T[c8 + 2 * i + 1][hh];
            o[i] = (unsigned int)lo | ((unsigned int)hi << 16);
        }
        *reinterpret_cast<uint4*>(hnT + ((long)b * 2048 + h0 + hh) * 512 + c0 + c8) =
            uint4{o[0], o[1], o[2], o[3]};
    }
}

// ---------------- fp32 -> bf16 weight conversion (512x512 each, y selects src) ----------------
__global__ __launch_bounds__(256) void w2bf(const float* __restrict__ a,
                                            const float* __restrict__ b,
                                            const float* __restrict__ c,
                                            u16* __restrict__ dst) {
    const float* s = (blockIdx.y == 0) ? a : (blockIdx.y == 1) ? b : c;
    const int i = (blockIdx.x * 256 + threadIdx.x) * 4;
    const float4 v = *reinterpret_cast<const float4*>(s + i);
    ushort4 p;
    p.x = f2bf(v.x); p.y = f2bf(v.y); p.z = f2bf(v.z); p.w = f2bf(v.w);
    *reinterpret_cast<ushort4*>(dst + (long)blockIdx.y * 262144 + i) = p;
}

// ------------------ softmax over rows of S[i, :] (bf16) in place ------------------
__global__ __launch_bounds__(256) void softmax_rows(u16* __restrict__ S) {
    u16* p = S + (long)blockIdx.x * 2048;
    const int tid = threadIdx.x;
    uint4 v = *reinterpret_cast<const uint4*>(p + (tid << 3));
    unsigned int w[4] = {v.x, v.y, v.z, v.w};
    float f[8];
#pragma unroll
    for (int i = 0; i < 4; i++) {
        f[2 * i]     = bf2f((u16)(w[i] & 0xffffu));
        f[2 * i + 1] = bf2f((u16)(w[i] >> 16));
    }
    float m = f[0];
#pragma unroll
    for (int i = 1; i < 8; i++) m = fmaxf(m, f[i]);
    const int lane = tid & 63, wave = tid >> 6;
#pragma unroll
    for (int o = 32; o > 0; o >>= 1) m = fmaxf(m, __shfl_down(m, o, 64));
    __shared__ float rb[4];
    __shared__ float bc;
    if (lane == 0) rb[wave] = m;
    __syncthreads();
    if (tid == 0) bc = fmaxf(fmaxf(rb[0], rb[1]), fmaxf(rb[2], rb[3]));
    __syncthreads();
    m = bc;
    float s = 0.f;
#pragma unroll
    for (int i = 0; i < 8; i++) { f[i] = __expf(f[i] - m); s += f[i]; }
#pragma unroll
    for (int o = 32; o > 0; o >>= 1) s += __shfl_down(s, o, 64);
    __syncthreads();
    if (lane == 0) rb[wave] = s;
    __syncthreads();
    if (tid == 0) bc = 1.f / (rb[0] + rb[1] + rb[2] + rb[3]);
    __syncthreads();
    const float inv = bc;
#pragma unroll
    for (int i = 0; i < 4; i++)
        w[i] = (unsigned int)f2bf(f[2 * i] * inv) | ((unsigned int)f2bf(f[2 * i + 1] * inv) << 16);
    *reinterpret_cast<uint4*>(p + (tid << 3)) = uint4{w[0], w[1], w[2], w[3]};
}

// ===================== ASYNC double-buffered MFMA GEMM (bf16 operands) =====================
// SWIZ 0: normal 2D grid (x = n-tile, y = m-tile).
// SWIZ 1: 1D grid of 64 (4 n x 16 m); the 4 n-tiles sharing an A-strip get the same
//         bx%8 (same XCD) in consecutive slots -> A-strip fetched once per XCD.
// SWIZ 2: 1D grid of 256 (16 n x 16 m); each XCD owns a 4m x 8n quadrant.
template <int EPI, int SWIZ>
__global__ __launch_bounds__(256) void gemm_tn_a(const u16* __restrict__ Ag, long sA,
                                                 const u16* __restrict__ Bg, long sB,
                                                 const float* __restrict__ bias,
                                                 const float* __restrict__ Xg, long sX,
                                                 void* __restrict__ Ogv, long sO,
                                                 int K, int lda, int ldb, int ldo,
                                                 float scale) {
    const int b = blockIdx.z;
    Ag += (long)b * sA;
    Bg += (long)b * sB;
    int tx, ty;
    if (SWIZ == 1) {
        const int xcd = blockIdx.x & 7, s = blockIdx.x >> 3;
        ty = xcd + 8 * (s >> 2);
        tx = s & 3;
    } else if (SWIZ == 2) {
        const int xcd = blockIdx.x & 7, s = blockIdx.x >> 3;
        ty = (xcd & 3) * 4 + (s & 3);
        tx = (xcd >> 2) * 8 + (s >> 2);
    } else {
        tx = blockIdx.x; ty = blockIdx.y;
    }
    const int m0 = ty * BM;
    const int n0 = tx * BN;

    __shared__ __align__(16) u16 As[2][BM * BK];
    __shared__ __align__(16) u16 Bs[2][BN * BK];

    const int tid = threadIdx.x;
    const int wave = tid >> 6;
    const int lane = tid & 63;
    const int quad = lane >> 4;
    const int l16 = lane & 15;
    const int wm = (wave >> 1) * 64;
    const int wn = (wave & 1) * 64;
    const int rl = lane >> 2;
    const int cl = (lane & 3) * 8;

    f32x4 acc[4][4];
#pragma unroll
    for (int i = 0; i < 4; i++)
#pragma unroll
        for (int j = 0; j < 4; j++) acc[i][j] = f32x4{0.f, 0.f, 0.f, 0.f};

    auto stage = [&](int buf, int k0) {
#pragma unroll
        for (int j = 0; j < 2; j++) {
            const int rbase = wave * 32 + j * 16;
            async_cp16(Ag + (long)(m0 + rbase + rl) * lda + k0 + cl, &As[buf][rbase * BK]);
            async_cp16(Bg + (long)(n0 + rbase + rl) * ldb + k0 + cl, &Bs[buf][rbase * BK]);
        }
    };
    auto compute = [&](int buf) {
        s16x8 af[4], bfr[4];
#pragma unroll
        for (int i = 0; i < 4; i++)
            af[i] = *reinterpret_cast<const s16x8*>(&As[buf][(wm + i * 16 + l16) * BK + quad * 8]);
#pragma unroll
        for (int j = 0; j < 4; j++)
            bfr[j] = *reinterpret_cast<const s16x8*>(&Bs[buf][(wn + j * 16 + l16) * BK + quad * 8]);
#pragma unroll
        for (int i = 0; i < 4; i++)
#pragma unroll
            for (int j = 0; j < 4; j++)
                acc[i][j] = __builtin_amdgcn_mfma_f32_16x16x32_bf16(af[i], bfr[j], acc[i][j], 0, 0, 0);
    };

    stage(0, 0);
    for (int k0 = 0; k0 < K; k0 += 2 * BK) {
        __syncthreads();
        stage(1, k0 + BK);
        compute(0);
        __syncthreads();
        if (k0 + 2 * BK < K) stage(0, k0 + 2 * BK);
        compute(1);
    }

#pragma unroll
    for (int i = 0; i < 4; i++) {
        const int mb = m0 + wm + i * 16 + quad * 4;
#pragma unroll
        for (int j = 0; j < 4; j++) {
            const int n = n0 + wn + j * 16 + l16;
            if (EPI == 0) {
                u16* O = (u16*)Ogv + (long)b * sO;
#pragma unroll
                for (int r = 0; r < 4; r++) {
                    float vv = acc[i][j][r] * scale;
                    if (bias) vv += bias[mb + r];
                    O[(long)(mb + r) * ldo + n] = f2bf(vv);
                }
            } else if (EPI == 1) {
                u16* O = (u16*)Ogv + (long)b * sO;
                ushort4 pk;
                pk.x = f2bf(acc[i][j][0] + bias[mb + 0]);
                pk.y = f2bf(acc[i][j][1] + bias[mb + 1]);
                pk.z = f2bf(acc[i][j][2] + bias[mb + 2]);
                pk.w = f2bf(acc[i][j][3] + bias[mb + 3]);
                *reinterpret_cast<ushort4*>(&O[(long)n * ldo + mb]) = pk;
            } else {
                float* O = (float*)Ogv + (long)b * sO;
                const float* X = Xg + (long)b * sX;
                const float bn = bias[n];
                const float4 xv = *reinterpret_cast<const float4*>(&X[(long)n * ldo + mb]);
                float4 pk;
                pk.x = acc[i][j][0] + bn + xv.x;
                pk.y = acc[i][j][1] + bn + xv.y;
                pk.z = acc[i][j][2] + bn + xv.z;
                pk.w = acc[i][j][3] + bn + xv.w;
                *reinterpret_cast<float4*>(&O[(long)n * ldo + mb]) = pk;
            }
        }
    }
}

// ===================== BN=64 async GEMM: 4 blocks/CU for narrow-N shapes =====================
// Occupancy fix for the PV (M=2048,N=512,K=2048) and proj (M=2048,N=512,K=512) GEMMs:
// BN=128 gave only 512 blocks = 2 blocks/CU = 8 waves/CU, so the 2-phase vmcnt(0)+barrier
// drain was unhidden (MfmaUtil 20%). BN=64 -> 1024 blocks = 4/CU = 16 waves/CU.
// Grid: dim3(128,1,B). Swizzle: my = (bx&7)+8*(bx>>6), nx = (bx>>3)&7 so the 8 n-tiles
// sharing one A-strip (S rows, 512 KB) land on the same XCD consecutively.
template <int EPI>
__global__ __launch_bounds__(256) void gemm_tn_a64(const u16* __restrict__ Ag, long sA,
                                                   const u16* __restrict__ Bg, long sB,
                                                   const float* __restrict__ bias,
                                                   const float* __restrict__ Xg, long sX,
                                                   void* __restrict__ Ogv, long sO,
                                                   int K, int lda, int ldb, int ldo,
                                                   float scale) {
    const int b = blockIdx.z;
    Ag += (long)b * sA;
    Bg += (long)b * sB;
    const int bx = blockIdx.x;
    const int ty = (bx & 7) + 8 * (bx >> 6);   // m-tile [0,16)
    const int tx = (bx >> 3) & 7;              // n-tile [0,8)
    const int m0 = ty * BM;
    const int n0 = tx * 64;

    __shared__ __align__(16) u16 As[2][BM * BK];
    __shared__ __align__(16) u16 Bs[2][64 * BK];

    const int tid = threadIdx.x;
    const int wave = tid >> 6;
    const int lane = tid & 63;
    const int quad = lane >> 4;
    const int l16 = lane & 15;
    const int wm = (wave >> 1) * 64;           // 2 m-halves
    const int wn = (wave & 1) * 32;            // 2 n-halves of 32
    const int rl = lane >> 2;
    const int cl = (lane & 3) * 8;

    f32x4 acc[4][2];
#pragma unroll
    for (int i = 0; i < 4; i++)
#pragma unroll
        for (int j = 0; j < 2; j++) acc[i][j] = f32x4{0.f, 0.f, 0.f, 0.f};

    auto stage = [&](int buf, int k0) {
#pragma unroll
        for (int j = 0; j < 2; j++) {
            const int rbase = wave * 32 + j * 16;
            async_cp16(Ag + (long)(m0 + rbase + rl) * lda + k0 + cl, &As[buf][rbase * BK]);
        }
        const int rb2 = wave * 16;
        async_cp16(Bg + (long)(n0 + rb2 + rl) * ldb + k0 + cl, &Bs[buf][rb2 * BK]);
    };
    auto compute = [&](int buf) {
        s16x8 af[4], bfr[2];
#pragma unroll
        for (int i = 0; i < 4; i++)
            af[i] = *reinterpret_cast<const s16x8*>(&As[buf][(wm + i * 16 + l16) * BK + quad * 8]);
#pragma unroll
        for (int j = 0; j < 2; j++)
            bfr[j] = *reinterpret_cast<const s16x8*>(&Bs[buf][(wn + j * 16 + l16) * BK + quad * 8]);
#pragma unroll
        for (int i = 0; i < 4; i++)
#pragma unroll
            for (int j = 0; j < 2; j++)
                acc[i][j] = __builtin_amdgcn_mfma_f32_16x16x32_bf16(af[i], bfr[j], acc[i][j], 0, 0, 0);
    };

    stage(0, 0);
    for (int k0 = 0; k0 < K; k0 += 2 * BK) {
        __syncthreads();
        stage(1, k0 + BK);
        compute(0);
        __syncthreads();
        if (k0 + 2 * BK < K) stage(0, k0 + 2 * BK);
        compute(1);
    }

#pragma unroll
    for (int i = 0; i < 4; i++) {
        const int mb = m0 + wm + i * 16 + quad * 4;
#pragma unroll
        for (int j = 0; j < 2; j++) {
            const int n = n0 + wn + j * 16 + l16;
            if (EPI == 0) {
                u16* O = (u16*)Ogv + (long)b * sO;
#pragma unroll
                for (int r = 0; r < 4; r++) {
                    float vv = acc[i][j][r] * scale;
                    if (bias) vv += bias[mb + r];
                    O[(long)(mb + r) * ldo + n] = f2bf(vv);
                }
            } else {
                float* O = (float*)Ogv + (long)b * sO;
                const float* X = Xg + (long)b * sX;
                const float bn = bias[n];
                const float4 xv = *reinterpret_cast<const float4*>(&X[(long)n * ldo + mb]);
                float4 pk;
                pk.x = acc[i][j][0] + bn + xv.x;
                pk.y = acc[i][j][1] + bn + xv.y;
                pk.z = acc[i][j][2] + bn + xv.z;
                pk.w = acc[i][j][3] + bn + xv.w;
                *reinterpret_cast<float4*>(&O[(long)n * ldo + mb]) = pk;
            }
        }
    }
}

// ===================== merged QKV GEMM, XCD-swizzled: grid (192,1,8) =====================
// 12 blocks sharing an hnT strip (4 m-tiles x 3 outputs) co-locate on one XCD.
__global__ __launch_bounds__(256) void qkv_a(const u16* __restrict__ wb3,
                                             const u16* __restrict__ hnT,
                                             const float* __restrict__ bq,
                                             const float* __restrict__ bk,
                                             const float* __restrict__ bv,
                                             u16* __restrict__ qT, u16* __restrict__ kT,
                                             u16* __restrict__ vv) {
    const long HC = 1048576;
    const int b = blockIdx.z;
    const int xcd = blockIdx.x & 7, s = blockIdx.x >> 3;   // s in [0,24)
    const int hi = (s >= 12) ? 1 : 0;
    const int yy = s - hi * 12;                            // [0,12)
    const int x = xcd + 8 * hi;                            // n-tile [0,16)
    const int which = yy >> 2;                             // 0=q 1=k 2=v
    const int my = yy & 3;                                 // m-tile [0,4)
    const u16* Ag = wb3 + which * 262144;
    const u16* Bg = hnT + (long)b * HC;
    const int m0 = my * BM;
    const int n0 = x * BN;

    __shared__ __align__(16) u16 As[2][BM * BK];
    __shared__ __align__(16) u16 Bs[2][BN * BK];

    const int tid = threadIdx.x;
    const int wave = tid >> 6;
    const int lane = tid & 63;
    const int quad = lane >> 4;
    const int l16 = lane & 15;
    const int wm = (wave >> 1) * 64;
    const int wn = (wave & 1) * 64;
    const int rl = lane >> 2;
    const int cl = (lane & 3) * 8;

    f32x4 acc[4][4];
#pragma unroll
    for (int i = 0; i < 4; i++)
#pragma unroll
        for (int j = 0; j < 4; j++) acc[i][j] = f32x4{0.f, 0.f, 0.f, 0.f};

    auto stage = [&](int buf, int k0) {
#pragma unroll
        for (int j = 0; j < 2; j++) {
            const int rbase = wave * 32 + j * 16;
            async_cp16(Ag + (long)(m0 + rbase + rl) * 512 + k0 + cl, &As[buf][rbase * BK]);
            async_cp16(Bg + (long)(n0 + rbase + rl) * 512 + k0 + cl, &Bs[buf][rbase * BK]);
        }
    };
    auto compute = [&](int buf) {
        s16x8 af[4], bfr[4];
#pragma unroll
        for (int i = 0; i < 4; i++)
            af[i] = *reinterpret_cast<const s16x8*>(&As[buf][(wm + i * 16 + l16) * BK + quad * 8]);
#pragma unroll
        for (int j = 0; j < 4; j++)
            bfr[j] = *reinterpret_cast<const s16x8*>(&Bs[buf][(wn + j * 16 + l16) * BK + quad * 8]);
#pragma unroll
        for (int i = 0; i < 4; i++)
#pragma unroll
            for (int j = 0; j < 4; j++)
                acc[i][j] = __builtin_amdgcn_mfma_f32_16x16x32_bf16(af[i], bfr[j], acc[i][j], 0, 0, 0);
    };

    stage(0, 0);
    for (int k0 = 0; k0 < 512; k0 += 2 * BK) {
        __syncthreads();
        stage(1, k0 + BK);
        compute(0);
        __syncthreads();
        if (k0 + 2 * BK < 512) stage(0, k0 + 2 * BK);
        compute(1);
    }

    if (which == 2) {
        u16* O = vv + (long)b * HC;
#pragma unroll
        for (int i = 0; i < 4; i++) {
            const int mb = m0 + wm + i * 16 + quad * 4;
#pragma unroll
            for (int j = 0; j < 4; j++) {
                const int n = n0 + wn + j * 16 + l16;
#pragma unroll
                for (int r = 0; r < 4; r++)
                    O[(long)(mb + r) * 2048 + n] = f2bf(acc[i][j][r] + bv[mb + r]);
            }
        }
    } else {
        const float* bias = which ? bk : bq;
        u16* O = (which ? kT : qT) + (long)b * HC;
#pragma unroll
        for (int i = 0; i < 4; i++) {
            const int mb = m0 + wm + i * 16 + quad * 4;
#pragma unroll
            for (int j = 0; j < 4; j++) {
                const int n = n0 + wn + j * 16 + l16;
                ushort4 pk;
                pk.x = f2bf(acc[i][j][0] + bias[mb + 0]);
                pk.y = f2bf(acc[i][j][1] + bias[mb + 1]);
                pk.z = f2bf(acc[i][j][2] + bias[mb + 2]);
                pk.w = f2bf(acc[i][j][3] + bias[mb + 3]);
                *reinterpret_cast<ushort4*>(&O[(long)n * 512 + mb]) = pk;
            }
        }
    }
}

// ===================== legacy padded GEMM (fallback tiers, fp32-capable) =====================
template <int F32>
__device__ __forceinline__ void stage_tile(const char* G, int ld, int r0, int k0,
                                           u16* __restrict__ lds, int tid) {
    if (F32) {
        const float* g = (const float*)G;
#pragma unroll
        for (int s = 0; s < 4; s++) {
            const int c = tid + s * 256;
            const int row = c >> 3, col = (c & 7) * 4;
            const float4 v = *reinterpret_cast<const float4*>(g + (long)(r0 + row) * ld + k0 + col);
            ushort4 pk;
            pk.x = f2bf(v.x); pk.y = f2bf(v.y); pk.z = f2bf(v.z); pk.w = f2bf(v.w);
            *reinterpret_cast<ushort4*>(&lds[row * KPAD + col]) = pk;
        }
    } else {
        const u16* g = (const u16*)G;
#pragma unroll
        for (int s = 0; s < 2; s++) {
            const int c = tid + s * 256;
            const int row = c >> 2, col = (c & 3) * 8;
            const uint4 v = *reinterpret_cast<const uint4*>(g + (long)(r0 + row) * ld + k0 + col);
            *reinterpret_cast<uint4*>(&lds[row * KPAD + col]) = v;
        }
    }
}

template <int EPI, int AF32, int BF32>
__global__ __launch_bounds__(256) void gemm_tn(const void* __restrict__ Agv, long sA,
                                               const void* __restrict__ Bgv, long sB,
                                               const float* __restrict__ bias,
                                               const float* __restrict__ Xg, long sX,
                                               void* __restrict__ Ogv, long sO,
                                               int K, int lda, int ldb, int ldo,
                                               float scale) {
    const int b = blockIdx.z;
    const char* A8 = (const char*)Agv + (long)b * sA * (AF32 ? 4 : 2);
    const char* B8 = (const char*)Bgv + (long)b * sB * (BF32 ? 4 : 2);
    const int m0 = blockIdx.y * BM;
    const int n0 = blockIdx.x * BN;

    __shared__ __align__(16) u16 As[BM * KPAD];
    __shared__ __align__(16) u16 Bs[BN * KPAD];

    const int tid = threadIdx.x;
    const int wave = tid >> 6;
    const int lane = tid & 63;
    const int quad = lane >> 4;
    const int l16 = lane & 15;
    const int wm = (wave >> 1) * 64;
    const int wn = (wave & 1) * 64;

    f32x4 acc[4][4];
#pragma unroll
    for (int i = 0; i < 4; i++)
#pragma unroll
        for (int j = 0; j < 4; j++) acc[i][j] = f32x4{0.f, 0.f, 0.f, 0.f};

    for (int k0 = 0; k0 < K; k0 += BK) {
        __syncthreads();
        stage_tile<AF32>(A8, lda, m0, k0, As, tid);
        stage_tile<BF32>(B8, ldb, n0, k0, Bs, tid);
        __syncthreads();
        s16x8 af[4], bfr[4];
#pragma unroll
        for (int i = 0; i < 4; i++)
            af[i] = *reinterpret_cast<const s16x8*>(&As[(wm + i * 16 + l16) * KPAD + quad * 8]);
#pragma unroll
        for (int j = 0; j < 4; j++)
            bfr[j] = *reinterpret_cast<const s16x8*>(&Bs[(wn + j * 16 + l16) * KPAD + quad * 8]);
#pragma unroll
        for (int i = 0; i < 4; i++)
#pragma unroll
            for (int j = 0; j < 4; j++)
                acc[i][j] = __builtin_amdgcn_mfma_f32_16x16x32_bf16(af[i], bfr[j], acc[i][j], 0, 0, 0);
    }

#pragma unroll
    for (int i = 0; i < 4; i++) {
        const int mb = m0 + wm + i * 16 + quad * 4;
#pragma unroll
        for (int j = 0; j < 4; j++) {
            const int n = n0 + wn + j * 16 + l16;
            if (EPI == 0) {
                u16* O = (u16*)Ogv + (long)b * sO;
#pragma unroll
                for (int r = 0; r < 4; r++) {
                    float vv = acc[i][j][r] * scale;
                    if (bias) vv += bias[mb + r];
                    O[(long)(mb + r) * ldo + n] = f2bf(vv);
                }
            } else if (EPI == 1) {
                u16* O = (u16*)Ogv + (long)b * sO;
                ushort4 pk;
                pk.x = f2bf(acc[i][j][0] + bias[mb + 0]);
                pk.y = f2bf(acc[i][j][1] + bias[mb + 1]);
                pk.z = f2bf(acc[i][j][2] + bias[mb + 2]);
                pk.w = f2bf(acc[i][j][3] + bias[mb + 3]);
                *reinterpret_cast<ushort4*>(&O[(long)n * ldo + mb]) = pk;
            } else {
                float* O = (float*)Ogv + (long)b * sO;
                const float* X = Xg + (long)b * sX;
                const float bn = bias[n];
                const float4 xv = *reinterpret_cast<const float4*>(&X[(long)n * ldo + mb]);
                float4 pk;
                pk.x = acc[i][j][0] + bn + xv.x;
                pk.y = acc[i][j][1] + bn + xv.y;
                pk.z = acc[i][j][2] + bn + xv.z;
                pk.w = acc[i][j][3] + bn + xv.w;
                *reinterpret_cast<float4*>(&O[(long)n * ldo + mb]) = pk;
            }
        }
    }
}

extern "C" void kernel_launch(void* const* d_in, const int* in_sizes, int n_in,
                              void* d_out, int out_size, void* d_ws, size_t ws_size,
                              hipStream_t stream) {
    const float* x     = (const float*)d_in[0];
    const float* gamma = (const float*)d_in[1];
    const float* beta  = (const float*)d_in[2];
    const float* wq    = (const float*)d_in[3];
    const float* bq    = (const float*)d_in[4];
    const float* wk    = (const float*)d_in[5];
    const float* bk    = (const float*)d_in[6];
    const float* wv    = (const float*)d_in[7];
    const float* bv    = (const float*)d_in[8];
    const float* wp    = (const float*)d_in[9];
    const float* bp    = (const float*)d_in[10];
    float* out = (float*)d_out;

    const long HC = (long)2048 * 512;
    const long HH = (long)2048 * 2048;
    const long WSZ = 512 * 512;
    const float scl = 0.044194173824159216f;   // 1/sqrt(512)

    char* ws = (char*)d_ws;
    float* meanb = (float*)ws;
    float* rstdb = (float*)(ws + 1024);
    u16* base = (u16*)(ws + 4096);

    const size_t FULL_NEED   = 4096 + 2 * (size_t)(24 * HC + 8 * HH);     // 117,444,608
    const size_t MED_NEED    = 4096 + 2 * (size_t)(32 * HC + HH);         //  75,501,568
    const size_t SMALL_NEED  = 4096 + 2 * (size_t)(4 * HC + HH);          //  16,781,312
    const size_t CHUNK512    = 4096 + 2 * (size_t)(4 * HC + 512 * 2048);  //  10,489,856

    gn_stats<<<256, 256, 0, stream>>>(x, meanb, rstdb);

    if (ws_size >= FULL_NEED) {
        // ---- FULL: all-batched, dbuf-async GEMMs, XCD-swizzled grids ----
        u16* qT  = base;                       // [B,H,C]
        u16* kT  = qT + 8 * HC;                // [B,H,C]
        u16* vv  = kT + 8 * HC;                // [B,C,H]
        u16* Sb  = vv + 8 * HC;                // [B,H,H]
        u16* hnT = Sb;                         // overlay: dead before S written
        u16* wb3 = Sb + 8 * HH - 3 * WSZ;      // overlay: wq|wk|wv bf16, dead after QKV
        u16* hT  = qT;                         // overlay: qT dead after S-GEMM
        u16* wpb = vv;                         // overlay: vv dead after PV

        w2bf<<<dim3(256, 3), 256, 0, stream>>>(wq, wk, wv, wb3);
        gn_apply_t<<<dim3(32, 8, 8), 256, 0, stream>>>(x, gamma, beta, meanb, rstdb, hnT);
        qkv_a<<<dim3(192, 1, 8), 256, 0, stream>>>(wb3, hnT, bq, bk, bv, qT, kT, vv);
        gemm_tn_a<0, 2><<<dim3(256, 1, 8), 256, 0, stream>>>(qT, HC, kT, HC, nullptr, nullptr, 0,
                                                             Sb, HH, 512, 512, 512, 2048, scl);
        softmax_rows<<<16384, 256, 0, stream>>>(Sb);
        gemm_tn_a64<0><<<dim3(128, 1, 8), 256, 0, stream>>>(Sb, HH, vv, HC, nullptr, nullptr, 0,
                                                            hT, HC, 2048, 2048, 2048, 512, 1.f);
        w2bf<<<dim3(256, 1), 256, 0, stream>>>(wp, wp, wp, wpb);
        gemm_tn_a64<2><<<dim3(128, 1, 8), 256, 0, stream>>>(hT, HC, wpb, 0, bp, x, HC,
                                                            out, HC, 512, 512, 512, 2048, 1.f);
    } else if (ws_size >= MED_NEED) {
        u16* hnT = base;
        u16* qT  = hnT + 8 * HC;
        u16* kT  = qT + 8 * HC;
        u16* vv  = kT + 8 * HC;
        u16* Sb  = vv + 8 * HC;
        u16* hT  = hnT;
        gn_apply_t<<<dim3(32, 8, 8), 256, 0, stream>>>(x, gamma, beta, meanb, rstdb, hnT);
        gemm_tn<1, 1, 0><<<dim3(16, 4, 8), 256, 0, stream>>>(wq, 0, hnT, HC, bq, nullptr, 0,
                                                             qT, HC, 512, 512, 512, 512, 1.f);
        gemm_tn<1, 1, 0><<<dim3(16, 4, 8), 256, 0, stream>>>(wk, 0, hnT, HC, bk, nullptr, 0,
                                                             kT, HC, 512, 512, 512, 512, 1.f);
        gemm_tn<0, 1, 0><<<dim3(16, 4, 8), 256, 0, stream>>>(wv, 0, hnT, HC, bv, nullptr, 0,
                                                             vv, HC, 512, 512, 512, 2048, 1.f);
        for (int b = 0; b < 8; b++) {
            gemm_tn<0, 0, 0><<<dim3(16, 16, 1), 256, 0, stream>>>(qT + b * HC, 0, kT + b * HC, 0,
                                                                  nullptr, nullptr, 0, Sb, 0,
                                                                  512, 512, 512, 2048, scl);
            softmax_rows<<<2048, 256, 0, stream>>>(Sb);
            gemm_tn<0, 0, 0><<<dim3(4, 16, 1), 256, 0, stream>>>(Sb, 0, vv + b * HC, 0,
                                                                 nullptr, nullptr, 0, hT + b * HC, 0,
                                                                 2048, 2048, 2048, 512, 1.f);
        }
        gemm_tn<2, 0, 1><<<dim3(4, 16, 8), 256, 0, stream>>>(hT, HC, wp, 0, bp, x, HC,
                                                             out, HC, 512, 512, 512, 2048, 1.f);
    } else {
        const int CH = (ws_size >= SMALL_NEED) ? 2048 : ((ws_size >= CHUNK512) ? 512 : 128);
        u16* hn = base;
        u16* q  = hn + HC;
        u16* k  = q + HC;
        u16* v  = k + HC;
        u16* Sc = v + HC;
        u16* hT = hn;
        for (int b = 0; b < 8; b++) {
            const float* xb = x + (long)b * HC;
            gn_apply_t<<<dim3(32, 8, 1), 256, 0, stream>>>(xb, gamma, beta,
                                                           meanb + b * 32, rstdb + b * 32, hn);
            gemm_tn<1, 1, 0><<<dim3(16, 4, 1), 256, 0, stream>>>(wq, 0, hn, 0, bq, nullptr, 0,
                                                                 q, 0, 512, 512, 512, 512, 1.f);
            gemm_tn<1, 1, 0><<<dim3(16, 4, 1), 256, 0, stream>>>(wk, 0, hn, 0, bk, nullptr, 0,
                                                                 k, 0, 512, 512, 512, 512, 1.f);
            gemm_tn<0, 1, 0><<<dim3(16, 4, 1), 256, 0, stream>>>(wv, 0, hn, 0, bv, nullptr, 0,
                                                                 v, 0, 512, 512, 512, 2048, 1.f);
            for (int i0 = 0; i0 < 2048; i0 += CH) {
                gemm_tn<0, 0, 0><<<dim3(16, CH / 128, 1), 256, 0, stream>>>(
                    q + (long)i0 * 512, 0, k, 0, nullptr, nullptr, 0, Sc, 0,
                    512, 512, 512, 2048, scl);
                softmax_rows<<<CH, 256, 0, stream>>>(Sc);
                gemm_tn<0, 0, 0><<<dim3(4, CH / 128, 1), 256, 0, stream>>>(
                    Sc, 0, v, 0, nullptr, nullptr, 0, hT + (long)i0 * 512, 0,
                    2048, 2048, 2048, 512, 1.f);
            }
            gemm_tn<2, 0, 1><<<dim3(4, 16, 1), 256, 0, stream>>>(hT, 0, wp, 0, bp, xb, 0,
                                                                 out + (long)b * HC, 0,
                                                                 512, 512, 512, 2048, 1.f);
        }
    }
}

// Round 2
// 305.906 us; speedup vs baseline: 1.0445x; 1.0445x over previous
//
#include <hip/hip_runtime.h>
#include <stdint.h>

typedef unsigned short u16;
typedef short s16x8 __attribute__((ext_vector_type(8)));
typedef float f32x4 __attribute__((ext_vector_type(4)));

#define BM 128
#define BN 128
#define BK 32
#define KPAD 40   // padded LDS row stride for the legacy (non-async) kernel

__device__ __forceinline__ float bf2f(u16 b) {
    union { unsigned int u; float f; } v; v.u = ((unsigned int)b) << 16; return v.f;
}
__device__ __forceinline__ u16 f2bf(float f) {
    union { float f; unsigned int u; } v; v.f = f;
    unsigned int u = v.u;
    u += 0x7fffu + ((u >> 16) & 1u);   // RNE
    return (u16)(u >> 16);
}
__device__ __forceinline__ void async_cp16(const u16* g, u16* l) {
    // global -> LDS direct copy, 16 B per lane; LDS dest = wave-uniform base + lane*16
    __builtin_amdgcn_global_load_lds((const __attribute__((address_space(1))) void*)g,
                                     (__attribute__((address_space(3))) void*)l, 16, 0, 0);
}

// ---------------- GroupNorm statistics: one block per (b,g), fp32 input ----------------
__global__ __launch_bounds__(256) void gn_stats(const float* __restrict__ x,
                                                float* __restrict__ mean,
                                                float* __restrict__ rstd) {
    const int bg = blockIdx.x;
    const float* p = x + (long)bg * 16 * 2048;     // 32768 fp32 per group
    float s = 0.f, ss = 0.f;
    for (int it = 0; it < 32; it++) {
        const float4 v = *reinterpret_cast<const float4*>(p + ((it * 256 + threadIdx.x) << 2));
        s += v.x + v.y + v.z + v.w;
        ss += v.x * v.x + v.y * v.y + v.z * v.z + v.w * v.w;
    }
    const int lane = threadIdx.x & 63, wave = threadIdx.x >> 6;
#pragma unroll
    for (int o = 32; o > 0; o >>= 1) { s += __shfl_down(s, o, 64); ss += __shfl_down(ss, o, 64); }
    __shared__ float rb[8];
    if (lane == 0) { rb[wave] = s; rb[4 + wave] = ss; }
    __syncthreads();
    if (threadIdx.x == 0) {
        float S = rb[0] + rb[1] + rb[2] + rb[3];
        float SS = rb[4] + rb[5] + rb[6] + rb[7];
        float mu = S * (1.f / 32768.f);
        float var = SS * (1.f / 32768.f) - mu * mu;
        mean[bg] = mu;
        rstd[bg] = rsqrtf(var + 1e-6f);
    }
}

// ---------- GroupNorm apply + transpose: fp32 x -> bf16 hnT[h, c] ----------
__global__ __launch_bounds__(256) void gn_apply_t(const float* __restrict__ x,
                                                  const float* __restrict__ gamma,
                                                  const float* __restrict__ beta,
                                                  const float* __restrict__ mean,
                                                  const float* __restrict__ rstd,
                                                  u16* __restrict__ hnT) {
    const int b = blockIdx.z, c0 = blockIdx.y * 64, h0 = blockIdx.x * 64;
    __shared__ __align__(16) u16 T[64][72];
    const int tid = threadIdx.x;
#pragma unroll
    for (int sidx = 0; sidx < 4; sidx++) {
        int ch = tid + sidx * 256;                 // 1024 float4-chunks
        int cc = ch >> 4, h4 = (ch & 15) * 4;
        int c = c0 + cc;
        float mu = mean[b * 32 + (c >> 4)], rs = rstd[b * 32 + (c >> 4)];
        float ga = gamma[c], be = beta[c];
        const float4 v = *reinterpret_cast<const float4*>(x + ((long)b * 512 + c) * 2048 + h0 + h4);
        ushort4 pk;
        pk.x = f2bf((v.x - mu) * rs * ga + be);
        pk.y = f2bf((v.y - mu) * rs * ga + be);
        pk.z = f2bf((v.z - mu) * rs * ga + be);
        pk.w = f2bf((v.w - mu) * rs * ga + be);
        *reinterpret_cast<ushort4*>(&T[cc][h4]) = pk;
    }
    __syncthreads();
#pragma unroll
    for (int sidx = 0; sidx < 2; sidx++) {
        int ch = tid + sidx * 256;                 // 512 uint4-chunks
        int hh = ch >> 3, c8 = (ch & 7) * 8;
        unsigned int o[4];
#pragma unroll
        for (int i = 0; i < 4; i++) {
            u16 lo = T[c8 + 2 * i][hh];
            u16 hi = T[c8 + 2 * i + 1][hh];
            o[i] = (unsigned int)lo | ((unsigned int)hi << 16);
        }
        *reinterpret_cast<uint4*>(hnT + ((long)b * 2048 + h0 + hh) * 512 + c0 + c8) =
            uint4{o[0], o[1], o[2], o[3]};
    }
}

// ---------------- fp32 -> bf16 weight conversion (512x512 each, y selects src) ----------------
__global__ __launch_bounds__(256) void w2bf(const float* __restrict__ a,
                                            const float* __restrict__ b,
                                            const float* __restrict__ c,
                                            u16* __restrict__ dst) {
    const float* s = (blockIdx.y == 0) ? a : (blockIdx.y == 1) ? b : c;
    const int i = (blockIdx.x * 256 + threadIdx.x) * 4;
    const float4 v = *reinterpret_cast<const float4*>(s + i);
    ushort4 p;
    p.x = f2bf(v.x); p.y = f2bf(v.y); p.z = f2bf(v.z); p.w = f2bf(v.w);
    *reinterpret_cast<ushort4*>(dst + (long)blockIdx.y * 262144 + i) = p;
}

// ------------------ softmax over rows of S[i, :] (bf16) in place ------------------
__global__ __launch_bounds__(256) void softmax_rows(u16* __restrict__ S) {
    u16* p = S + (long)blockIdx.x * 2048;
    const int tid = threadIdx.x;
    uint4 v = *reinterpret_cast<const uint4*>(p + (tid << 3));
    unsigned int w[4] = {v.x, v.y, v.z, v.w};
    float f[8];
#pragma unroll
    for (int i = 0; i < 4; i++) {
        f[2 * i]     = bf2f((u16)(w[i] & 0xffffu));
        f[2 * i + 1] = bf2f((u16)(w[i] >> 16));
    }
    float m = f[0];
#pragma unroll
    for (int i = 1; i < 8; i++) m = fmaxf(m, f[i]);
    const int lane = tid & 63, wave = tid >> 6;
#pragma unroll
    for (int o = 32; o > 0; o >>= 1) m = fmaxf(m, __shfl_down(m, o, 64));
    __shared__ float rb[4];
    __shared__ float bc;
    if (lane == 0) rb[wave] = m;
    __syncthreads();
    if (tid == 0) bc = fmaxf(fmaxf(rb[0], rb[1]), fmaxf(rb[2], rb[3]));
    __syncthreads();
    m = bc;
    float s = 0.f;
#pragma unroll
    for (int i = 0; i < 8; i++) { f[i] = __expf(f[i] - m); s += f[i]; }
#pragma unroll
    for (int o = 32; o > 0; o >>= 1) s += __shfl_down(s, o, 64);
    __syncthreads();
    if (lane == 0) rb[wave] = s;
    __syncthreads();
    if (tid == 0) bc = 1.f / (rb[0] + rb[1] + rb[2] + rb[3]);
    __syncthreads();
    const float inv = bc;
#pragma unroll
    for (int i = 0; i < 4; i++)
        w[i] = (unsigned int)f2bf(f[2 * i] * inv) | ((unsigned int)f2bf(f[2 * i + 1] * inv) << 16);
    *reinterpret_cast<uint4*>(p + (tid << 3)) = uint4{w[0], w[1], w[2], w[3]};
}

// ===================== ASYNC 3-deep counted-vmcnt MFMA GEMM (bf16 operands) =====================
// T4 (counted vmcnt, never drain to 0 in the main loop) on a 3-buffer LDS pipeline.
// Per K-step: s_waitcnt vmcnt(4) [oldest stage landed, newest 4 loads stay in flight]
//   -> raw s_barrier (asm "memory" clobber: no LDS op crosses at compile time)
//   -> issue stage t+2 -> compute t. Loads get ~2 compute bodies of latency cover.
// WAR safety: buffer staged at iter t was last ds_read at iter t-1; those reads complete
// before each wave's barrier entry (lgkmcnt gates the consuming MFMAs), so the barrier
// at t makes the overwrite safe.
// SWIZ 0: normal 2D grid. SWIZ 1: 1D grid of 64 (4n x 16m, A-strip per XCD).
// SWIZ 2: 1D grid of 256 (16n x 16m, 4m x 8n quadrant per XCD).
template <int EPI, int SWIZ>
__global__ __launch_bounds__(256) void gemm_tn_a(const u16* __restrict__ Ag, long sA,
                                                 const u16* __restrict__ Bg, long sB,
                                                 const float* __restrict__ bias,
                                                 const float* __restrict__ Xg, long sX,
                                                 void* __restrict__ Ogv, long sO,
                                                 int K, int lda, int ldb, int ldo,
                                                 float scale) {
    const int b = blockIdx.z;
    Ag += (long)b * sA;
    Bg += (long)b * sB;
    int tx, ty;
    if (SWIZ == 1) {
        const int xcd = blockIdx.x & 7, s = blockIdx.x >> 3;
        ty = xcd + 8 * (s >> 2);
        tx = s & 3;
    } else if (SWIZ == 2) {
        const int xcd = blockIdx.x & 7, s = blockIdx.x >> 3;
        ty = (xcd & 3) * 4 + (s & 3);
        tx = (xcd >> 2) * 8 + (s >> 2);
    } else {
        tx = blockIdx.x; ty = blockIdx.y;
    }
    const int m0 = ty * BM;
    const int n0 = tx * BN;

    __shared__ __align__(16) u16 As[3][BM * BK];
    __shared__ __align__(16) u16 Bs[3][BN * BK];

    const int tid = threadIdx.x;
    const int wave = tid >> 6;
    const int lane = tid & 63;
    const int quad = lane >> 4;
    const int l16 = lane & 15;
    const int wm = (wave >> 1) * 64;
    const int wn = (wave & 1) * 64;
    const int rl = lane >> 2;
    const int cl = (lane & 3) * 8;

    f32x4 acc[4][4];
#pragma unroll
    for (int i = 0; i < 4; i++)
#pragma unroll
        for (int j = 0; j < 4; j++) acc[i][j] = f32x4{0.f, 0.f, 0.f, 0.f};

    auto stage = [&](int buf, int k0) {      // 4 global_load_lds per wave
#pragma unroll
        for (int j = 0; j < 2; j++) {
            const int rbase = wave * 32 + j * 16;
            async_cp16(Ag + (long)(m0 + rbase + rl) * lda + k0 + cl, &As[buf][rbase * BK]);
            async_cp16(Bg + (long)(n0 + rbase + rl) * ldb + k0 + cl, &Bs[buf][rbase * BK]);
        }
    };
    auto compute = [&](int buf) {
        s16x8 af[4], bfr[4];
#pragma unroll
        for (int i = 0; i < 4; i++)
            af[i] = *reinterpret_cast<const s16x8*>(&As[buf][(wm + i * 16 + l16) * BK + quad * 8]);
#pragma unroll
        for (int j = 0; j < 4; j++)
            bfr[j] = *reinterpret_cast<const s16x8*>(&Bs[buf][(wn + j * 16 + l16) * BK + quad * 8]);
#pragma unroll
        for (int i = 0; i < 4; i++)
#pragma unroll
            for (int j = 0; j < 4; j++)
                acc[i][j] = __builtin_amdgcn_mfma_f32_16x16x32_bf16(af[i], bfr[j], acc[i][j], 0, 0, 0);
    };

    const int nsteps = K / BK;
    stage(0, 0);
    stage(1, BK);
    int t = 0;
    for (; t < nsteps - 1; t++) {
        asm volatile("s_waitcnt vmcnt(4)" ::: "memory");
        asm volatile("s_barrier" ::: "memory");
        if (t + 2 < nsteps) stage((t + 2) % 3, (t + 2) * BK);
        compute(t % 3);
    }
    asm volatile("s_waitcnt vmcnt(0)" ::: "memory");
    asm volatile("s_barrier" ::: "memory");
    compute(t % 3);

#pragma unroll
    for (int i = 0; i < 4; i++) {
        const int mb = m0 + wm + i * 16 + quad * 4;
#pragma unroll
        for (int j = 0; j < 4; j++) {
            const int n = n0 + wn + j * 16 + l16;
            if (EPI == 0) {
                u16* O = (u16*)Ogv + (long)b * sO;
#pragma unroll
                for (int r = 0; r < 4; r++) {
                    float vv = acc[i][j][r] * scale;
                    if (bias) vv += bias[mb + r];
                    O[(long)(mb + r) * ldo + n] = f2bf(vv);
                }
            } else if (EPI == 1) {
                u16* O = (u16*)Ogv + (long)b * sO;
                ushort4 pk;
                pk.x = f2bf(acc[i][j][0] + bias[mb + 0]);
                pk.y = f2bf(acc[i][j][1] + bias[mb + 1]);
                pk.z = f2bf(acc[i][j][2] + bias[mb + 2]);
                pk.w = f2bf(acc[i][j][3] + bias[mb + 3]);
                *reinterpret_cast<ushort4*>(&O[(long)n * ldo + mb]) = pk;
            } else {
                float* O = (float*)Ogv + (long)b * sO;
                const float* X = Xg + (long)b * sX;
                const float bn = bias[n];
                const float4 xv = *reinterpret_cast<const float4*>(&X[(long)n * ldo + mb]);
                float4 pk;
                pk.x = acc[i][j][0] + bn + xv.x;
                pk.y = acc[i][j][1] + bn + xv.y;
                pk.z = acc[i][j][2] + bn + xv.z;
                pk.w = acc[i][j][3] + bn + xv.w;
                *reinterpret_cast<float4*>(&O[(long)n * ldo + mb]) = pk;
            }
        }
    }
}

// ===================== merged QKV GEMM, XCD-swizzled, 3-deep counted-vmcnt =====================
// 12 blocks sharing an hnT strip (4 m-tiles x 3 outputs) co-locate on one XCD.
__global__ __launch_bounds__(256) void qkv_a(const u16* __restrict__ wb3,
                                             const u16* __restrict__ hnT,
                                             const float* __restrict__ bq,
                                             const float* __restrict__ bk,
                                             const float* __restrict__ bv,
                                             u16* __restrict__ qT, u16* __restrict__ kT,
                                             u16* __restrict__ vv) {
    const long HC = 1048576;
    const int b = blockIdx.z;
    const int xcd = blockIdx.x & 7, s = blockIdx.x >> 3;   // s in [0,24)
    const int hi = (s >= 12) ? 1 : 0;
    const int yy = s - hi * 12;                            // [0,12)
    const int x = xcd + 8 * hi;                            // n-tile [0,16)
    const int which = yy >> 2;                             // 0=q 1=k 2=v
    const int my = yy & 3;                                 // m-tile [0,4)
    const u16* Ag = wb3 + which * 262144;
    const u16* Bg = hnT + (long)b * HC;
    const int m0 = my * BM;
    const int n0 = x * BN;

    __shared__ __align__(16) u16 As[3][BM * BK];
    __shared__ __align__(16) u16 Bs[3][BN * BK];

    const int tid = threadIdx.x;
    const int wave = tid >> 6;
    const int lane = tid & 63;
    const int quad = lane >> 4;
    const int l16 = lane & 15;
    const int wm = (wave >> 1) * 64;
    const int wn = (wave & 1) * 64;
    const int rl = lane >> 2;
    const int cl = (lane & 3) * 8;

    f32x4 acc[4][4];
#pragma unroll
    for (int i = 0; i < 4; i++)
#pragma unroll
        for (int j = 0; j < 4; j++) acc[i][j] = f32x4{0.f, 0.f, 0.f, 0.f};

    auto stage = [&](int buf, int k0) {      // 4 global_load_lds per wave
#pragma unroll
        for (int j = 0; j < 2; j++) {
            const int rbase = wave * 32 + j * 16;
            async_cp16(Ag + (long)(m0 + rbase + rl) * 512 + k0 + cl, &As[buf][rbase * BK]);
            async_cp16(Bg + (long)(n0 + rbase + rl) * 512 + k0 + cl, &Bs[buf][rbase * BK]);
        }
    };
    auto compute = [&](int buf) {
        s16x8 af[4], bfr[4];
#pragma unroll
        for (int i = 0; i < 4; i++)
            af[i] = *reinterpret_cast<const s16x8*>(&As[buf][(wm + i * 16 + l16) * BK + quad * 8]);
#pragma unroll
        for (int j = 0; j < 4; j++)
            bfr[j] = *reinterpret_cast<const s16x8*>(&Bs[buf][(wn + j * 16 + l16) * BK + quad * 8]);
#pragma unroll
        for (int i = 0; i < 4; i++)
#pragma unroll
            for (int j = 0; j < 4; j++)
                acc[i][j] = __builtin_amdgcn_mfma_f32_16x16x32_bf16(af[i], bfr[j], acc[i][j], 0, 0, 0);
    };

    const int nsteps = 512 / BK;   // 16
    stage(0, 0);
    stage(1, BK);
    int t = 0;
    for (; t < nsteps - 1; t++) {
        asm volatile("s_waitcnt vmcnt(4)" ::: "memory");
        asm volatile("s_barrier" ::: "memory");
        if (t + 2 < nsteps) stage((t + 2) % 3, (t + 2) * BK);
        compute(t % 3);
    }
    asm volatile("s_waitcnt vmcnt(0)" ::: "memory");
    asm volatile("s_barrier" ::: "memory");
    compute(t % 3);

    if (which == 2) {
        u16* O = vv + (long)b * HC;
#pragma unroll
        for (int i = 0; i < 4; i++) {
            const int mb = m0 + wm + i * 16 + quad * 4;
#pragma unroll
            for (int j = 0; j < 4; j++) {
                const int n = n0 + wn + j * 16 + l16;
#pragma unroll
                for (int r = 0; r < 4; r++)
                    O[(long)(mb + r) * 2048 + n] = f2bf(acc[i][j][r] + bv[mb + r]);
            }
        }
    } else {
        const float* bias = which ? bk : bq;
        u16* O = (which ? kT : qT) + (long)b * HC;
#pragma unroll
        for (int i = 0; i < 4; i++) {
            const int mb = m0 + wm + i * 16 + quad * 4;
#pragma unroll
            for (int j = 0; j < 4; j++) {
                const int n = n0 + wn + j * 16 + l16;
                ushort4 pk;
                pk.x = f2bf(acc[i][j][0] + bias[mb + 0]);
                pk.y = f2bf(acc[i][j][1] + bias[mb + 1]);
                pk.z = f2bf(acc[i][j][2] + bias[mb + 2]);
                pk.w = f2bf(acc[i][j][3] + bias[mb + 3]);
                *reinterpret_cast<ushort4*>(&O[(long)n * 512 + mb]) = pk;
            }
        }
    }
}

// ===================== legacy padded GEMM (fallback tiers, fp32-capable) =====================
template <int F32>
__device__ __forceinline__ void stage_tile(const char* G, int ld, int r0, int k0,
                                           u16* __restrict__ lds, int tid) {
    if (F32) {
        const float* g = (const float*)G;
#pragma unroll
        for (int s = 0; s < 4; s++) {
            const int c = tid + s * 256;
            const int row = c >> 3, col = (c & 7) * 4;
            const float4 v = *reinterpret_cast<const float4*>(g + (long)(r0 + row) * ld + k0 + col);
            ushort4 pk;
            pk.x = f2bf(v.x); pk.y = f2bf(v.y); pk.z = f2bf(v.z); pk.w = f2bf(v.w);
            *reinterpret_cast<ushort4*>(&lds[row * KPAD + col]) = pk;
        }
    } else {
        const u16* g = (const u16*)G;
#pragma unroll
        for (int s = 0; s < 2; s++) {
            const int c = tid + s * 256;
            const int row = c >> 2, col = (c & 3) * 8;
            const uint4 v = *reinterpret_cast<const uint4*>(g + (long)(r0 + row) * ld + k0 + col);
            *reinterpret_cast<uint4*>(&lds[row * KPAD + col]) = v;
        }
    }
}

template <int EPI, int AF32, int BF32>
__global__ __launch_bounds__(256) void gemm_tn(const void* __restrict__ Agv, long sA,
                                               const void* __restrict__ Bgv, long sB,
                                               const float* __restrict__ bias,
                                               const float* __restrict__ Xg, long sX,
                                               void* __restrict__ Ogv, long sO,
                                               int K, int lda, int ldb, int ldo,
                                               float scale) {
    const int b = blockIdx.z;
    const char* A8 = (const char*)Agv + (long)b * sA * (AF32 ? 4 : 2);
    const char* B8 = (const char*)Bgv + (long)b * sB * (BF32 ? 4 : 2);
    const int m0 = blockIdx.y * BM;
    const int n0 = blockIdx.x * BN;

    __shared__ __align__(16) u16 As[BM * KPAD];
    __shared__ __align__(16) u16 Bs[BN * KPAD];

    const int tid = threadIdx.x;
    const int wave = tid >> 6;
    const int lane = tid & 63;
    const int quad = lane >> 4;
    const int l16 = lane & 15;
    const int wm = (wave >> 1) * 64;
    const int wn = (wave & 1) * 64;

    f32x4 acc[4][4];
#pragma unroll
    for (int i = 0; i < 4; i++)
#pragma unroll
        for (int j = 0; j < 4; j++) acc[i][j] = f32x4{0.f, 0.f, 0.f, 0.f};

    for (int k0 = 0; k0 < K; k0 += BK) {
        __syncthreads();
        stage_tile<AF32>(A8, lda, m0, k0, As, tid);
        stage_tile<BF32>(B8, ldb, n0, k0, Bs, tid);
        __syncthreads();
        s16x8 af[4], bfr[4];
#pragma unroll
        for (int i = 0; i < 4; i++)
            af[i] = *reinterpret_cast<const s16x8*>(&As[(wm + i * 16 + l16) * KPAD + quad * 8]);
#pragma unroll
        for (int j = 0; j < 4; j++)
            bfr[j] = *reinterpret_cast<const s16x8*>(&Bs[(wn + j * 16 + l16) * KPAD + quad * 8]);
#pragma unroll
        for (int i = 0; i < 4; i++)
#pragma unroll
            for (int j = 0; j < 4; j++)
                acc[i][j] = __builtin_amdgcn_mfma_f32_16x16x32_bf16(af[i], bfr[j], acc[i][j], 0, 0, 0);
    }

#pragma unroll
    for (int i = 0; i < 4; i++) {
        const int mb = m0 + wm + i * 16 + quad * 4;
#pragma unroll
        for (int j = 0; j < 4; j++) {
            const int n = n0 + wn + j * 16 + l16;
            if (EPI == 0) {
                u16* O = (u16*)Ogv + (long)b * sO;
#pragma unroll
                for (int r = 0; r < 4; r++) {
                    float vv = acc[i][j][r] * scale;
                    if (bias) vv += bias[mb + r];
                    O[(long)(mb + r) * ldo + n] = f2bf(vv);
                }
            } else if (EPI == 1) {
                u16* O = (u16*)Ogv + (long)b * sO;
                ushort4 pk;
                pk.x = f2bf(acc[i][j][0] + bias[mb + 0]);
                pk.y = f2bf(acc[i][j][1] + bias[mb + 1]);
                pk.z = f2bf(acc[i][j][2] + bias[mb + 2]);
                pk.w = f2bf(acc[i][j][3] + bias[mb + 3]);
                *reinterpret_cast<ushort4*>(&O[(long)n * ldo + mb]) = pk;
            } else {
                float* O = (float*)Ogv + (long)b * sO;
                const float* X = Xg + (long)b * sX;
                const float bn = bias[n];
                const float4 xv = *reinterpret_cast<const float4*>(&X[(long)n * ldo + mb]);
                float4 pk;
                pk.x = acc[i][j][0] + bn + xv.x;
                pk.y = acc[i][j][1] + bn + xv.y;
                pk.z = acc[i][j][2] + bn + xv.z;
                pk.w = acc[i][j][3] + bn + xv.w;
                *reinterpret_cast<float4*>(&O[(long)n * ldo + mb]) = pk;
            }
        }
    }
}

extern "C" void kernel_launch(void* const* d_in, const int* in_sizes, int n_in,
                              void* d_out, int out_size, void* d_ws, size_t ws_size,
                              hipStream_t stream) {
    const float* x     = (const float*)d_in[0];
    const float* gamma = (const float*)d_in[1];
    const float* beta  = (const float*)d_in[2];
    const float* wq    = (const float*)d_in[3];
    const float* bq    = (const float*)d_in[4];
    const float* wk    = (const float*)d_in[5];
    const float* bk    = (const float*)d_in[6];
    const float* wv    = (const float*)d_in[7];
    const float* bv    = (const float*)d_in[8];
    const float* wp    = (const float*)d_in[9];
    const float* bp    = (const float*)d_in[10];
    float* out = (float*)d_out;

    const long HC = (long)2048 * 512;
    const long HH = (long)2048 * 2048;
    const long WSZ = 512 * 512;
    const float scl = 0.044194173824159216f;   // 1/sqrt(512)

    char* ws = (char*)d_ws;
    float* meanb = (float*)ws;
    float* rstdb = (float*)(ws + 1024);
    u16* base = (u16*)(ws + 4096);

    const size_t FULL_NEED   = 4096 + 2 * (size_t)(24 * HC + 8 * HH);     // 117,444,608
    const size_t MED_NEED    = 4096 + 2 * (size_t)(32 * HC + HH);         //  75,501,568
    const size_t SMALL_NEED  = 4096 + 2 * (size_t)(4 * HC + HH);          //  16,781,312
    const size_t CHUNK512    = 4096 + 2 * (size_t)(4 * HC + 512 * 2048);  //  10,489,856

    gn_stats<<<256, 256, 0, stream>>>(x, meanb, rstdb);

    if (ws_size >= FULL_NEED) {
        // ---- FULL: all-batched, 3-deep counted-vmcnt GEMMs, XCD-swizzled grids ----
        u16* qT  = base;                       // [B,H,C]
        u16* kT  = qT + 8 * HC;                // [B,H,C]
        u16* vv  = kT + 8 * HC;                // [B,C,H]
        u16* Sb  = vv + 8 * HC;                // [B,H,H]
        u16* hnT = Sb;                         // overlay: dead before S written
        u16* wb3 = Sb + 8 * HH - 3 * WSZ;      // overlay: wq|wk|wv bf16, dead after QKV
        u16* hT  = qT;                         // overlay: qT dead after S-GEMM
        u16* wpb = vv;                         // overlay: vv dead after PV

        w2bf<<<dim3(256, 3), 256, 0, stream>>>(wq, wk, wv, wb3);
        gn_apply_t<<<dim3(32, 8, 8), 256, 0, stream>>>(x, gamma, beta, meanb, rstdb, hnT);
        qkv_a<<<dim3(192, 1, 8), 256, 0, stream>>>(wb3, hnT, bq, bk, bv, qT, kT, vv);
        gemm_tn_a<0, 2><<<dim3(256, 1, 8), 256, 0, stream>>>(qT, HC, kT, HC, nullptr, nullptr, 0,
                                                             Sb, HH, 512, 512, 512, 2048, scl);
        softmax_rows<<<16384, 256, 0, stream>>>(Sb);
        gemm_tn_a<0, 1><<<dim3(64, 1, 8), 256, 0, stream>>>(Sb, HH, vv, HC, nullptr, nullptr, 0,
                                                            hT, HC, 2048, 2048, 2048, 512, 1.f);
        w2bf<<<dim3(256, 1), 256, 0, stream>>>(wp, wp, wp, wpb);
        gemm_tn_a<2, 1><<<dim3(64, 1, 8), 256, 0, stream>>>(hT, HC, wpb, 0, bp, x, HC,
                                                            out, HC, 512, 512, 512, 2048, 1.f);
    } else if (ws_size >= MED_NEED) {
        u16* hnT = base;
        u16* qT  = hnT + 8 * HC;
        u16* kT  = qT + 8 * HC;
        u16* vv  = kT + 8 * HC;
        u16* Sb  = vv + 8 * HC;
        u16* hT  = hnT;
        gn_apply_t<<<dim3(32, 8, 8), 256, 0, stream>>>(x, gamma, beta, meanb, rstdb, hnT);
        gemm_tn<1, 1, 0><<<dim3(16, 4, 8), 256, 0, stream>>>(wq, 0, hnT, HC, bq, nullptr, 0,
                                                             qT, HC, 512, 512, 512, 512, 1.f);
        gemm_tn<1, 1, 0><<<dim3(16, 4, 8), 256, 0, stream>>>(wk, 0, hnT, HC, bk, nullptr, 0,
                                                             kT, HC, 512, 512, 512, 512, 1.f);
        gemm_tn<0, 1, 0><<<dim3(16, 4, 8), 256, 0, stream>>>(wv, 0, hnT, HC, bv, nullptr, 0,
                                                             vv, HC, 512, 512, 512, 2048, 1.f);
        for (int b = 0; b < 8; b++) {
            gemm_tn<0, 0, 0><<<dim3(16, 16, 1), 256, 0, stream>>>(qT + b * HC, 0, kT + b * HC, 0,
                                                                  nullptr, nullptr, 0, Sb, 0,
                                                                  512, 512, 512, 2048, scl);
            softmax_rows<<<2048, 256, 0, stream>>>(Sb);
            gemm_tn<0, 0, 0><<<dim3(4, 16, 1), 256, 0, stream>>>(Sb, 0, vv + b * HC, 0,
                                                                 nullptr, nullptr, 0, hT + b * HC, 0,
                                                                 2048, 2048, 2048, 512, 1.f);
        }
        gemm_tn<2, 0, 1><<<dim3(4, 16, 8), 256, 0, stream>>>(hT, HC, wp, 0, bp, x, HC,
                                                             out, HC, 512, 512, 512, 2048, 1.f);
    } else {
        const int CH = (ws_size >= SMALL_NEED) ? 2048 : ((ws_size >= CHUNK512) ? 512 : 128);
        u16* hn = base;
        u16* q  = hn + HC;
        u16* k  = q + HC;
        u16* v  = k + HC;
        u16* Sc = v + HC;
        u16* hT = hn;
        for (int b = 0; b < 8; b++) {
            const float* xb = x + (long)b * HC;
            gn_apply_t<<<dim3(32, 8, 1), 256, 0, stream>>>(xb, gamma, beta,
                                                           meanb + b * 32, rstdb + b * 32, hn);
            gemm_tn<1, 1, 0><<<dim3(16, 4, 1), 256, 0, stream>>>(wq, 0, hn, 0, bq, nullptr, 0,
                                                                 q, 0, 512, 512, 512, 512, 1.f);
            gemm_tn<1, 1, 0><<<dim3(16, 4, 1), 256, 0, stream>>>(wk, 0, hn, 0, bk, nullptr, 0,
                                                                 k, 0, 512, 512, 512, 512, 1.f);
            gemm_tn<0, 1, 0><<<dim3(16, 4, 1), 256, 0, stream>>>(wv, 0, hn, 0, bv, nullptr, 0,
                                                                 v, 0, 512, 512, 512, 2048, 1.f);
            for (int i0 = 0; i0 < 2048; i0 += CH) {
                gemm_tn<0, 0, 0><<<dim3(16, CH / 128, 1), 256, 0, stream>>>(
                    q + (long)i0 * 512, 0, k, 0, nullptr, nullptr, 0, Sc, 0,
                    512, 512, 512, 2048, scl);
                softmax_rows<<<CH, 256, 0, stream>>>(Sc);
                gemm_tn<0, 0, 0><<<dim3(4, CH / 128, 1), 256, 0, stream>>>(
                    Sc, 0, v, 0, nullptr, nullptr, 0, hT + (long)i0 * 512, 0,
                    2048, 2048, 2048, 512, 1.f);
            }
            gemm_tn<2, 0, 1><<<dim3(4, 16, 1), 256, 0, stream>>>(hT, 0, wp, 0, bp, xb, 0,
                                                                 out + (long)b * HC, 0,
                                                                 512, 512, 512, 2048, 1.f);
        }
    }
}

// Round 5
// 302.144 us; speedup vs baseline: 1.0575x; 1.0125x over previous
//
#include <hip/hip_runtime.h>
#include <stdint.h>

typedef unsigned short u16;
typedef short s16x8 __attribute__((ext_vector_type(8)));
typedef float f32x4 __attribute__((ext_vector_type(4)));

#define BM 128
#define BN 128
#define BK 32
#define KPAD 40   // padded LDS row stride for the legacy (non-async) kernel

#define WAITV(n) asm volatile("s_waitcnt vmcnt(" #n ")" ::: "memory")
#define BARR()   asm volatile("s_barrier" ::: "memory")
#define SB0()    __builtin_amdgcn_sched_barrier(0)

__device__ __forceinline__ float bf2f(u16 b) {
    union { unsigned int u; float f; } v; v.u = ((unsigned int)b) << 16; return v.f;
}
__device__ __forceinline__ u16 f2bf(float f) {
    union { float f; unsigned int u; } v; v.f = f;
    unsigned int u = v.u;
    u += 0x7fffu + ((u >> 16) & 1u);   // RNE
    return (u16)(u >> 16);
}
__device__ __forceinline__ void async_cp16(const u16* g, u16* l) {
    // global -> LDS direct copy, 16 B per lane; LDS dest = wave-uniform base + lane*16
    __builtin_amdgcn_global_load_lds((const __attribute__((address_space(1))) void*)g,
                                     (__attribute__((address_space(3))) void*)l, 16, 0, 0);
}

// ---------------- GroupNorm statistics: one block per (b,g), fp32 input ----------------
__global__ __launch_bounds__(256) void gn_stats(const float* __restrict__ x,
                                                float* __restrict__ mean,
                                                float* __restrict__ rstd) {
    const int bg = blockIdx.x;
    const float* p = x + (long)bg * 16 * 2048;     // 32768 fp32 per group
    float s = 0.f, ss = 0.f;
    for (int it = 0; it < 32; it++) {
        const float4 v = *reinterpret_cast<const float4*>(p + ((it * 256 + threadIdx.x) << 2));
        s += v.x + v.y + v.z + v.w;
        ss += v.x * v.x + v.y * v.y + v.z * v.z + v.w * v.w;
    }
    const int lane = threadIdx.x & 63, wave = threadIdx.x >> 6;
#pragma unroll
    for (int o = 32; o > 0; o >>= 1) { s += __shfl_down(s, o, 64); ss += __shfl_down(ss, o, 64); }
    __shared__ float rb[8];
    if (lane == 0) { rb[wave] = s; rb[4 + wave] = ss; }
    __syncthreads();
    if (threadIdx.x == 0) {
        float S = rb[0] + rb[1] + rb[2] + rb[3];
        float SS = rb[4] + rb[5] + rb[6] + rb[7];
        float mu = S * (1.f / 32768.f);
        float var = SS * (1.f / 32768.f) - mu * mu;
        mean[bg] = mu;
        rstd[bg] = rsqrtf(var + 1e-6f);
    }
}

// ---------- GroupNorm apply + transpose: fp32 x -> bf16 hnT[h, c] ----------
__global__ __launch_bounds__(256) void gn_apply_t(const float* __restrict__ x,
                                                  const float* __restrict__ gamma,
                                                  const float* __restrict__ beta,
                                                  const float* __restrict__ mean,
                                                  const float* __restrict__ rstd,
                                                  u16* __restrict__ hnT) {
    const int b = blockIdx.z, c0 = blockIdx.y * 64, h0 = blockIdx.x * 64;
    __shared__ __align__(16) u16 T[64][72];
    const int tid = threadIdx.x;
#pragma unroll
    for (int sidx = 0; sidx < 4; sidx++) {
        int ch = tid + sidx * 256;                 // 1024 float4-chunks
        int cc = ch >> 4, h4 = (ch & 15) * 4;
        int c = c0 + cc;
        float mu = mean[b * 32 + (c >> 4)], rs = rstd[b * 32 + (c >> 4)];
        float ga = gamma[c], be = beta[c];
        const float4 v = *reinterpret_cast<const float4*>(x + ((long)b * 512 + c) * 2048 + h0 + h4);
        ushort4 pk;
        pk.x = f2bf((v.x - mu) * rs * ga + be);
        pk.y = f2bf((v.y - mu) * rs * ga + be);
        pk.z = f2bf((v.z - mu) * rs * ga + be);
        pk.w = f2bf((v.w - mu) * rs * ga + be);
        *reinterpret_cast<ushort4*>(&T[cc][h4]) = pk;
    }
    __syncthreads();
#pragma unroll
    for (int sidx = 0; sidx < 2; sidx++) {
        int ch = tid + sidx * 256;                 // 512 uint4-chunks
        int hh = ch >> 3, c8 = (ch & 7) * 8;
        unsigned int o[4];
#pragma unroll
        for (int i = 0; i < 4; i++) {
            u16 lo = T[c8 + 2 * i][hh];
            u16 hi = T[c8 + 2 * i + 1][hh];
            o[i] = (unsigned int)lo | ((unsigned int)hi << 16);
        }
        *reinterpret_cast<uint4*>(hnT + ((long)b * 2048 + h0 + hh) * 512 + c0 + c8) =
            uint4{o[0], o[1], o[2], o[3]};
    }
}

// ---------------- fp32 -> bf16 weight conversion (512x512 each, y selects src) ----------------
__global__ __launch_bounds__(256) void w2bf(const float* __restrict__ a,
                                            const float* __restrict__ b,
                                            const float* __restrict__ c,
                                            u16* __restrict__ dst) {
    const float* s = (blockIdx.y == 0) ? a : (blockIdx.y == 1) ? b : c;
    const int i = (blockIdx.x * 256 + threadIdx.x) * 4;
    const float4 v = *reinterpret_cast<const float4*>(s + i);
    ushort4 p;
    p.x = f2bf(v.x); p.y = f2bf(v.y); p.z = f2bf(v.z); p.w = f2bf(v.w);
    *reinterpret_cast<ushort4*>(dst + (long)blockIdx.y * 262144 + i) = p;
}

// ------------------ softmax over rows of S[i, :] (bf16) in place ------------------
__global__ __launch_bounds__(256) void softmax_rows(u16* __restrict__ S) {
    u16* p = S + (long)blockIdx.x * 2048;
    const int tid = threadIdx.x;
    uint4 v = *reinterpret_cast<const uint4*>(p + (tid << 3));
    unsigned int w[4] = {v.x, v.y, v.z, v.w};
    float f[8];
#pragma unroll
    for (int i = 0; i < 4; i++) {
        f[2 * i]     = bf2f((u16)(w[i] & 0xffffu));
        f[2 * i + 1] = bf2f((u16)(w[i] >> 16));
    }
    float m = f[0];
#pragma unroll
    for (int i = 1; i < 8; i++) m = fmaxf(m, f[i]);
    const int lane = tid & 63, wave = tid >> 6;
#pragma unroll
    for (int o = 32; o > 0; o >>= 1) m = fmaxf(m, __shfl_down(m, o, 64));
    __shared__ float rb[4];
    __shared__ float bc;
    if (lane == 0) rb[wave] = m;
    __syncthreads();
    if (tid == 0) bc = fmaxf(fmaxf(rb[0], rb[1]), fmaxf(rb[2], rb[3]));
    __syncthreads();
    m = bc;
    float s = 0.f;
#pragma unroll
    for (int i = 0; i < 8; i++) { f[i] = __expf(f[i] - m); s += f[i]; }
#pragma unroll
    for (int o = 32; o > 0; o >>= 1) s += __shfl_down(s, o, 64);
    __syncthreads();
    if (lane == 0) rb[wave] = s;
    __syncthreads();
    if (tid == 0) bc = 1.f / (rb[0] + rb[1] + rb[2] + rb[3]);
    __syncthreads();
    const float inv = bc;
#pragma unroll
    for (int i = 0; i < 4; i++)
        w[i] = (unsigned int)f2bf(f[2 * i] * inv) | ((unsigned int)f2bf(f[2 * i + 1] * inv) << 16);
    *reinterpret_cast<uint4*>(p + (tid << 3)) = uint4{w[0], w[1], w[2], w[3]};
}

// ===================== 256x256-tile 8-wave 4-phase GEMM (T2+T3+T4+T5 stack) =====================
// C[m,n] = scale * sum_k A[m,k] B[n,k]; A,B row-major bf16 with K-contiguous rows.
// 512 threads = 8 waves (2 wm x 4 wn); per-wave C = 128x64 (acc 8x4 f32x4 frags).
// K-tile = 64, double-buffered LDS (128 KiB) split into 4 regions per buf:
//   A-lo = rows for quadrant mh=0 {m0+0-63 @ LDS 0-63, m0+128-191 @ 64-127};
//   A-hi = mh=1 {m0+64-127, m0+192-255}; B-lo/B-hi same pattern on n0 (+0/+32 per 32-row grp).
// 4 phases per K-tile, quadrants (mh,nh) = (0,0),(0,1),(1,1),(1,0):
//   p1: read fa<-A-lo + fblo<-B-lo; p2: read fbhi<-B-hi; p3: read fa<-A-hi; p4: regs only.
// Stage slots: p1: A-hi(t+1); p2: A-lo(t+2); p3: B-lo(t+2); p4: B-hi(t+2).
// Counted vmcnt(8) at every phase end; tail 8/4/2/0 in last two K-tiles; never 0 mid-loop.
// XOR swizzle (byte ^= (row&4)<<3) applied as pre-swizzled GLOBAL source (gload_lds dest
// linear) + swizzled ds_read (both-sides rule #21).
// r3/r4 FAIL root cause (fixed here): staging base addresses pA/pB omitted the tile
// origin (m0/n0) — every block staged tile (0,0)'s data. Deterministic (identical absmax
// across both failing rounds). Region maps/swizzle/sync ledger were verified correct.
// Keep r4 hardening: __launch_bounds__(512,1) (no spill VMEM to corrupt vmcnt ledger;
// LDS caps at 1 block/CU anyway) + sched_barrier(0) pins after every waitcnt/barrier.
// Grid: 512 blocks 1D; bx&7 = batch -> each XCD owns one batch (qT+kT = 4 MB = its L2).
__global__ __launch_bounds__(512, 1) void gemm256_s(const u16* __restrict__ Ag, long sA,
                                                    const u16* __restrict__ Bg, long sB,
                                                    u16* __restrict__ Og, long sO,
                                                    int K, int lda, int ldb, int ldo,
                                                    float scale) {
    const int bx = blockIdx.x;
    const int b = bx & 7, s = bx >> 3;
    const int ty = s & 7, tx = s >> 3;
    const int m0 = ty * 256, n0 = tx * 256;
    Ag += (long)b * sA;
    Bg += (long)b * sB;
    u16* O = Og + (long)b * sO;

    __shared__ __align__(16) u16 LA[2][2][128 * 64];   // [buf][region mh][row*64+k] 64 KiB
    __shared__ __align__(16) u16 LB[2][2][128 * 64];   // [buf][region nh]           64 KiB

    const int tid = threadIdx.x;
    const int lane = tid & 63, wave = tid >> 6;
    const int wm = wave >> 2, w4 = wave & 3;
    const int l15 = lane & 15, quad = lane >> 4;

    // ds_read offsets (u16 units); swizzle byte = (quad*16) ^ ((row&4)?32:0), row&4 == lane&4
    const int qxu   = ((quad << 4) ^ ((lane & 4) << 3)) >> 1;
    const int arow_u = (wm * 64 + l15) * 64;
    const int brow_u = (w4 * 32 + l15) * 64;

    // staging: lane covers LDS row (wave*8 + lane/8), col-block lane&7; global col-block
    // pre-swizzled: (lane&7) ^ 2 when LDS row&4 (i.e. lane&32)
    const int l8 = lane >> 3;
    const int lrow0 = wave * 8 + l8;                            // region row, issue 0 (0..63)
    const int sEl = (((lane & 7) ^ ((lane & 32) >> 4)) << 3);   // pre-swizzled col (elements)
    int pA[2], pB[2];
    pA[0] = (m0 + lrow0) * lda + sEl;                           // A-lo: global rows m0+lrow0
    pA[1] = (m0 + 64 + lrow0) * lda + sEl;                      // A-hi: global rows m0+64+lrow0
    {
        const int gb = (lrow0 >> 5) * 64 + (lrow0 & 31);        // B region row pattern
        pB[0] = (n0 + gb) * ldb + sEl;                          // B-lo: global cols n0+gb
        pB[1] = (n0 + gb + 32) * ldb + sEl;                     // B-hi: +32
    }
    const int jA = 128 * lda;
    const int jB = 128 * ldb;

    auto stageA = [&](int buf, int mh, int k0) {
        u16* d = &LA[buf][mh][wave * 512];
        async_cp16(Ag + pA[mh] + k0, d);
        async_cp16(Ag + pA[mh] + jA + k0, d + 4096);
    };
    auto stageB = [&](int buf, int nh, int k0) {
        u16* d = &LB[buf][nh][wave * 512];
        async_cp16(Bg + pB[nh] + k0, d);
        async_cp16(Bg + pB[nh] + jB + k0, d + 4096);
    };

    f32x4 acc[8][4];
#pragma unroll
    for (int i = 0; i < 8; i++)
#pragma unroll
        for (int j = 0; j < 4; j++) acc[i][j] = f32x4{0.f, 0.f, 0.f, 0.f};

    s16x8 fa[4][2], fblo[2][2], fbhi[2][2];

    const int NT = K >> 6;

    // ---- prologue: tile 0 (all 4 regions) + tile 1 (3 regions; A-hi(1) at p1 of t=0)
    stageA(0, 0, 0);            // A-lo(0)
    stageB(0, 0, 0);            // B-lo(0)
    stageB(0, 1, 0);            // B-hi(0)
    stageA(0, 1, 0);            // A-hi(0)
    if (NT > 1) {
        stageA(1, 0, 64);       // A-lo(1)
        stageB(1, 0, 64);       // B-lo(1)
        stageB(1, 1, 64);       // B-hi(1)
    }
    WAITV(8); SB0();
    BARR(); SB0();

    for (int t = 0; t < NT; t++) {
        const int buf = t & 1;
        const int k2 = (t + 2) << 6;
        // ---------------- phase 1: quadrant (mh=0, nh=0)
        {
            const u16* Ar = &LA[buf][0][0];
            const u16* Br = &LB[buf][0][0];
#pragma unroll
            for (int mf = 0; mf < 4; mf++)
#pragma unroll
                for (int ks = 0; ks < 2; ks++)
                    fa[mf][ks] = *reinterpret_cast<const s16x8*>(Ar + arow_u + mf * 1024 + ks * 32 + qxu);
#pragma unroll
            for (int nf = 0; nf < 2; nf++)
#pragma unroll
                for (int ks = 0; ks < 2; ks++)
                    fblo[nf][ks] = *reinterpret_cast<const s16x8*>(Br + brow_u + nf * 1024 + ks * 32 + qxu);
            if (t + 1 < NT) stageA(buf ^ 1, 1, (t + 1) << 6);      // A-hi(t+1)
            if (t == NT - 1) { WAITV(2); } else { WAITV(8); }
            SB0();
            BARR(); SB0();
            __builtin_amdgcn_s_setprio(1);
#pragma unroll
            for (int mf = 0; mf < 4; mf++)
#pragma unroll
                for (int nf = 0; nf < 2; nf++)
#pragma unroll
                    for (int ks = 0; ks < 2; ks++)
                        acc[mf][nf] = __builtin_amdgcn_mfma_f32_16x16x32_bf16(fa[mf][ks], fblo[nf][ks], acc[mf][nf], 0, 0, 0);
            __builtin_amdgcn_s_setprio(0);
            BARR(); SB0();
        }
        // ---------------- phase 2: quadrant (mh=0, nh=1)
        {
            const u16* Br = &LB[buf][1][0];
#pragma unroll
            for (int nf = 0; nf < 2; nf++)
#pragma unroll
                for (int ks = 0; ks < 2; ks++)
                    fbhi[nf][ks] = *reinterpret_cast<const s16x8*>(Br + brow_u + nf * 1024 + ks * 32 + qxu);
            if (t + 2 < NT) stageA(buf, 0, k2);                     // A-lo(t+2)
            if (t == NT - 1) { WAITV(0); } else { WAITV(8); }
            SB0();
            BARR(); SB0();
            __builtin_amdgcn_s_setprio(1);
#pragma unroll
            for (int mf = 0; mf < 4; mf++)
#pragma unroll
                for (int nf = 0; nf < 2; nf++)
#pragma unroll
                    for (int ks = 0; ks < 2; ks++)
                        acc[mf][2 + nf] = __builtin_amdgcn_mfma_f32_16x16x32_bf16(fa[mf][ks], fbhi[nf][ks], acc[mf][2 + nf], 0, 0, 0);
            __builtin_amdgcn_s_setprio(0);
            BARR(); SB0();
        }
        // ---------------- phase 3: quadrant (mh=1, nh=1)
        {
            const u16* Ar = &LA[buf][1][0];
#pragma unroll
            for (int mf = 0; mf < 4; mf++)
#pragma unroll
                for (int ks = 0; ks < 2; ks++)
                    fa[mf][ks] = *reinterpret_cast<const s16x8*>(Ar + arow_u + mf * 1024 + ks * 32 + qxu);
            if (t + 2 < NT) stageB(buf, 0, k2);                     // B-lo(t+2)
            WAITV(8); SB0();
            BARR(); SB0();
            __builtin_amdgcn_s_setprio(1);
#pragma unroll
            for (int mf = 0; mf < 4; mf++)
#pragma unroll
                for (int nf = 0; nf < 2; nf++)
#pragma unroll
                    for (int ks = 0; ks < 2; ks++)
                        acc[4 + mf][2 + nf] = __builtin_amdgcn_mfma_f32_16x16x32_bf16(fa[mf][ks], fbhi[nf][ks], acc[4 + mf][2 + nf], 0, 0, 0);
            __builtin_amdgcn_s_setprio(0);
            BARR(); SB0();
        }
        // ---------------- phase 4: quadrant (mh=1, nh=0) — operands held in registers
        {
            if (t + 2 < NT) stageB(buf, 1, k2);                     // B-hi(t+2)
            if (t == NT - 2) { WAITV(4); } else { WAITV(8); }
            SB0();
            BARR(); SB0();
            __builtin_amdgcn_s_setprio(1);
#pragma unroll
            for (int mf = 0; mf < 4; mf++)
#pragma unroll
                for (int nf = 0; nf < 2; nf++)
#pragma unroll
                    for (int ks = 0; ks < 2; ks++)
                        acc[4 + mf][nf] = __builtin_amdgcn_mfma_f32_16x16x32_bf16(fa[mf][ks], fblo[nf][ks], acc[4 + mf][nf], 0, 0, 0);
            __builtin_amdgcn_s_setprio(0);
            BARR(); SB0();
        }
    }

    // ---- epilogue: C = acc * scale, bf16 row-major [ldo]
    const int orow = m0 + wm * 128 + quad * 4;
    const int ocol = n0 + w4 * 64 + l15;
#pragma unroll
    for (int mi = 0; mi < 8; mi++)
#pragma unroll
        for (int ni = 0; ni < 4; ni++) {
            const long rb = (long)(orow + mi * 16) * ldo + ocol + ni * 16;
#pragma unroll
            for (int r = 0; r < 4; r++)
                O[rb + (long)r * ldo] = f2bf(acc[mi][ni][r] * scale);
        }
}

// ===================== ASYNC 3-deep counted-vmcnt MFMA GEMM (bf16 operands) =====================
// T4 (counted vmcnt, never drain to 0 in the main loop) on a 3-buffer LDS pipeline.
// SWIZ 0: normal 2D grid. SWIZ 1: 1D grid of 64 (4n x 16m, A-strip per XCD).
// SWIZ 2: 1D grid of 256 (16n x 16m, 4m x 8n quadrant per XCD).
template <int EPI, int SWIZ>
__global__ __launch_bounds__(256) void gemm_tn_a(const u16* __restrict__ Ag, long sA,
                                                 const u16* __restrict__ Bg, long sB,
                                                 const float* __restrict__ bias,
                                                 const float* __restrict__ Xg, long sX,
                                                 void* __restrict__ Ogv, long sO,
                                                 int K, int lda, int ldb, int ldo,
                                                 float scale) {
    const int b = blockIdx.z;
    Ag += (long)b * sA;
    Bg += (long)b * sB;
    int tx, ty;
    if (SWIZ == 1) {
        const int xcd = blockIdx.x & 7, s = blockIdx.x >> 3;
        ty = xcd + 8 * (s >> 2);
        tx = s & 3;
    } else if (SWIZ == 2) {
        const int xcd = blockIdx.x & 7, s = blockIdx.x >> 3;
        ty = (xcd & 3) * 4 + (s & 3);
        tx = (xcd >> 2) * 8 + (s >> 2);
    } else {
        tx = blockIdx.x; ty = blockIdx.y;
    }
    const int m0 = ty * BM;
    const int n0 = tx * BN;

    __shared__ __align__(16) u16 As[3][BM * BK];
    __shared__ __align__(16) u16 Bs[3][BN * BK];

    const int tid = threadIdx.x;
    const int wave = tid >> 6;
    const int lane = tid & 63;
    const int quad = lane >> 4;
    const int l16 = lane & 15;
    const int wm = (wave >> 1) * 64;
    const int wn = (wave & 1) * 64;
    const int rl = lane >> 2;
    const int cl = (lane & 3) * 8;

    f32x4 acc[4][4];
#pragma unroll
    for (int i = 0; i < 4; i++)
#pragma unroll
        for (int j = 0; j < 4; j++) acc[i][j] = f32x4{0.f, 0.f, 0.f, 0.f};

    auto stage = [&](int buf, int k0) {      // 4 global_load_lds per wave
#pragma unroll
        for (int j = 0; j < 2; j++) {
            const int rbase = wave * 32 + j * 16;
            async_cp16(Ag + (long)(m0 + rbase + rl) * lda + k0 + cl, &As[buf][rbase * BK]);
            async_cp16(Bg + (long)(n0 + rbase + rl) * ldb + k0 + cl, &Bs[buf][rbase * BK]);
        }
    };
    auto compute = [&](int buf) {
        s16x8 af[4], bfr[4];
#pragma unroll
        for (int i = 0; i < 4; i++)
            af[i] = *reinterpret_cast<const s16x8*>(&As[buf][(wm + i * 16 + l16) * BK + quad * 8]);
#pragma unroll
        for (int j = 0; j < 4; j++)
            bfr[j] = *reinterpret_cast<const s16x8*>(&Bs[buf][(wn + j * 16 + l16) * BK + quad * 8]);
#pragma unroll
        for (int i = 0; i < 4; i++)
#pragma unroll
            for (int j = 0; j < 4; j++)
                acc[i][j] = __builtin_amdgcn_mfma_f32_16x16x32_bf16(af[i], bfr[j], acc[i][j], 0, 0, 0);
    };

    const int nsteps = K / BK;
    stage(0, 0);
    stage(1, BK);
    int t = 0;
    for (; t < nsteps - 1; t++) {
        asm volatile("s_waitcnt vmcnt(4)" ::: "memory");
        asm volatile("s_barrier" ::: "memory");
        if (t + 2 < nsteps) stage((t + 2) % 3, (t + 2) * BK);
        compute(t % 3);
    }
    asm volatile("s_waitcnt vmcnt(0)" ::: "memory");
    asm volatile("s_barrier" ::: "memory");
    compute(t % 3);

#pragma unroll
    for (int i = 0; i < 4; i++) {
        const int mb = m0 + wm + i * 16 + quad * 4;
#pragma unroll
        for (int j = 0; j < 4; j++) {
            const int n = n0 + wn + j * 16 + l16;
            if (EPI == 0) {
                u16* O = (u16*)Ogv + (long)b * sO;
#pragma unroll
                for (int r = 0; r < 4; r++) {
                    float vv = acc[i][j][r] * scale;
                    if (bias) vv += bias[mb + r];
                    O[(long)(mb + r) * ldo + n] = f2bf(vv);
                }
            } else if (EPI == 1) {
                u16* O = (u16*)Ogv + (long)b * sO;
                ushort4 pk;
                pk.x = f2bf(acc[i][j][0] + bias[mb + 0]);
                pk.y = f2bf(acc[i][j][1] + bias[mb + 1]);
                pk.z = f2bf(acc[i][j][2] + bias[mb + 2]);
                pk.w = f2bf(acc[i][j][3] + bias[mb + 3]);
                *reinterpret_cast<ushort4*>(&O[(long)n * ldo + mb]) = pk;
            } else {
                float* O = (float*)Ogv + (long)b * sO;
                const float* X = Xg + (long)b * sX;
                const float bn = bias[n];
                const float4 xv = *reinterpret_cast<const float4*>(&X[(long)n * ldo + mb]);
                float4 pk;
                pk.x = acc[i][j][0] + bn + xv.x;
                pk.y = acc[i][j][1] + bn + xv.y;
                pk.z = acc[i][j][2] + bn + xv.z;
                pk.w = acc[i][j][3] + bn + xv.w;
                *reinterpret_cast<float4*>(&O[(long)n * ldo + mb]) = pk;
            }
        }
    }
}

// ===================== merged QKV GEMM, XCD-swizzled, 3-deep counted-vmcnt =====================
__global__ __launch_bounds__(256) void qkv_a(const u16* __restrict__ wb3,
                                             const u16* __restrict__ hnT,
                                             const float* __restrict__ bq,
                                             const float* __restrict__ bk,
                                             const float* __restrict__ bv,
                                             u16* __restrict__ qT, u16* __restrict__ kT,
                                             u16* __restrict__ vv) {
    const long HC = 1048576;
    const int b = blockIdx.z;
    const int xcd = blockIdx.x & 7, s = blockIdx.x >> 3;   // s in [0,24)
    const int hi = (s >= 12) ? 1 : 0;
    const int yy = s - hi * 12;                            // [0,12)
    const int x = xcd + 8 * hi;                            // n-tile [0,16)
    const int which = yy >> 2;                             // 0=q 1=k 2=v
    const int my = yy & 3;                                 // m-tile [0,4)
    const u16* Ag = wb3 + which * 262144;
    const u16* Bg = hnT + (long)b * HC;
    const int m0 = my * BM;
    const int n0 = x * BN;

    __shared__ __align__(16) u16 As[3][BM * BK];
    __shared__ __align__(16) u16 Bs[3][BN * BK];

    const int tid = threadIdx.x;
    const int wave = tid >> 6;
    const int lane = tid & 63;
    const int quad = lane >> 4;
    const int l16 = lane & 15;
    const int wm = (wave >> 1) * 64;
    const int wn = (wave & 1) * 64;
    const int rl = lane >> 2;
    const int cl = (lane & 3) * 8;

    f32x4 acc[4][4];
#pragma unroll
    for (int i = 0; i < 4; i++)
#pragma unroll
        for (int j = 0; j < 4; j++) acc[i][j] = f32x4{0.f, 0.f, 0.f, 0.f};

    auto stage = [&](int buf, int k0) {      // 4 global_load_lds per wave
#pragma unroll
        for (int j = 0; j < 2; j++) {
            const int rbase = wave * 32 + j * 16;
            async_cp16(Ag + (long)(m0 + rbase + rl) * 512 + k0 + cl, &As[buf][rbase * BK]);
            async_cp16(Bg + (long)(n0 + rbase + rl) * 512 + k0 + cl, &Bs[buf][rbase * BK]);
        }
    };
    auto compute = [&](int buf) {
        s16x8 af[4], bfr[4];
#pragma unroll
        for (int i = 0; i < 4; i++)
            af[i] = *reinterpret_cast<const s16x8*>(&As[buf][(wm + i * 16 + l16) * BK + quad * 8]);
#pragma unroll
        for (int j = 0; j < 4; j++)
            bfr[j] = *reinterpret_cast<const s16x8*>(&Bs[buf][(wn + j * 16 + l16) * BK + quad * 8]);
#pragma unroll
        for (int i = 0; i < 4; i++)
#pragma unroll
            for (int j = 0; j < 4; j++)
                acc[i][j] = __builtin_amdgcn_mfma_f32_16x16x32_bf16(af[i], bfr[j], acc[i][j], 0, 0, 0);
    };

    const int nsteps = 512 / BK;   // 16
    stage(0, 0);
    stage(1, BK);
    int t = 0;
    for (; t < nsteps - 1; t++) {
        asm volatile("s_waitcnt vmcnt(4)" ::: "memory");
        asm volatile("s_barrier" ::: "memory");
        if (t + 2 < nsteps) stage((t + 2) % 3, (t + 2) * BK);
        compute(t % 3);
    }
    asm volatile("s_waitcnt vmcnt(0)" ::: "memory");
    asm volatile("s_barrier" ::: "memory");
    compute(t % 3);

    if (which == 2) {
        u16* O = vv + (long)b * HC;
#pragma unroll
        for (int i = 0; i < 4; i++) {
            const int mb = m0 + wm + i * 16 + quad * 4;
#pragma unroll
            for (int j = 0; j < 4; j++) {
                const int n = n0 + wn + j * 16 + l16;
#pragma unroll
                for (int r = 0; r < 4; r++)
                    O[(long)(mb + r) * 2048 + n] = f2bf(acc[i][j][r] + bv[mb + r]);
            }
        }
    } else {
        const float* bias = which ? bk : bq;
        u16* O = (which ? kT : qT) + (long)b * HC;
#pragma unroll
        for (int i = 0; i < 4; i++) {
            const int mb = m0 + wm + i * 16 + quad * 4;
#pragma unroll
            for (int j = 0; j < 4; j++) {
                const int n = n0 + wn + j * 16 + l16;
                ushort4 pk;
                pk.x = f2bf(acc[i][j][0] + bias[mb + 0]);
                pk.y = f2bf(acc[i][j][1] + bias[mb + 1]);
                pk.z = f2bf(acc[i][j][2] + bias[mb + 2]);
                pk.w = f2bf(acc[i][j][3] + bias[mb + 3]);
                *reinterpret_cast<ushort4*>(&O[(long)n * 512 + mb]) = pk;
            }
        }
    }
}

// ===================== legacy padded GEMM (fallback tiers, fp32-capable) =====================
template <int F32>
__device__ __forceinline__ void stage_tile(const char* G, int ld, int r0, int k0,
                                           u16* __restrict__ lds, int tid) {
    if (F32) {
        const float* g = (const float*)G;
#pragma unroll
        for (int s = 0; s < 4; s++) {
            const int c = tid + s * 256;
            const int row = c >> 3, col = (c & 7) * 4;
            const float4 v = *reinterpret_cast<const float4*>(g + (long)(r0 + row) * ld + k0 + col);
            ushort4 pk;
            pk.x = f2bf(v.x); pk.y = f2bf(v.y); pk.z = f2bf(v.z); pk.w = f2bf(v.w);
            *reinterpret_cast<ushort4*>(&lds[row * KPAD + col]) = pk;
        }
    } else {
        const u16* g = (const u16*)G;
#pragma unroll
        for (int s = 0; s < 2; s++) {
            const int c = tid + s * 256;
            const int row = c >> 2, col = (c & 3) * 8;
            const uint4 v = *reinterpret_cast<const uint4*>(g + (long)(r0 + row) * ld + k0 + col);
            *reinterpret_cast<uint4*>(&lds[row * KPAD + col]) = v;
        }
    }
}

template <int EPI, int AF32, int BF32>
__global__ __launch_bounds__(256) void gemm_tn(const void* __restrict__ Agv, long sA,
                                               const void* __restrict__ Bgv, long sB,
                                               const float* __restrict__ bias,
                                               const float* __restrict__ Xg, long sX,
                                               void* __restrict__ Ogv, long sO,
                                               int K, int lda, int ldb, int ldo,
                                               float scale) {
    const int b = blockIdx.z;
    const char* A8 = (const char*)Agv + (long)b * sA * (AF32 ? 4 : 2);
    const char* B8 = (const char*)Bgv + (long)b * sB * (BF32 ? 4 : 2);
    const int m0 = blockIdx.y * BM;
    const int n0 = blockIdx.x * BN;

    __shared__ __align__(16) u16 As[BM * KPAD];
    __shared__ __align__(16) u16 Bs[BN * KPAD];

    const int tid = threadIdx.x;
    const int wave = tid >> 6;
    const int lane = tid & 63;
    const int quad = lane >> 4;
    const int l16 = lane & 15;
    const int wm = (wave >> 1) * 64;
    const int wn = (wave & 1) * 64;

    f32x4 acc[4][4];
#pragma unroll
    for (int i = 0; i < 4; i++)
#pragma unroll
        for (int j = 0; j < 4; j++) acc[i][j] = f32x4{0.f, 0.f, 0.f, 0.f};

    for (int k0 = 0; k0 < K; k0 += BK) {
        __syncthreads();
        stage_tile<AF32>(A8, lda, m0, k0, As, tid);
        stage_tile<BF32>(B8, ldb, n0, k0, Bs, tid);
        __syncthreads();
        s16x8 af[4], bfr[4];
#pragma unroll
        for (int i = 0; i < 4; i++)
            af[i] = *reinterpret_cast<const s16x8*>(&As[(wm + i * 16 + l16) * KPAD + quad * 8]);
#pragma unroll
        for (int j = 0; j < 4; j++)
            bfr[j] = *reinterpret_cast<const s16x8*>(&Bs[(wn + j * 16 + l16) * KPAD + quad * 8]);
#pragma unroll
        for (int i = 0; i < 4; i++)
#pragma unroll
            for (int j = 0; j < 4; j++)
                acc[i][j] = __builtin_amdgcn_mfma_f32_16x16x32_bf16(af[i], bfr[j], acc[i][j], 0, 0, 0);
    }

#pragma unroll
    for (int i = 0; i < 4; i++) {
        const int mb = m0 + wm + i * 16 + quad * 4;
#pragma unroll
        for (int j = 0; j < 4; j++) {
            const int n = n0 + wn + j * 16 + l16;
            if (EPI == 0) {
                u16* O = (u16*)Ogv + (long)b * sO;
#pragma unroll
                for (int r = 0; r < 4; r++) {
                    float vv = acc[i][j][r] * scale;
                    if (bias) vv += bias[mb + r];
                    O[(long)(mb + r) * ldo + n] = f2bf(vv);
                }
            } else if (EPI == 1) {
                u16* O = (u16*)Ogv + (long)b * sO;
                ushort4 pk;
                pk.x = f2bf(acc[i][j][0] + bias[mb + 0]);
                pk.y = f2bf(acc[i][j][1] + bias[mb + 1]);
                pk.z = f2bf(acc[i][j][2] + bias[mb + 2]);
                pk.w = f2bf(acc[i][j][3] + bias[mb + 3]);
                *reinterpret_cast<ushort4*>(&O[(long)n * ldo + mb]) = pk;
            } else {
                float* O = (float*)Ogv + (long)b * sO;
                const float* X = Xg + (long)b * sX;
                const float bn = bias[n];
                const float4 xv = *reinterpret_cast<const float4*>(&X[(long)n * ldo + mb]);
                float4 pk;
                pk.x = acc[i][j][0] + bn + xv.x;
                pk.y = acc[i][j][1] + bn + xv.y;
                pk.z = acc[i][j][2] + bn + xv.z;
                pk.w = acc[i][j][3] + bn + xv.w;
                *reinterpret_cast<float4*>(&O[(long)n * ldo + mb]) = pk;
            }
        }
    }
}

extern "C" void kernel_launch(void* const* d_in, const int* in_sizes, int n_in,
                              void* d_out, int out_size, void* d_ws, size_t ws_size,
                              hipStream_t stream) {
    const float* x     = (const float*)d_in[0];
    const float* gamma = (const float*)d_in[1];
    const float* beta  = (const float*)d_in[2];
    const float* wq    = (const float*)d_in[3];
    const float* bq    = (const float*)d_in[4];
    const float* wk    = (const float*)d_in[5];
    const float* bk    = (const float*)d_in[6];
    const float* wv    = (const float*)d_in[7];
    const float* bv    = (const float*)d_in[8];
    const float* wp    = (const float*)d_in[9];
    const float* bp    = (const float*)d_in[10];
    float* out = (float*)d_out;

    const long HC = (long)2048 * 512;
    const long HH = (long)2048 * 2048;
    const long WSZ = 512 * 512;
    const float scl = 0.044194173824159216f;   // 1/sqrt(512)

    char* ws = (char*)d_ws;
    float* meanb = (float*)ws;
    float* rstdb = (float*)(ws + 1024);
    u16* base = (u16*)(ws + 4096);

    const size_t FULL_NEED   = 4096 + 2 * (size_t)(24 * HC + 8 * HH);     // 117,444,608
    const size_t MED_NEED    = 4096 + 2 * (size_t)(32 * HC + HH);         //  75,501,568
    const size_t SMALL_NEED  = 4096 + 2 * (size_t)(4 * HC + HH);          //  16,781,312
    const size_t CHUNK512    = 4096 + 2 * (size_t)(4 * HC + 512 * 2048);  //  10,489,856

    gn_stats<<<256, 256, 0, stream>>>(x, meanb, rstdb);

    if (ws_size >= FULL_NEED) {
        // ---- FULL: all-batched; S-GEMM on the 256^2 4-phase template ----
        u16* qT  = base;                       // [B,H,C]
        u16* kT  = qT + 8 * HC;                // [B,H,C]
        u16* vv  = kT + 8 * HC;                // [B,C,H]
        u16* Sb  = vv + 8 * HC;                // [B,H,H]
        u16* hnT = Sb;                         // overlay: dead before S written
        u16* wb3 = Sb + 8 * HH - 3 * WSZ;      // overlay: wq|wk|wv bf16, dead after QKV
        u16* hT  = qT;                         // overlay: qT dead after S-GEMM
        u16* wpb = vv;                         // overlay: vv dead after PV

        w2bf<<<dim3(256, 3), 256, 0, stream>>>(wq, wk, wv, wb3);
        gn_apply_t<<<dim3(32, 8, 8), 256, 0, stream>>>(x, gamma, beta, meanb, rstdb, hnT);
        qkv_a<<<dim3(192, 1, 8), 256, 0, stream>>>(wb3, hnT, bq, bk, bv, qT, kT, vv);
        gemm256_s<<<dim3(512), 512, 0, stream>>>(qT, HC, kT, HC, Sb, HH,
                                                 512, 512, 512, 2048, scl);
        softmax_rows<<<16384, 256, 0, stream>>>(Sb);
        gemm_tn_a<0, 1><<<dim3(64, 1, 8), 256, 0, stream>>>(Sb, HH, vv, HC, nullptr, nullptr, 0,
                                                            hT, HC, 2048, 2048, 2048, 512, 1.f);
        w2bf<<<dim3(256, 1), 256, 0, stream>>>(wp, wp, wp, wpb);
        gemm_tn_a<2, 1><<<dim3(64, 1, 8), 256, 0, stream>>>(hT, HC, wpb, 0, bp, x, HC,
                                                            out, HC, 512, 512, 512, 2048, 1.f);
    } else if (ws_size >= MED_NEED) {
        u16* hnT = base;
        u16* qT  = hnT + 8 * HC;
        u16* kT  = qT + 8 * HC;
        u16* vv  = kT + 8 * HC;
        u16* Sb  = vv + 8 * HC;
        u16* hT  = hnT;
        gn_apply_t<<<dim3(32, 8, 8), 256, 0, stream>>>(x, gamma, beta, meanb, rstdb, hnT);
        gemm_tn<1, 1, 0><<<dim3(16, 4, 8), 256, 0, stream>>>(wq, 0, hnT, HC, bq, nullptr, 0,
                                                             qT, HC, 512, 512, 512, 512, 1.f);
        gemm_tn<1, 1, 0><<<dim3(16, 4, 8), 256, 0, stream>>>(wk, 0, hnT, HC, bk, nullptr, 0,
                                                             kT, HC, 512, 512, 512, 512, 1.f);
        gemm_tn<0, 1, 0><<<dim3(16, 4, 8), 256, 0, stream>>>(wv, 0, hnT, HC, bv, nullptr, 0,
                                                             vv, HC, 512, 512, 512, 2048, 1.f);
        for (int b = 0; b < 8; b++) {
            gemm_tn<0, 0, 0><<<dim3(16, 16, 1), 256, 0, stream>>>(qT + b * HC, 0, kT + b * HC, 0,
                                                                  nullptr, nullptr, 0, Sb, 0,
                                                                  512, 512, 512, 2048, scl);
            softmax_rows<<<2048, 256, 0, stream>>>(Sb);
            gemm_tn<0, 0, 0><<<dim3(4, 16, 1), 256, 0, stream>>>(Sb, 0, vv + b * HC, 0,
                                                                 nullptr, nullptr, 0, hT + b * HC, 0,
                                                                 2048, 2048, 2048, 512, 1.f);
        }
        gemm_tn<2, 0, 1><<<dim3(4, 16, 8), 256, 0, stream>>>(hT, HC, wp, 0, bp, x, HC,
                                                             out, HC, 512, 512, 512, 2048, 1.f);
    } else {
        const int CH = (ws_size >= SMALL_NEED) ? 2048 : ((ws_size >= CHUNK512) ? 512 : 128);
        u16* hn = base;
        u16* q  = hn + HC;
        u16* k  = q + HC;
        u16* v  = k + HC;
        u16* Sc = v + HC;
        u16* hT = hn;
        for (int b = 0; b < 8; b++) {
            const float* xb = x + (long)b * HC;
            gn_apply_t<<<dim3(32, 8, 1), 256, 0, stream>>>(xb, gamma, beta,
                                                           meanb + b * 32, rstdb + b * 32, hn);
            gemm_tn<1, 1, 0><<<dim3(16, 4, 1), 256, 0, stream>>>(wq, 0, hn, 0, bq, nullptr, 0,
                                                                 q, 0, 512, 512, 512, 512, 1.f);
            gemm_tn<1, 1, 0><<<dim3(16, 4, 1), 256, 0, stream>>>(wk, 0, hn, 0, bk, nullptr, 0,
                                                                 k, 0, 512, 512, 512, 512, 1.f);
            gemm_tn<0, 1, 0><<<dim3(16, 4, 1), 256, 0, stream>>>(wv, 0, hn, 0, bv, nullptr, 0,
                                                                 v, 0, 512, 512, 512, 2048, 1.f);
            for (int i0 = 0; i0 < 2048; i0 += CH) {
                gemm_tn<0, 0, 0><<<dim3(16, CH / 128, 1), 256, 0, stream>>>(
                    q + (long)i0 * 512, 0, k, 0, nullptr, nullptr, 0, Sc, 0,
                    512, 512, 512, 2048, scl);
                softmax_rows<<<CH, 256, 0, stream>>>(Sc);
                gemm_tn<0, 0, 0><<<dim3(4, CH / 128, 1), 256, 0, stream>>>(
                    Sc, 0, v, 0, nullptr, nullptr, 0, hT + (long)i0 * 512, 0,
                    2048, 2048, 2048, 512, 1.f);
            }
            gemm_tn<2, 0, 1><<<dim3(4, 16, 1), 256, 0, stream>>>(hT, 0, wp, 0, bp, xb, 0,
                                                                 out + (long)b * HC, 0,
                                                                 512, 512, 512, 2048, 1.f);
        }
    }
}

// Round 6
// 291.647 us; speedup vs baseline: 1.0955x; 1.0360x over previous
//
#include <hip/hip_runtime.h>
#include <stdint.h>

typedef unsigned short u16;
typedef short s16x8 __attribute__((ext_vector_type(8)));
typedef float f32x4 __attribute__((ext_vector_type(4)));

#define BM 128
#define BN 128
#define BK 32
#define KPAD 40   // padded LDS row stride for the legacy (non-async) kernel

#define WAITV(n) asm volatile("s_waitcnt vmcnt(" #n ")" ::: "memory")
#define BARR()   asm volatile("s_barrier" ::: "memory")
#define SB0()    __builtin_amdgcn_sched_barrier(0)

__device__ __forceinline__ float bf2f(u16 b) {
    union { unsigned int u; float f; } v; v.u = ((unsigned int)b) << 16; return v.f;
}
__device__ __forceinline__ u16 f2bf(float f) {
    union { float f; unsigned int u; } v; v.f = f;
    unsigned int u = v.u;
    u += 0x7fffu + ((u >> 16) & 1u);   // RNE
    return (u16)(u >> 16);
}
__device__ __forceinline__ void async_cp16(const u16* g, u16* l) {
    // global -> LDS direct copy, 16 B per lane; LDS dest = wave-uniform base + lane*16
    __builtin_amdgcn_global_load_lds((const __attribute__((address_space(1))) void*)g,
                                     (__attribute__((address_space(3))) void*)l, 16, 0, 0);
}

// ---------------- GroupNorm statistics: one block per (b,g), fp32 input ----------------
__global__ __launch_bounds__(256) void gn_stats(const float* __restrict__ x,
                                                float* __restrict__ mean,
                                                float* __restrict__ rstd) {
    const int bg = blockIdx.x;
    const float* p = x + (long)bg * 16 * 2048;     // 32768 fp32 per group
    float s = 0.f, ss = 0.f;
    for (int it = 0; it < 32; it++) {
        const float4 v = *reinterpret_cast<const float4*>(p + ((it * 256 + threadIdx.x) << 2));
        s += v.x + v.y + v.z + v.w;
        ss += v.x * v.x + v.y * v.y + v.z * v.z + v.w * v.w;
    }
    const int lane = threadIdx.x & 63, wave = threadIdx.x >> 6;
#pragma unroll
    for (int o = 32; o > 0; o >>= 1) { s += __shfl_down(s, o, 64); ss += __shfl_down(ss, o, 64); }
    __shared__ float rb[8];
    if (lane == 0) { rb[wave] = s; rb[4 + wave] = ss; }
    __syncthreads();
    if (threadIdx.x == 0) {
        float S = rb[0] + rb[1] + rb[2] + rb[3];
        float SS = rb[4] + rb[5] + rb[6] + rb[7];
        float mu = S * (1.f / 32768.f);
        float var = SS * (1.f / 32768.f) - mu * mu;
        mean[bg] = mu;
        rstd[bg] = rsqrtf(var + 1e-6f);
    }
}

// ---------- GroupNorm apply + transpose: fp32 x -> bf16 hnT[h, c] ----------
__global__ __launch_bounds__(256) void gn_apply_t(const float* __restrict__ x,
                                                  const float* __restrict__ gamma,
                                                  const float* __restrict__ beta,
                                                  const float* __restrict__ mean,
                                                  const float* __restrict__ rstd,
                                                  u16* __restrict__ hnT) {
    const int b = blockIdx.z, c0 = blockIdx.y * 64, h0 = blockIdx.x * 64;
    __shared__ __align__(16) u16 T[64][72];
    const int tid = threadIdx.x;
#pragma unroll
    for (int sidx = 0; sidx < 4; sidx++) {
        int ch = tid + sidx * 256;                 // 1024 float4-chunks
        int cc = ch >> 4, h4 = (ch & 15) * 4;
        int c = c0 + cc;
        float mu = mean[b * 32 + (c >> 4)], rs = rstd[b * 32 + (c >> 4)];
        float ga = gamma[c], be = beta[c];
        const float4 v = *reinterpret_cast<const float4*>(x + ((long)b * 512 + c) * 2048 + h0 + h4);
        ushort4 pk;
        pk.x = f2bf((v.x - mu) * rs * ga + be);
        pk.y = f2bf((v.y - mu) * rs * ga + be);
        pk.z = f2bf((v.z - mu) * rs * ga + be);
        pk.w = f2bf((v.w - mu) * rs * ga + be);
        *reinterpret_cast<ushort4*>(&T[cc][h4]) = pk;
    }
    __syncthreads();
#pragma unroll
    for (int sidx = 0; sidx < 2; sidx++) {
        int ch = tid + sidx * 256;                 // 512 uint4-chunks
        int hh = ch >> 3, c8 = (ch & 7) * 8;
        unsigned int o[4];
#pragma unroll
        for (int i = 0; i < 4; i++) {
            u16 lo = T[c8 + 2 * i][hh];
            u16 hi = T[c8 + 2 * i + 1][hh];
            o[i] = (unsigned int)lo | ((unsigned int)hi << 16);
        }
        *reinterpret_cast<uint4*>(hnT + ((long)b * 2048 + h0 + hh) * 512 + c0 + c8) =
            uint4{o[0], o[1], o[2], o[3]};
    }
}

// ---------------- fp32 -> bf16 weight conversion (512x512 each, y selects src) ----------------
__global__ __launch_bounds__(256) void w2bf(const float* __restrict__ a,
                                            const float* __restrict__ b,
                                            const float* __restrict__ c,
                                            u16* __restrict__ dst) {
    const float* s = (blockIdx.y == 0) ? a : (blockIdx.y == 1) ? b : c;
    const int i = (blockIdx.x * 256 + threadIdx.x) * 4;
    const float4 v = *reinterpret_cast<const float4*>(s + i);
    ushort4 p;
    p.x = f2bf(v.x); p.y = f2bf(v.y); p.z = f2bf(v.z); p.w = f2bf(v.w);
    *reinterpret_cast<ushort4*>(dst + (long)blockIdx.y * 262144 + i) = p;
}

// ------------------ softmax over rows of S[i, :] (bf16) in place ------------------
__global__ __launch_bounds__(256) void softmax_rows(u16* __restrict__ S) {
    u16* p = S + (long)blockIdx.x * 2048;
    const int tid = threadIdx.x;
    uint4 v = *reinterpret_cast<const uint4*>(p + (tid << 3));
    unsigned int w[4] = {v.x, v.y, v.z, v.w};
    float f[8];
#pragma unroll
    for (int i = 0; i < 4; i++) {
        f[2 * i]     = bf2f((u16)(w[i] & 0xffffu));
        f[2 * i + 1] = bf2f((u16)(w[i] >> 16));
    }
    float m = f[0];
#pragma unroll
    for (int i = 1; i < 8; i++) m = fmaxf(m, f[i]);
    const int lane = tid & 63, wave = tid >> 6;
#pragma unroll
    for (int o = 32; o > 0; o >>= 1) m = fmaxf(m, __shfl_down(m, o, 64));
    __shared__ float rb[4];
    __shared__ float bc;
    if (lane == 0) rb[wave] = m;
    __syncthreads();
    if (tid == 0) bc = fmaxf(fmaxf(rb[0], rb[1]), fmaxf(rb[2], rb[3]));
    __syncthreads();
    m = bc;
    float s = 0.f;
#pragma unroll
    for (int i = 0; i < 8; i++) { f[i] = __expf(f[i] - m); s += f[i]; }
#pragma unroll
    for (int o = 32; o > 0; o >>= 1) s += __shfl_down(s, o, 64);
    __syncthreads();
    if (lane == 0) rb[wave] = s;
    __syncthreads();
    if (tid == 0) bc = 1.f / (rb[0] + rb[1] + rb[2] + rb[3]);
    __syncthreads();
    const float inv = bc;
#pragma unroll
    for (int i = 0; i < 4; i++)
        w[i] = (unsigned int)f2bf(f[2 * i] * inv) | ((unsigned int)f2bf(f[2 * i + 1] * inv) << 16);
    *reinterpret_cast<uint4*>(p + (tid << 3)) = uint4{w[0], w[1], w[2], w[3]};
}

// ===================== 256x256-tile 8-wave 4-phase GEMM (S-GEMM) =====================
// (unchanged from r5, harness-verified) — see comments in r5; fixed m0/n0 staging bug.
__global__ __launch_bounds__(512, 1) void gemm256_s(const u16* __restrict__ Ag, long sA,
                                                    const u16* __restrict__ Bg, long sB,
                                                    u16* __restrict__ Og, long sO,
                                                    int K, int lda, int ldb, int ldo,
                                                    float scale) {
    const int bx = blockIdx.x;
    const int b = bx & 7, s = bx >> 3;
    const int ty = s & 7, tx = s >> 3;
    const int m0 = ty * 256, n0 = tx * 256;
    Ag += (long)b * sA;
    Bg += (long)b * sB;
    u16* O = Og + (long)b * sO;

    __shared__ __align__(16) u16 LA[2][2][128 * 64];   // [buf][region mh][row*64+k] 64 KiB
    __shared__ __align__(16) u16 LB[2][2][128 * 64];   // [buf][region nh]           64 KiB

    const int tid = threadIdx.x;
    const int lane = tid & 63, wave = tid >> 6;
    const int wm = wave >> 2, w4 = wave & 3;
    const int l15 = lane & 15, quad = lane >> 4;

    const int qxu   = ((quad << 4) ^ ((lane & 4) << 3)) >> 1;
    const int arow_u = (wm * 64 + l15) * 64;
    const int brow_u = (w4 * 32 + l15) * 64;

    const int l8 = lane >> 3;
    const int lrow0 = wave * 8 + l8;                            // region row, issue 0 (0..63)
    const int sEl = (((lane & 7) ^ ((lane & 32) >> 4)) << 3);   // pre-swizzled col (elements)
    int pA[2], pB[2];
    pA[0] = (m0 + lrow0) * lda + sEl;
    pA[1] = (m0 + 64 + lrow0) * lda + sEl;
    {
        const int gb = (lrow0 >> 5) * 64 + (lrow0 & 31);
        pB[0] = (n0 + gb) * ldb + sEl;
        pB[1] = (n0 + gb + 32) * ldb + sEl;
    }
    const int jA = 128 * lda;
    const int jB = 128 * ldb;

    auto stageA = [&](int buf, int mh, int k0) {
        u16* d = &LA[buf][mh][wave * 512];
        async_cp16(Ag + pA[mh] + k0, d);
        async_cp16(Ag + pA[mh] + jA + k0, d + 4096);
    };
    auto stageB = [&](int buf, int nh, int k0) {
        u16* d = &LB[buf][nh][wave * 512];
        async_cp16(Bg + pB[nh] + k0, d);
        async_cp16(Bg + pB[nh] + jB + k0, d + 4096);
    };

    f32x4 acc[8][4];
#pragma unroll
    for (int i = 0; i < 8; i++)
#pragma unroll
        for (int j = 0; j < 4; j++) acc[i][j] = f32x4{0.f, 0.f, 0.f, 0.f};

    s16x8 fa[4][2], fblo[2][2], fbhi[2][2];

    const int NT = K >> 6;

    stageA(0, 0, 0);
    stageB(0, 0, 0);
    stageB(0, 1, 0);
    stageA(0, 1, 0);
    if (NT > 1) {
        stageA(1, 0, 64);
        stageB(1, 0, 64);
        stageB(1, 1, 64);
    }
    WAITV(8); SB0();
    BARR(); SB0();

    for (int t = 0; t < NT; t++) {
        const int buf = t & 1;
        const int k2 = (t + 2) << 6;
        // phase 1: (mh=0, nh=0)
        {
            const u16* Ar = &LA[buf][0][0];
            const u16* Br = &LB[buf][0][0];
#pragma unroll
            for (int mf = 0; mf < 4; mf++)
#pragma unroll
                for (int ks = 0; ks < 2; ks++)
                    fa[mf][ks] = *reinterpret_cast<const s16x8*>(Ar + arow_u + mf * 1024 + ks * 32 + qxu);
#pragma unroll
            for (int nf = 0; nf < 2; nf++)
#pragma unroll
                for (int ks = 0; ks < 2; ks++)
                    fblo[nf][ks] = *reinterpret_cast<const s16x8*>(Br + brow_u + nf * 1024 + ks * 32 + qxu);
            if (t + 1 < NT) stageA(buf ^ 1, 1, (t + 1) << 6);
            if (t == NT - 1) { WAITV(2); } else { WAITV(8); }
            SB0();
            BARR(); SB0();
            __builtin_amdgcn_s_setprio(1);
#pragma unroll
            for (int mf = 0; mf < 4; mf++)
#pragma unroll
                for (int nf = 0; nf < 2; nf++)
#pragma unroll
                    for (int ks = 0; ks < 2; ks++)
                        acc[mf][nf] = __builtin_amdgcn_mfma_f32_16x16x32_bf16(fa[mf][ks], fblo[nf][ks], acc[mf][nf], 0, 0, 0);
            __builtin_amdgcn_s_setprio(0);
            BARR(); SB0();
        }
        // phase 2: (mh=0, nh=1)
        {
            const u16* Br = &LB[buf][1][0];
#pragma unroll
            for (int nf = 0; nf < 2; nf++)
#pragma unroll
                for (int ks = 0; ks < 2; ks++)
                    fbhi[nf][ks] = *reinterpret_cast<const s16x8*>(Br + brow_u + nf * 1024 + ks * 32 + qxu);
            if (t + 2 < NT) stageA(buf, 0, k2);
            if (t == NT - 1) { WAITV(0); } else { WAITV(8); }
            SB0();
            BARR(); SB0();
            __builtin_amdgcn_s_setprio(1);
#pragma unroll
            for (int mf = 0; mf < 4; mf++)
#pragma unroll
                for (int nf = 0; nf < 2; nf++)
#pragma unroll
                    for (int ks = 0; ks < 2; ks++)
                        acc[mf][2 + nf] = __builtin_amdgcn_mfma_f32_16x16x32_bf16(fa[mf][ks], fbhi[nf][ks], acc[mf][2 + nf], 0, 0, 0);
            __builtin_amdgcn_s_setprio(0);
            BARR(); SB0();
        }
        // phase 3: (mh=1, nh=1)
        {
            const u16* Ar = &LA[buf][1][0];
#pragma unroll
            for (int mf = 0; mf < 4; mf++)
#pragma unroll
                for (int ks = 0; ks < 2; ks++)
                    fa[mf][ks] = *reinterpret_cast<const s16x8*>(Ar + arow_u + mf * 1024 + ks * 32 + qxu);
            if (t + 2 < NT) stageB(buf, 0, k2);
            WAITV(8); SB0();
            BARR(); SB0();
            __builtin_amdgcn_s_setprio(1);
#pragma unroll
            for (int mf = 0; mf < 4; mf++)
#pragma unroll
                for (int nf = 0; nf < 2; nf++)
#pragma unroll
                    for (int ks = 0; ks < 2; ks++)
                        acc[4 + mf][2 + nf] = __builtin_amdgcn_mfma_f32_16x16x32_bf16(fa[mf][ks], fbhi[nf][ks], acc[4 + mf][2 + nf], 0, 0, 0);
            __builtin_amdgcn_s_setprio(0);
            BARR(); SB0();
        }
        // phase 4: (mh=1, nh=0)
        {
            if (t + 2 < NT) stageB(buf, 1, k2);
            if (t == NT - 2) { WAITV(4); } else { WAITV(8); }
            SB0();
            BARR(); SB0();
            __builtin_amdgcn_s_setprio(1);
#pragma unroll
            for (int mf = 0; mf < 4; mf++)
#pragma unroll
                for (int nf = 0; nf < 2; nf++)
#pragma unroll
                    for (int ks = 0; ks < 2; ks++)
                        acc[4 + mf][nf] = __builtin_amdgcn_mfma_f32_16x16x32_bf16(fa[mf][ks], fblo[nf][ks], acc[4 + mf][nf], 0, 0, 0);
            __builtin_amdgcn_s_setprio(0);
            BARR(); SB0();
        }
    }

    const int orow = m0 + wm * 128 + quad * 4;
    const int ocol = n0 + w4 * 64 + l15;
#pragma unroll
    for (int mi = 0; mi < 8; mi++)
#pragma unroll
        for (int ni = 0; ni < 4; ni++) {
            const long rb = (long)(orow + mi * 16) * ldo + ocol + ni * 16;
#pragma unroll
            for (int r = 0; r < 4; r++)
                O[rb + (long)r * ldo] = f2bf(acc[mi][ni][r] * scale);
        }
}

// ===================== 256x128-tile 8-wave 4-phase GEMM (PV: M=2048,N=512,K=2048) =====================
// Geometry: tile 256(M) x 128(N); grid 256 blocks = 8 m-tiles x 4 n-tiles x 8 batches = 1/CU.
// 8 waves in 4(M) x 2(N) grid; per-wave 64x64; acc 4x4 f32x4 (64 VGPR) — no spill risk.
// LDS 96 KiB: LA[2buf][2mh][128rows*64k] (A-lo = rows {wm*64+0..31}, A-hi = +32, region row
// ra = wm*32+r <-> global m0 + wm*64 + (mh?32:0) + r); LB[2buf][2nh][64rows*64k]
// (region row rb = wn*32+r <-> global n0 + wn*64 + (nh?32:0) + r).
// Phases/K-tile: p1 (mh0,nh0): read fa(A-lo)4+fblo4; p2 (mh0,nh1): read fbhi4;
// p3 (mh1,nh1): read fa(A-hi)4; p4 (mh1,nh0): regs only. 8 MFMA each; 1 barrier/phase.
// Stage slots: p1: A-lo(t+1)->buf^1 [2]; p2: A-hi(t+1)->buf^1 [2]; p3: B-lo+B-hi(t+2)->buf [2].
// Ledger (in-order vmcnt retirement, derived + tail-audited):
//   p1: WAITV(4)  (retires A-hi(t), needed by p3's reads; barrier after)    [tail NT-1: 0]
//   p4: WAITV(4)  (retires B(t)... i.e. B(t+1)+A-lo(t+1) for next p1)       [tail NT-2: 2]
//   p2, p3: no wait. Every stage has >=3 phases of latency cover; never drains mid-loop.
// WAR: every stage targets a region whose last read precedes >=1 intervening barrier.
// Swizzle: identical both-sides scheme as gemm256_s (LDS row bit2 <-> 32B flip; staging
// pre-swizzle keyed on lane bit5 = (tid>>3)&4; reads keyed on lane bit2 = l15 bit2).
// Grid swizzle: b = bx&7 (batch per XCD -> vv 2MB L2-resident); 4 n-tiles of one m-strip adjacent.
template <int EPI>
__global__ __launch_bounds__(512, 1) void gemm256_pv(const u16* __restrict__ Ag, long sA,
                                                     const u16* __restrict__ Bg, long sB,
                                                     u16* __restrict__ Og, long sO,
                                                     int K, int lda, int ldb, int ldo,
                                                     float scale) {
    const int bx = blockIdx.x;
    const int b = bx & 7, s = bx >> 3;      // s in [0,32)
    const int mt = s >> 2, nt = s & 3;
    const int m0 = mt * 256, n0 = nt * 128;
    Ag += (long)b * sA;
    Bg += (long)b * sB;
    u16* O = Og + (long)b * sO;

    __shared__ __align__(16) u16 LA[2][2][128 * 64];   // 64 KiB
    __shared__ __align__(16) u16 LB[2][2][64 * 64];    // 32 KiB

    const int tid = threadIdx.x;
    const int lane = tid & 63, wave = tid >> 6;
    const int wm = wave >> 1, wn = wave & 1;           // 4(M) x 2(N)
    const int l15 = lane & 15, quad = lane >> 4;

    const int qxu = ((quad << 4) ^ ((lane & 4) << 3)) >> 1;   // swizzled 16B slot (u16 units)

    // staging: thread covers region row r0 = tid>>3 (64 rows per 8KB issue)
    const int r0 = tid >> 3;
    const int sEl = (((lane & 7) ^ ((lane & 32) >> 4)) << 3);
    const int gA = (r0 >> 5) * 64 + (r0 & 31);         // A region row -> global local-M
    int pA[2], pB[2];
    pA[0] = (m0 + gA) * lda + sEl;                     // A-lo
    pA[1] = (m0 + gA + 32) * lda + sEl;                // A-hi
    pB[0] = (n0 + gA) * ldb + sEl;                     // B-lo (same row pattern)
    pB[1] = (n0 + gA + 32) * ldb + sEl;                // B-hi
    const int jA = 128 * lda;                          // A issue-1 delta (+128 global rows)

    auto stageA = [&](int buf, int mh, int k0) {       // 2 instr (16 KB region)
        u16* d = &LA[buf][mh][wave * 512];
        async_cp16(Ag + pA[mh] + k0, d);
        async_cp16(Ag + pA[mh] + jA + k0, d + 4096);
    };
    auto stageBB = [&](int buf, int k0) {              // 2 instr (both 8 KB B regions)
        async_cp16(Bg + pB[0] + k0, &LB[buf][0][wave * 512]);
        async_cp16(Bg + pB[1] + k0, &LB[buf][1][wave * 512]);
    };

    f32x4 acc[4][4];
#pragma unroll
    for (int i = 0; i < 4; i++)
#pragma unroll
        for (int j = 0; j < 4; j++) acc[i][j] = f32x4{0.f, 0.f, 0.f, 0.f};

    s16x8 fa[2][2], fblo[2][2], fbhi[2][2];

    const int arow_u = (wm * 32 + l15) * 64;           // + mf*16*64
    const int brow_u = (wn * 32 + l15) * 64;           // + nf*16*64

    const int NT = K >> 6;                             // 32 for PV

    // prologue: B(0), A-lo(0), A-hi(0), B(1); retire through A-lo(0) -> WAITV(4)
    stageBB(0, 0);
    stageA(0, 0, 0);
    stageA(0, 1, 0);
    if (NT > 1) stageBB(1, 64);
    WAITV(4); SB0();
    BARR(); SB0();

    for (int t = 0; t < NT; t++) {
        const int buf = t & 1;
        const int k1 = (t + 1) << 6, k2 = (t + 2) << 6;
        // ---- phase 1: (mh=0, nh=0) — reads A-lo(t), B-lo(t)
        {
            const u16* Ar = &LA[buf][0][0];
            const u16* Br = &LB[buf][0][0];
#pragma unroll
            for (int mf = 0; mf < 2; mf++)
#pragma unroll
                for (int ks = 0; ks < 2; ks++)
                    fa[mf][ks] = *reinterpret_cast<const s16x8*>(Ar + arow_u + mf * 1024 + ks * 32 + qxu);
#pragma unroll
            for (int nf = 0; nf < 2; nf++)
#pragma unroll
                for (int ks = 0; ks < 2; ks++)
                    fblo[nf][ks] = *reinterpret_cast<const s16x8*>(Br + brow_u + nf * 1024 + ks * 32 + qxu);
            if (t + 1 < NT) stageA(buf ^ 1, 0, k1);    // A-lo(t+1)
            __builtin_amdgcn_s_setprio(1);
#pragma unroll
            for (int mf = 0; mf < 2; mf++)
#pragma unroll
                for (int nf = 0; nf < 2; nf++)
#pragma unroll
                    for (int ks = 0; ks < 2; ks++)
                        acc[mf][nf] = __builtin_amdgcn_mfma_f32_16x16x32_bf16(fa[mf][ks], fblo[nf][ks], acc[mf][nf], 0, 0, 0);
            __builtin_amdgcn_s_setprio(0);
            if (t == NT - 1) { WAITV(0); } else { WAITV(4); }   // retire A-hi(t) for p3
            SB0();
            BARR(); SB0();
        }
        // ---- phase 2: (mh=0, nh=1) — reads B-hi(t)
        {
            const u16* Br = &LB[buf][1][0];
#pragma unroll
            for (int nf = 0; nf < 2; nf++)
#pragma unroll
                for (int ks = 0; ks < 2; ks++)
                    fbhi[nf][ks] = *reinterpret_cast<const s16x8*>(Br + brow_u + nf * 1024 + ks * 32 + qxu);
            if (t + 1 < NT) stageA(buf ^ 1, 1, k1);    // A-hi(t+1)
            __builtin_amdgcn_s_setprio(1);
#pragma unroll
            for (int mf = 0; mf < 2; mf++)
#pragma unroll
                for (int nf = 0; nf < 2; nf++)
#pragma unroll
                    for (int ks = 0; ks < 2; ks++)
                        acc[mf][2 + nf] = __builtin_amdgcn_mfma_f32_16x16x32_bf16(fa[mf][ks], fbhi[nf][ks], acc[mf][2 + nf], 0, 0, 0);
            __builtin_amdgcn_s_setprio(0);
            BARR(); SB0();
        }
        // ---- phase 3: (mh=1, nh=1) — reads A-hi(t) (retired by p1's WAITV)
        {
            const u16* Ar = &LA[buf][1][0];
#pragma unroll
            for (int mf = 0; mf < 2; mf++)
#pragma unroll
                for (int ks = 0; ks < 2; ks++)
                    fa[mf][ks] = *reinterpret_cast<const s16x8*>(Ar + arow_u + mf * 1024 + ks * 32 + qxu);
            if (t + 2 < NT) stageBB(buf, k2);          // B(t+2) -> same buf (WAR: B(t) last read p2, barrier between)
            __builtin_amdgcn_s_setprio(1);
#pragma unroll
            for (int mf = 0; mf < 2; mf++)
#pragma unroll
                for (int nf = 0; nf < 2; nf++)
#pragma unroll
                    for (int ks = 0; ks < 2; ks++)
                        acc[2 + mf][2 + nf] = __builtin_amdgcn_mfma_f32_16x16x32_bf16(fa[mf][ks], fbhi[nf][ks], acc[2 + mf][2 + nf], 0, 0, 0);
            __builtin_amdgcn_s_setprio(0);
            BARR(); SB0();
        }
        // ---- phase 4: (mh=1, nh=0) — regs only; WAITV retires B(t+1)+A-lo(t+1) for next p1
        {
            __builtin_amdgcn_s_setprio(1);
#pragma unroll
            for (int mf = 0; mf < 2; mf++)
#pragma unroll
                for (int nf = 0; nf < 2; nf++)
#pragma unroll
                    for (int ks = 0; ks < 2; ks++)
                        acc[2 + mf][nf] = __builtin_amdgcn_mfma_f32_16x16x32_bf16(fa[mf][ks], fblo[nf][ks], acc[2 + mf][nf], 0, 0, 0);
            __builtin_amdgcn_s_setprio(0);
            if (t == NT - 2) { WAITV(2); } else if (t < NT - 2) { WAITV(4); }
            SB0();
            BARR(); SB0();
        }
    }

    // epilogue: row = m0 + wm*64 + mi*16 + quad*4 + r; col = n0 + wn*64 + ni*16 + l15
    const int orow = m0 + wm * 64 + quad * 4;
    const int ocol = n0 + wn * 64 + l15;
#pragma unroll
    for (int mi = 0; mi < 4; mi++)
#pragma unroll
        for (int ni = 0; ni < 4; ni++) {
            const long rb = (long)(orow + mi * 16) * ldo + ocol + ni * 16;
#pragma unroll
            for (int r = 0; r < 4; r++)
                O[rb + (long)r * ldo] = f2bf(acc[mi][ni][r] * scale);
        }
}

// ===================== ASYNC 3-deep counted-vmcnt MFMA GEMM (bf16 operands) =====================
template <int EPI, int SWIZ>
__global__ __launch_bounds__(256) void gemm_tn_a(const u16* __restrict__ Ag, long sA,
                                                 const u16* __restrict__ Bg, long sB,
                                                 const float* __restrict__ bias,
                                                 const float* __restrict__ Xg, long sX,
                                                 void* __restrict__ Ogv, long sO,
                                                 int K, int lda, int ldb, int ldo,
                                                 float scale) {
    const int b = blockIdx.z;
    Ag += (long)b * sA;
    Bg += (long)b * sB;
    int tx, ty;
    if (SWIZ == 1) {
        const int xcd = blockIdx.x & 7, s = blockIdx.x >> 3;
        ty = xcd + 8 * (s >> 2);
        tx = s & 3;
    } else if (SWIZ == 2) {
        const int xcd = blockIdx.x & 7, s = blockIdx.x >> 3;
        ty = (xcd & 3) * 4 + (s & 3);
        tx = (xcd >> 2) * 8 + (s >> 2);
    } else {
        tx = blockIdx.x; ty = blockIdx.y;
    }
    const int m0 = ty * BM;
    const int n0 = tx * BN;

    __shared__ __align__(16) u16 As[3][BM * BK];
    __shared__ __align__(16) u16 Bs[3][BN * BK];

    const int tid = threadIdx.x;
    const int wave = tid >> 6;
    const int lane = tid & 63;
    const int quad = lane >> 4;
    const int l16 = lane & 15;
    const int wm = (wave >> 1) * 64;
    const int wn = (wave & 1) * 64;
    const int rl = lane >> 2;
    const int cl = (lane & 3) * 8;

    f32x4 acc[4][4];
#pragma unroll
    for (int i = 0; i < 4; i++)
#pragma unroll
        for (int j = 0; j < 4; j++) acc[i][j] = f32x4{0.f, 0.f, 0.f, 0.f};

    auto stage = [&](int buf, int k0) {
#pragma unroll
        for (int j = 0; j < 2; j++) {
            const int rbase = wave * 32 + j * 16;
            async_cp16(Ag + (long)(m0 + rbase + rl) * lda + k0 + cl, &As[buf][rbase * BK]);
            async_cp16(Bg + (long)(n0 + rbase + rl) * ldb + k0 + cl, &Bs[buf][rbase * BK]);
        }
    };
    auto compute = [&](int buf) {
        s16x8 af[4], bfr[4];
#pragma unroll
        for (int i = 0; i < 4; i++)
            af[i] = *reinterpret_cast<const s16x8*>(&As[buf][(wm + i * 16 + l16) * BK + quad * 8]);
#pragma unroll
        for (int j = 0; j < 4; j++)
            bfr[j] = *reinterpret_cast<const s16x8*>(&Bs[buf][(wn + j * 16 + l16) * BK + quad * 8]);
#pragma unroll
        for (int i = 0; i < 4; i++)
#pragma unroll
            for (int j = 0; j < 4; j++)
                acc[i][j] = __builtin_amdgcn_mfma_f32_16x16x32_bf16(af[i], bfr[j], acc[i][j], 0, 0, 0);
    };

    const int nsteps = K / BK;
    stage(0, 0);
    stage(1, BK);
    int t = 0;
    for (; t < nsteps - 1; t++) {
        asm volatile("s_waitcnt vmcnt(4)" ::: "memory");
        asm volatile("s_barrier" ::: "memory");
        if (t + 2 < nsteps) stage((t + 2) % 3, (t + 2) * BK);
        compute(t % 3);
    }
    asm volatile("s_waitcnt vmcnt(0)" ::: "memory");
    asm volatile("s_barrier" ::: "memory");
    compute(t % 3);

#pragma unroll
    for (int i = 0; i < 4; i++) {
        const int mb = m0 + wm + i * 16 + quad * 4;
#pragma unroll
        for (int j = 0; j < 4; j++) {
            const int n = n0 + wn + j * 16 + l16;
            if (EPI == 0) {
                u16* O = (u16*)Ogv + (long)b * sO;
#pragma unroll
                for (int r = 0; r < 4; r++) {
                    float vv = acc[i][j][r] * scale;
                    if (bias) vv += bias[mb + r];
                    O[(long)(mb + r) * ldo + n] = f2bf(vv);
                }
            } else if (EPI == 1) {
                u16* O = (u16*)Ogv + (long)b * sO;
                ushort4 pk;
                pk.x = f2bf(acc[i][j][0] + bias[mb + 0]);
                pk.y = f2bf(acc[i][j][1] + bias[mb + 1]);
                pk.z = f2bf(acc[i][j][2] + bias[mb + 2]);
                pk.w = f2bf(acc[i][j][3] + bias[mb + 3]);
                *reinterpret_cast<ushort4*>(&O[(long)n * ldo + mb]) = pk;
            } else {
                float* O = (float*)Ogv + (long)b * sO;
                const float* X = Xg + (long)b * sX;
                const float bn = bias[n];
                const float4 xv = *reinterpret_cast<const float4*>(&X[(long)n * ldo + mb]);
                float4 pk;
                pk.x = acc[i][j][0] + bn + xv.x;
                pk.y = acc[i][j][1] + bn + xv.y;
                pk.z = acc[i][j][2] + bn + xv.z;
                pk.w = acc[i][j][3] + bn + xv.w;
                *reinterpret_cast<float4*>(&O[(long)n * ldo + mb]) = pk;
            }
        }
    }
}

// ===================== merged QKV GEMM, XCD-swizzled, 3-deep counted-vmcnt =====================
__global__ __launch_bounds__(256) void qkv_a(const u16* __restrict__ wb3,
                                             const u16* __restrict__ hnT,
                                             const float* __restrict__ bq,
                                             const float* __restrict__ bk,
                                             const float* __restrict__ bv,
                                             u16* __restrict__ qT, u16* __restrict__ kT,
                                             u16* __restrict__ vv) {
    const long HC = 1048576;
    const int b = blockIdx.z;
    const int xcd = blockIdx.x & 7, s = blockIdx.x >> 3;   // s in [0,24)
    const int hi = (s >= 12) ? 1 : 0;
    const int yy = s - hi * 12;                            // [0,12)
    const int x = xcd + 8 * hi;                            // n-tile [0,16)
    const int which = yy >> 2;                             // 0=q 1=k 2=v
    const int my = yy & 3;                                 // m-tile [0,4)
    const u16* Ag = wb3 + which * 262144;
    const u16* Bg = hnT + (long)b * HC;
    const int m0 = my * BM;
    const int n0 = x * BN;

    __shared__ __align__(16) u16 As[3][BM * BK];
    __shared__ __align__(16) u16 Bs[3][BN * BK];

    const int tid = threadIdx.x;
    const int wave = tid >> 6;
    const int lane = tid & 63;
    const int quad = lane >> 4;
    const int l16 = lane & 15;
    const int wm = (wave >> 1) * 64;
    const int wn = (wave & 1) * 64;
    const int rl = lane >> 2;
    const int cl = (lane & 3) * 8;

    f32x4 acc[4][4];
#pragma unroll
    for (int i = 0; i < 4; i++)
#pragma unroll
        for (int j = 0; j < 4; j++) acc[i][j] = f32x4{0.f, 0.f, 0.f, 0.f};

    auto stage = [&](int buf, int k0) {
#pragma unroll
        for (int j = 0; j < 2; j++) {
            const int rbase = wave * 32 + j * 16;
            async_cp16(Ag + (long)(m0 + rbase + rl) * 512 + k0 + cl, &As[buf][rbase * BK]);
            async_cp16(Bg + (long)(n0 + rbase + rl) * 512 + k0 + cl, &Bs[buf][rbase * BK]);
        }
    };
    auto compute = [&](int buf) {
        s16x8 af[4], bfr[4];
#pragma unroll
        for (int i = 0; i < 4; i++)
            af[i] = *reinterpret_cast<const s16x8*>(&As[buf][(wm + i * 16 + l16) * BK + quad * 8]);
#pragma unroll
        for (int j = 0; j < 4; j++)
            bfr[j] = *reinterpret_cast<const s16x8*>(&Bs[buf][(wn + j * 16 + l16) * BK + quad * 8]);
#pragma unroll
        for (int i = 0; i < 4; i++)
#pragma unroll
            for (int j = 0; j < 4; j++)
                acc[i][j] = __builtin_amdgcn_mfma_f32_16x16x32_bf16(af[i], bfr[j], acc[i][j], 0, 0, 0);
    };

    const int nsteps = 512 / BK;   // 16
    stage(0, 0);
    stage(1, BK);
    int t = 0;
    for (; t < nsteps - 1; t++) {
        asm volatile("s_waitcnt vmcnt(4)" ::: "memory");
        asm volatile("s_barrier" ::: "memory");
        if (t + 2 < nsteps) stage((t + 2) % 3, (t + 2) * BK);
        compute(t % 3);
    }
    asm volatile("s_waitcnt vmcnt(0)" ::: "memory");
    asm volatile("s_barrier" ::: "memory");
    compute(t % 3);

    if (which == 2) {
        u16* O = vv + (long)b * HC;
#pragma unroll
        for (int i = 0; i < 4; i++) {
            const int mb = m0 + wm + i * 16 + quad * 4;
#pragma unroll
            for (int j = 0; j < 4; j++) {
                const int n = n0 + wn + j * 16 + l16;
#pragma unroll
                for (int r = 0; r < 4; r++)
                    O[(long)(mb + r) * 2048 + n] = f2bf(acc[i][j][r] + bv[mb + r]);
            }
        }
    } else {
        const float* bias = which ? bk : bq;
        u16* O = (which ? kT : qT) + (long)b * HC;
#pragma unroll
        for (int i = 0; i < 4; i++) {
            const int mb = m0 + wm + i * 16 + quad * 4;
#pragma unroll
            for (int j = 0; j < 4; j++) {
                const int n = n0 + wn + j * 16 + l16;
                ushort4 pk;
                pk.x = f2bf(acc[i][j][0] + bias[mb + 0]);
                pk.y = f2bf(acc[i][j][1] + bias[mb + 1]);
                pk.z = f2bf(acc[i][j][2] + bias[mb + 2]);
                pk.w = f2bf(acc[i][j][3] + bias[mb + 3]);
                *reinterpret_cast<ushort4*>(&O[(long)n * 512 + mb]) = pk;
            }
        }
    }
}

// ===================== legacy padded GEMM (fallback tiers, fp32-capable) =====================
template <int F32>
__device__ __forceinline__ void stage_tile(const char* G, int ld, int r0, int k0,
                                           u16* __restrict__ lds, int tid) {
    if (F32) {
        const float* g = (const float*)G;
#pragma unroll
        for (int s = 0; s < 4; s++) {
            const int c = tid + s * 256;
            const int row = c >> 3, col = (c & 7) * 4;
            const float4 v = *reinterpret_cast<const float4*>(g + (long)(r0 + row) * ld + k0 + col);
            ushort4 pk;
            pk.x = f2bf(v.x); pk.y = f2bf(v.y); pk.z = f2bf(v.z); pk.w = f2bf(v.w);
            *reinterpret_cast<ushort4*>(&lds[row * KPAD + col]) = pk;
        }
    } else {
        const u16* g = (const u16*)G;
#pragma unroll
        for (int s = 0; s < 2; s++) {
            const int c = tid + s * 256;
            const int row = c >> 2, col = (c & 3) * 8;
            const uint4 v = *reinterpret_cast<const uint4*>(g + (long)(r0 + row) * ld + k0 + col);
            *reinterpret_cast<uint4*>(&lds[row * KPAD + col]) = v;
        }
    }
}

template <int EPI, int AF32, int BF32>
__global__ __launch_bounds__(256) void gemm_tn(const void* __restrict__ Agv, long sA,
                                               const void* __restrict__ Bgv, long sB,
                                               const float* __restrict__ bias,
                                               const float* __restrict__ Xg, long sX,
                                               void* __restrict__ Ogv, long sO,
                                               int K, int lda, int ldb, int ldo,
                                               float scale) {
    const int b = blockIdx.z;
    const char* A8 = (const char*)Agv + (long)b * sA * (AF32 ? 4 : 2);
    const char* B8 = (const char*)Bgv + (long)b * sB * (BF32 ? 4 : 2);
    const int m0 = blockIdx.y * BM;
    const int n0 = blockIdx.x * BN;

    __shared__ __align__(16) u16 As[BM * KPAD];
    __shared__ __align__(16) u16 Bs[BN * KPAD];

    const int tid = threadIdx.x;
    const int wave = tid >> 6;
    const int lane = tid & 63;
    const int quad = lane >> 4;
    const int l16 = lane & 15;
    const int wm = (wave >> 1) * 64;
    const int wn = (wave & 1) * 64;

    f32x4 acc[4][4];
#pragma unroll
    for (int i = 0; i < 4; i++)
#pragma unroll
        for (int j = 0; j < 4; j++) acc[i][j] = f32x4{0.f, 0.f, 0.f, 0.f};

    for (int k0 = 0; k0 < K; k0 += BK) {
        __syncthreads();
        stage_tile<AF32>(A8, lda, m0, k0, As, tid);
        stage_tile<BF32>(B8, ldb, n0, k0, Bs, tid);
        __syncthreads();
        s16x8 af[4], bfr[4];
#pragma unroll
        for (int i = 0; i < 4; i++)
            af[i] = *reinterpret_cast<const s16x8*>(&As[(wm + i * 16 + l16) * KPAD + quad * 8]);
#pragma unroll
        for (int j = 0; j < 4; j++)
            bfr[j] = *reinterpret_cast<const s16x8*>(&Bs[(wn + j * 16 + l16) * KPAD + quad * 8]);
#pragma unroll
        for (int i = 0; i < 4; i++)
#pragma unroll
            for (int j = 0; j < 4; j++)
                acc[i][j] = __builtin_amdgcn_mfma_f32_16x16x32_bf16(af[i], bfr[j], acc[i][j], 0, 0, 0);
    }

#pragma unroll
    for (int i = 0; i < 4; i++) {
        const int mb = m0 + wm + i * 16 + quad * 4;
#pragma unroll
        for (int j = 0; j < 4; j++) {
            const int n = n0 + wn + j * 16 + l16;
            if (EPI == 0) {
                u16* O = (u16*)Ogv + (long)b * sO;
#pragma unroll
                for (int r = 0; r < 4; r++) {
                    float vv = acc[i][j][r] * scale;
                    if (bias) vv += bias[mb + r];
                    O[(long)(mb + r) * ldo + n] = f2bf(vv);
                }
            } else if (EPI == 1) {
                u16* O = (u16*)Ogv + (long)b * sO;
                ushort4 pk;
                pk.x = f2bf(acc[i][j][0] + bias[mb + 0]);
                pk.y = f2bf(acc[i][j][1] + bias[mb + 1]);
                pk.z = f2bf(acc[i][j][2] + bias[mb + 2]);
                pk.w = f2bf(acc[i][j][3] + bias[mb + 3]);
                *reinterpret_cast<ushort4*>(&O[(long)n * ldo + mb]) = pk;
            } else {
                float* O = (float*)Ogv + (long)b * sO;
                const float* X = Xg + (long)b * sX;
                const float bn = bias[n];
                const float4 xv = *reinterpret_cast<const float4*>(&X[(long)n * ldo + mb]);
                float4 pk;
                pk.x = acc[i][j][0] + bn + xv.x;
                pk.y = acc[i][j][1] + bn + xv.y;
                pk.z = acc[i][j][2] + bn + xv.z;
                pk.w = acc[i][j][3] + bn + xv.w;
                *reinterpret_cast<float4*>(&O[(long)n * ldo + mb]) = pk;
            }
        }
    }
}

extern "C" void kernel_launch(void* const* d_in, const int* in_sizes, int n_in,
                              void* d_out, int out_size, void* d_ws, size_t ws_size,
                              hipStream_t stream) {
    const float* x     = (const float*)d_in[0];
    const float* gamma = (const float*)d_in[1];
    const float* beta  = (const float*)d_in[2];
    const float* wq    = (const float*)d_in[3];
    const float* bq    = (const float*)d_in[4];
    const float* wk    = (const float*)d_in[5];
    const float* bk    = (const float*)d_in[6];
    const float* wv    = (const float*)d_in[7];
    const float* bv    = (const float*)d_in[8];
    const float* wp    = (const float*)d_in[9];
    const float* bp    = (const float*)d_in[10];
    float* out = (float*)d_out;

    const long HC = (long)2048 * 512;
    const long HH = (long)2048 * 2048;
    const long WSZ = 512 * 512;
    const float scl = 0.044194173824159216f;   // 1/sqrt(512)

    char* ws = (char*)d_ws;
    float* meanb = (float*)ws;
    float* rstdb = (float*)(ws + 1024);
    u16* base = (u16*)(ws + 4096);

    const size_t FULL_NEED   = 4096 + 2 * (size_t)(24 * HC + 8 * HH);     // 117,444,608
    const size_t MED_NEED    = 4096 + 2 * (size_t)(32 * HC + HH);         //  75,501,568
    const size_t SMALL_NEED  = 4096 + 2 * (size_t)(4 * HC + HH);          //  16,781,312
    const size_t CHUNK512    = 4096 + 2 * (size_t)(4 * HC + 512 * 2048);  //  10,489,856

    gn_stats<<<256, 256, 0, stream>>>(x, meanb, rstdb);

    if (ws_size >= FULL_NEED) {
        // ---- FULL: all-batched; S on 256^2 4-phase; PV on 256x128 4-phase ----
        u16* qT  = base;                       // [B,H,C]
        u16* kT  = qT + 8 * HC;                // [B,H,C]
        u16* vv  = kT + 8 * HC;                // [B,C,H]
        u16* Sb  = vv + 8 * HC;                // [B,H,H]
        u16* hnT = Sb;                         // overlay: dead before S written
        u16* wb3 = Sb + 8 * HH - 3 * WSZ;      // overlay: wq|wk|wv bf16, dead after QKV
        u16* hT  = qT;                         // overlay: qT dead after S-GEMM
        u16* wpb = vv;                         // overlay: vv dead after PV

        w2bf<<<dim3(256, 3), 256, 0, stream>>>(wq, wk, wv, wb3);
        gn_apply_t<<<dim3(32, 8, 8), 256, 0, stream>>>(x, gamma, beta, meanb, rstdb, hnT);
        qkv_a<<<dim3(192, 1, 8), 256, 0, stream>>>(wb3, hnT, bq, bk, bv, qT, kT, vv);
        gemm256_s<<<dim3(512), 512, 0, stream>>>(qT, HC, kT, HC, Sb, HH,
                                                 512, 512, 512, 2048, scl);
        softmax_rows<<<16384, 256, 0, stream>>>(Sb);
        gemm256_pv<0><<<dim3(256), 512, 0, stream>>>(Sb, HH, vv, HC, hT, HC,
                                                     2048, 2048, 2048, 512, 1.f);
        w2bf<<<dim3(256, 1), 256, 0, stream>>>(wp, wp, wp, wpb);
        gemm_tn_a<2, 1><<<dim3(64, 1, 8), 256, 0, stream>>>(hT, HC, wpb, 0, bp, x, HC,
                                                            out, HC, 512, 512, 512, 2048, 1.f);
    } else if (ws_size >= MED_NEED) {
        u16* hnT = base;
        u16* qT  = hnT + 8 * HC;
        u16* kT  = qT + 8 * HC;
        u16* vv  = kT + 8 * HC;
        u16* Sb  = vv + 8 * HC;
        u16* hT  = hnT;
        gn_apply_t<<<dim3(32, 8, 8), 256, 0, stream>>>(x, gamma, beta, meanb, rstdb, hnT);
        gemm_tn<1, 1, 0><<<dim3(16, 4, 8), 256, 0, stream>>>(wq, 0, hnT, HC, bq, nullptr, 0,
                                                             qT, HC, 512, 512, 512, 512, 1.f);
        gemm_tn<1, 1, 0><<<dim3(16, 4, 8), 256, 0, stream>>>(wk, 0, hnT, HC, bk, nullptr, 0,
                                                             kT, HC, 512, 512, 512, 512, 1.f);
        gemm_tn<0, 1, 0><<<dim3(16, 4, 8), 256, 0, stream>>>(wv, 0, hnT, HC, bv, nullptr, 0,
                                                             vv, HC, 512, 512, 512, 2048, 1.f);
        for (int b = 0; b < 8; b++) {
            gemm_tn<0, 0, 0><<<dim3(16, 16, 1), 256, 0, stream>>>(qT + b * HC, 0, kT + b * HC, 0,
                                                                  nullptr, nullptr, 0, Sb, 0,
                                                                  512, 512, 512, 2048, scl);
            softmax_rows<<<2048, 256, 0, stream>>>(Sb);
            gemm_tn<0, 0, 0><<<dim3(4, 16, 1), 256, 0, stream>>>(Sb, 0, vv + b * HC, 0,
                                                                 nullptr, nullptr, 0, hT + b * HC, 0,
                                                                 2048, 2048, 2048, 512, 1.f);
        }
        gemm_tn<2, 0, 1><<<dim3(4, 16, 8), 256, 0, stream>>>(hT, HC, wp, 0, bp, x, HC,
                                                             out, HC, 512, 512, 512, 2048, 1.f);
    } else {
        const int CH = (ws_size >= SMALL_NEED) ? 2048 : ((ws_size >= CHUNK512) ? 512 : 128);
        u16* hn = base;
        u16* q  = hn + HC;
        u16* k  = q + HC;
        u16* v  = k + HC;
        u16* Sc = v + HC;
        u16* hT = hn;
        for (int b = 0; b < 8; b++) {
            const float* xb = x + (long)b * HC;
            gn_apply_t<<<dim3(32, 8, 1), 256, 0, stream>>>(xb, gamma, beta,
                                                           meanb + b * 32, rstdb + b * 32, hn);
            gemm_tn<1, 1, 0><<<dim3(16, 4, 1), 256, 0, stream>>>(wq, 0, hn, 0, bq, nullptr, 0,
                                                                 q, 0, 512, 512, 512, 512, 1.f);
            gemm_tn<1, 1, 0><<<dim3(16, 4, 1), 256, 0, stream>>>(wk, 0, hn, 0, bk, nullptr, 0,
                                                                 k, 0, 512, 512, 512, 512, 1.f);
            gemm_tn<0, 1, 0><<<dim3(16, 4, 1), 256, 0, stream>>>(wv, 0, hn, 0, bv, nullptr, 0,
                                                                 v, 0, 512, 512, 512, 2048, 1.f);
            for (int i0 = 0; i0 < 2048; i0 += CH) {
                gemm_tn<0, 0, 0><<<dim3(16, CH / 128, 1), 256, 0, stream>>>(
                    q + (long)i0 * 512, 0, k, 0, nullptr, nullptr, 0, Sc, 0,
                    512, 512, 512, 2048, scl);
                softmax_rows<<<CH, 256, 0, stream>>>(Sc);
                gemm_tn<0, 0, 0><<<dim3(4, CH / 128, 1), 256, 0, stream>>>(
                    Sc, 0, v, 0, nullptr, nullptr, 0, hT + (long)i0 * 512, 0,
                    2048, 2048, 2048, 512, 1.f);
            }
            gemm_tn<2, 0, 1><<<dim3(4, 16, 1), 256, 0, stream>>>(hT, 0, wp, 0, bp, xb, 0,
                                                                 out + (long)b * HC, 0,
                                                                 512, 512, 512, 2048, 1.f);
        }
    }
}

// Round 7
// 284.673 us; speedup vs baseline: 1.1224x; 1.0245x over previous
//
#include <hip/hip_runtime.h>
#include <stdint.h>

typedef unsigned short u16;
typedef short s16x8 __attribute__((ext_vector_type(8)));
typedef float f32x4 __attribute__((ext_vector_type(4)));

#define BM 128
#define BN 128
#define BK 32
#define KPAD 40   // padded LDS row stride for the legacy (non-async) kernel

#define WAITV(n) asm volatile("s_waitcnt vmcnt(" #n ")" ::: "memory")
#define BARR()   asm volatile("s_barrier" ::: "memory")
#define SB0()    __builtin_amdgcn_sched_barrier(0)

__device__ __forceinline__ float bf2f(u16 b) {
    union { unsigned int u; float f; } v; v.u = ((unsigned int)b) << 16; return v.f;
}
__device__ __forceinline__ u16 f2bf(float f) {
    union { float f; unsigned int u; } v; v.f = f;
    unsigned int u = v.u;
    u += 0x7fffu + ((u >> 16) & 1u);   // RNE
    return (u16)(u >> 16);
}
__device__ __forceinline__ void async_cp16(const u16* g, u16* l) {
    // global -> LDS direct copy, 16 B per lane; LDS dest = wave-uniform base + lane*16
    __builtin_amdgcn_global_load_lds((const __attribute__((address_space(1))) void*)g,
                                     (__attribute__((address_space(3))) void*)l, 16, 0, 0);
}

// ---------------- GroupNorm statistics: one block per (b,g), fp32 input ----------------
__global__ __launch_bounds__(256) void gn_stats(const float* __restrict__ x,
                                                float* __restrict__ mean,
                                                float* __restrict__ rstd) {
    const int bg = blockIdx.x;
    const float* p = x + (long)bg * 16 * 2048;     // 32768 fp32 per group
    float s = 0.f, ss = 0.f;
    for (int it = 0; it < 32; it++) {
        const float4 v = *reinterpret_cast<const float4*>(p + ((it * 256 + threadIdx.x) << 2));
        s += v.x + v.y + v.z + v.w;
        ss += v.x * v.x + v.y * v.y + v.z * v.z + v.w * v.w;
    }
    const int lane = threadIdx.x & 63, wave = threadIdx.x >> 6;
#pragma unroll
    for (int o = 32; o > 0; o >>= 1) { s += __shfl_down(s, o, 64); ss += __shfl_down(ss, o, 64); }
    __shared__ float rb[8];
    if (lane == 0) { rb[wave] = s; rb[4 + wave] = ss; }
    __syncthreads();
    if (threadIdx.x == 0) {
        float S = rb[0] + rb[1] + rb[2] + rb[3];
        float SS = rb[4] + rb[5] + rb[6] + rb[7];
        float mu = S * (1.f / 32768.f);
        float var = SS * (1.f / 32768.f) - mu * mu;
        mean[bg] = mu;
        rstd[bg] = rsqrtf(var + 1e-6f);
    }
}

// ---------- GroupNorm apply + transpose: fp32 x -> bf16 hnT[h, c] ----------
__global__ __launch_bounds__(256) void gn_apply_t(const float* __restrict__ x,
                                                  const float* __restrict__ gamma,
                                                  const float* __restrict__ beta,
                                                  const float* __restrict__ mean,
                                                  const float* __restrict__ rstd,
                                                  u16* __restrict__ hnT) {
    const int b = blockIdx.z, c0 = blockIdx.y * 64, h0 = blockIdx.x * 64;
    __shared__ __align__(16) u16 T[64][72];
    const int tid = threadIdx.x;
#pragma unroll
    for (int sidx = 0; sidx < 4; sidx++) {
        int ch = tid + sidx * 256;                 // 1024 float4-chunks
        int cc = ch >> 4, h4 = (ch & 15) * 4;
        int c = c0 + cc;
        float mu = mean[b * 32 + (c >> 4)], rs = rstd[b * 32 + (c >> 4)];
        float ga = gamma[c], be = beta[c];
        const float4 v = *reinterpret_cast<const float4*>(x + ((long)b * 512 + c) * 2048 + h0 + h4);
        ushort4 pk;
        pk.x = f2bf((v.x - mu) * rs * ga + be);
        pk.y = f2bf((v.y - mu) * rs * ga + be);
        pk.z = f2bf((v.z - mu) * rs * ga + be);
        pk.w = f2bf((v.w - mu) * rs * ga + be);
        *reinterpret_cast<ushort4*>(&T[cc][h4]) = pk;
    }
    __syncthreads();
#pragma unroll
    for (int sidx = 0; sidx < 2; sidx++) {
        int ch = tid + sidx * 256;                 // 512 uint4-chunks
        int hh = ch >> 3, c8 = (ch & 7) * 8;
        unsigned int o[4];
#pragma unroll
        for (int i = 0; i < 4; i++) {
            u16 lo = T[c8 + 2 * i][hh];
            u16 hi = T[c8 + 2 * i + 1][hh];
            o[i] = (unsigned int)lo | ((unsigned int)hi << 16);
        }
        *reinterpret_cast<uint4*>(hnT + ((long)b * 2048 + h0 + hh) * 512 + c0 + c8) =
            uint4{o[0], o[1], o[2], o[3]};
    }
}

// ---------------- fp32 -> bf16 weight conversion (512x512 each, y selects src) ----------------
__global__ __launch_bounds__(256) void w2bf(const float* __restrict__ a,
                                            const float* __restrict__ b,
                                            const float* __restrict__ c,
                                            u16* __restrict__ dst) {
    const float* s = (blockIdx.y == 0) ? a : (blockIdx.y == 1) ? b : c;
    const int i = (blockIdx.x * 256 + threadIdx.x) * 4;
    const float4 v = *reinterpret_cast<const float4*>(s + i);
    ushort4 p;
    p.x = f2bf(v.x); p.y = f2bf(v.y); p.z = f2bf(v.z); p.w = f2bf(v.w);
    *reinterpret_cast<ushort4*>(dst + (long)blockIdx.y * 262144 + i) = p;
}

// ------------------ softmax over rows of S[i, :] (bf16) in place ------------------
__global__ __launch_bounds__(256) void softmax_rows(u16* __restrict__ S) {
    u16* p = S + (long)blockIdx.x * 2048;
    const int tid = threadIdx.x;
    uint4 v = *reinterpret_cast<const uint4*>(p + (tid << 3));
    unsigned int w[4] = {v.x, v.y, v.z, v.w};
    float f[8];
#pragma unroll
    for (int i = 0; i < 4; i++) {
        f[2 * i]     = bf2f((u16)(w[i] & 0xffffu));
        f[2 * i + 1] = bf2f((u16)(w[i] >> 16));
    }
    float m = f[0];
#pragma unroll
    for (int i = 1; i < 8; i++) m = fmaxf(m, f[i]);
    const int lane = tid & 63, wave = tid >> 6;
#pragma unroll
    for (int o = 32; o > 0; o >>= 1) m = fmaxf(m, __shfl_down(m, o, 64));
    __shared__ float rb[4];
    __shared__ float bc;
    if (lane == 0) rb[wave] = m;
    __syncthreads();
    if (tid == 0) bc = fmaxf(fmaxf(rb[0], rb[1]), fmaxf(rb[2], rb[3]));
    __syncthreads();
    m = bc;
    float s = 0.f;
#pragma unroll
    for (int i = 0; i < 8; i++) { f[i] = __expf(f[i] - m); s += f[i]; }
#pragma unroll
    for (int o = 32; o > 0; o >>= 1) s += __shfl_down(s, o, 64);
    __syncthreads();
    if (lane == 0) rb[wave] = s;
    __syncthreads();
    if (tid == 0) bc = 1.f / (rb[0] + rb[1] + rb[2] + rb[3]);
    __syncthreads();
    const float inv = bc;
#pragma unroll
    for (int i = 0; i < 4; i++)
        w[i] = (unsigned int)f2bf(f[2 * i] * inv) | ((unsigned int)f2bf(f[2 * i + 1] * inv) << 16);
    *reinterpret_cast<uint4*>(p + (tid << 3)) = uint4{w[0], w[1], w[2], w[3]};
}

// ===================== 256x256-tile 8-wave 4-phase GEMM (S-GEMM) =====================
// Structure as r5/r6 (harness-verified). r7 change: FULL 3-bit XOR swizzle.
// r6 had 1-bit (byte ^= (row&4)<<3): an 8-lane hw group (8 rows, same 16B slot) was
// 4-way bank-conflicted (3.1M SQ_LDS_BANK_CONFLICT, 1.58x LDS slowdown per m136).
// 3-bit: in-row u16 slot = ((ks<<5)|(quad<<3)) ^ ((row&7)<<3) -> every 8-lane group
// covers 8 distinct 16B slots -> conflict-free. Write side (LDS dest linear, rule #21):
// global source col-block = (lane&7) ^ ((lane>>3)&7) = slot ^ (LDSrow&7); per 8-lane
// row-group the 8 col-blocks are a permutation of 0..7 -> contiguous 128B coalescing kept.
// Valid for both issues (+64 LDS rows ≡ same row&7) and all row bases (≡ 0 mod 8).
__global__ __launch_bounds__(512, 1) void gemm256_s(const u16* __restrict__ Ag, long sA,
                                                    const u16* __restrict__ Bg, long sB,
                                                    u16* __restrict__ Og, long sO,
                                                    int K, int lda, int ldb, int ldo,
                                                    float scale) {
    const int bx = blockIdx.x;
    const int b = bx & 7, s = bx >> 3;
    const int ty = s & 7, tx = s >> 3;
    const int m0 = ty * 256, n0 = tx * 256;
    Ag += (long)b * sA;
    Bg += (long)b * sB;
    u16* O = Og + (long)b * sO;

    __shared__ __align__(16) u16 LA[2][2][128 * 64];   // [buf][region mh][row*64+k] 64 KiB
    __shared__ __align__(16) u16 LB[2][2][128 * 64];   // [buf][region nh]           64 KiB

    const int tid = threadIdx.x;
    const int lane = tid & 63, wave = tid >> 6;
    const int wm = wave >> 2, w4 = wave & 3;
    const int l15 = lane & 15, quad = lane >> 4;

    // 3-bit XOR swizzle read slots (u16 units): bits[5:3] = {ks,q1,q0} ^ (row&7)
    const int sw   = (l15 & 7) << 3;
    const int slt0 = ((quad << 3)) ^ sw;          // ks=0
    const int slt1 = (32 + (quad << 3)) ^ sw;     // ks=1 (32 u16 = 64 B)
    const int arow_u = (wm * 64 + l15) * 64;
    const int brow_u = (w4 * 32 + l15) * 64;

    // staging: lane covers LDS row (wave*8 + lane/8), phys slot lane&7; global col-block
    // pre-swizzled by the SAME involution: (lane&7) ^ (LDSrow&7), LDSrow&7 = (lane>>3)&7
    const int l8 = lane >> 3;
    const int lrow0 = wave * 8 + l8;                               // region row, issue 0 (0..63)
    const int sEl = (((lane & 7) ^ ((lane >> 3) & 7)) << 3);       // pre-swizzled col (u16)
    int pA[2], pB[2];
    pA[0] = (m0 + lrow0) * lda + sEl;
    pA[1] = (m0 + 64 + lrow0) * lda + sEl;
    {
        const int gb = (lrow0 >> 5) * 64 + (lrow0 & 31);
        pB[0] = (n0 + gb) * ldb + sEl;
        pB[1] = (n0 + gb + 32) * ldb + sEl;
    }
    const int jA = 128 * lda;
    const int jB = 128 * ldb;

    auto stageA = [&](int buf, int mh, int k0) {
        u16* d = &LA[buf][mh][wave * 512];
        async_cp16(Ag + pA[mh] + k0, d);
        async_cp16(Ag + pA[mh] + jA + k0, d + 4096);
    };
    auto stageB = [&](int buf, int nh, int k0) {
        u16* d = &LB[buf][nh][wave * 512];
        async_cp16(Bg + pB[nh] + k0, d);
        async_cp16(Bg + pB[nh] + jB + k0, d + 4096);
    };

    f32x4 acc[8][4];
#pragma unroll
    for (int i = 0; i < 8; i++)
#pragma unroll
        for (int j = 0; j < 4; j++) acc[i][j] = f32x4{0.f, 0.f, 0.f, 0.f};

    s16x8 fa[4][2], fblo[2][2], fbhi[2][2];

    const int NT = K >> 6;

    stageA(0, 0, 0);
    stageB(0, 0, 0);
    stageB(0, 1, 0);
    stageA(0, 1, 0);
    if (NT > 1) {
        stageA(1, 0, 64);
        stageB(1, 0, 64);
        stageB(1, 1, 64);
    }
    WAITV(8); SB0();
    BARR(); SB0();

    for (int t = 0; t < NT; t++) {
        const int buf = t & 1;
        const int k2 = (t + 2) << 6;
        // phase 1: (mh=0, nh=0)
        {
            const u16* Ar = &LA[buf][0][0];
            const u16* Br = &LB[buf][0][0];
#pragma unroll
            for (int mf = 0; mf < 4; mf++)
#pragma unroll
                for (int ks = 0; ks < 2; ks++)
                    fa[mf][ks] = *reinterpret_cast<const s16x8*>(Ar + arow_u + mf * 1024 + (ks ? slt1 : slt0));
#pragma unroll
            for (int nf = 0; nf < 2; nf++)
#pragma unroll
                for (int ks = 0; ks < 2; ks++)
                    fblo[nf][ks] = *reinterpret_cast<const s16x8*>(Br + brow_u + nf * 1024 + (ks ? slt1 : slt0));
            if (t + 1 < NT) stageA(buf ^ 1, 1, (t + 1) << 6);
            if (t == NT - 1) { WAITV(2); } else { WAITV(8); }
            SB0();
            BARR(); SB0();
            __builtin_amdgcn_s_setprio(1);
#pragma unroll
            for (int mf = 0; mf < 4; mf++)
#pragma unroll
                for (int nf = 0; nf < 2; nf++)
#pragma unroll
                    for (int ks = 0; ks < 2; ks++)
                        acc[mf][nf] = __builtin_amdgcn_mfma_f32_16x16x32_bf16(fa[mf][ks], fblo[nf][ks], acc[mf][nf], 0, 0, 0);
            __builtin_amdgcn_s_setprio(0);
            BARR(); SB0();
        }
        // phase 2: (mh=0, nh=1)
        {
            const u16* Br = &LB[buf][1][0];
#pragma unroll
            for (int nf = 0; nf < 2; nf++)
#pragma unroll
                for (int ks = 0; ks < 2; ks++)
                    fbhi[nf][ks] = *reinterpret_cast<const s16x8*>(Br + brow_u + nf * 1024 + (ks ? slt1 : slt0));
            if (t + 2 < NT) stageA(buf, 0, k2);
            if (t == NT - 1) { WAITV(0); } else { WAITV(8); }
            SB0();
            BARR(); SB0();
            __builtin_amdgcn_s_setprio(1);
#pragma unroll
            for (int mf = 0; mf < 4; mf++)
#pragma unroll
                for (int nf = 0; nf < 2; nf++)
#pragma unroll
                    for (int ks = 0; ks < 2; ks++)
                        acc[mf][2 + nf] = __builtin_amdgcn_mfma_f32_16x16x32_bf16(fa[mf][ks], fbhi[nf][ks], acc[mf][2 + nf], 0, 0, 0);
            __builtin_amdgcn_s_setprio(0);
            BARR(); SB0();
        }
        // phase 3: (mh=1, nh=1)
        {
            const u16* Ar = &LA[buf][1][0];
#pragma unroll
            for (int mf = 0; mf < 4; mf++)
#pragma unroll
                for (int ks = 0; ks < 2; ks++)
                    fa[mf][ks] = *reinterpret_cast<const s16x8*>(Ar + arow_u + mf * 1024 + (ks ? slt1 : slt0));
            if (t + 2 < NT) stageB(buf, 0, k2);
            WAITV(8); SB0();
            BARR(); SB0();
            __builtin_amdgcn_s_setprio(1);
#pragma unroll
            for (int mf = 0; mf < 4; mf++)
#pragma unroll
                for (int nf = 0; nf < 2; nf++)
#pragma unroll
                    for (int ks = 0; ks < 2; ks++)
                        acc[4 + mf][2 + nf] = __builtin_amdgcn_mfma_f32_16x16x32_bf16(fa[mf][ks], fbhi[nf][ks], acc[4 + mf][2 + nf], 0, 0, 0);
            __builtin_amdgcn_s_setprio(0);
            BARR(); SB0();
        }
        // phase 4: (mh=1, nh=0)
        {
            if (t + 2 < NT) stageB(buf, 1, k2);
            if (t == NT - 2) { WAITV(4); } else { WAITV(8); }
            SB0();
            BARR(); SB0();
            __builtin_amdgcn_s_setprio(1);
#pragma unroll
            for (int mf = 0; mf < 4; mf++)
#pragma unroll
                for (int nf = 0; nf < 2; nf++)
#pragma unroll
                    for (int ks = 0; ks < 2; ks++)
                        acc[4 + mf][nf] = __builtin_amdgcn_mfma_f32_16x16x32_bf16(fa[mf][ks], fblo[nf][ks], acc[4 + mf][nf], 0, 0, 0);
            __builtin_amdgcn_s_setprio(0);
            BARR(); SB0();
        }
    }

    const int orow = m0 + wm * 128 + quad * 4;
    const int ocol = n0 + w4 * 64 + l15;
#pragma unroll
    for (int mi = 0; mi < 8; mi++)
#pragma unroll
        for (int ni = 0; ni < 4; ni++) {
            const long rb = (long)(orow + mi * 16) * ldo + ocol + ni * 16;
#pragma unroll
            for (int r = 0; r < 4; r++)
                O[rb + (long)r * ldo] = f2bf(acc[mi][ni][r] * scale);
        }
}

// ===================== 256x128-tile 8-wave 4-phase GEMM (PV) =====================
// Structure as r6 (harness-verified); r7: same 3-bit XOR swizzle upgrade as gemm256_s.
template <int EPI>
__global__ __launch_bounds__(512, 1) void gemm256_pv(const u16* __restrict__ Ag, long sA,
                                                     const u16* __restrict__ Bg, long sB,
                                                     u16* __restrict__ Og, long sO,
                                                     int K, int lda, int ldb, int ldo,
                                                     float scale) {
    const int bx = blockIdx.x;
    const int b = bx & 7, s = bx >> 3;      // s in [0,32)
    const int mt = s >> 2, nt = s & 3;
    const int m0 = mt * 256, n0 = nt * 128;
    Ag += (long)b * sA;
    Bg += (long)b * sB;
    u16* O = Og + (long)b * sO;

    __shared__ __align__(16) u16 LA[2][2][128 * 64];   // 64 KiB
    __shared__ __align__(16) u16 LB[2][2][64 * 64];    // 32 KiB

    const int tid = threadIdx.x;
    const int lane = tid & 63, wave = tid >> 6;
    const int wm = wave >> 1, wn = wave & 1;           // 4(M) x 2(N)
    const int l15 = lane & 15, quad = lane >> 4;

    // 3-bit XOR swizzle read slots (u16 units)
    const int sw   = (l15 & 7) << 3;
    const int slt0 = ((quad << 3)) ^ sw;
    const int slt1 = (32 + (quad << 3)) ^ sw;

    // staging: thread covers region row r0 = tid>>3; phys slot lane&7;
    // global col-block pre-swizzled by (lane&7) ^ ((lane>>3)&7) (= slot ^ LDSrow&7)
    const int r0 = tid >> 3;
    const int sEl = (((lane & 7) ^ ((lane >> 3) & 7)) << 3);
    const int gA = (r0 >> 5) * 64 + (r0 & 31);         // A region row -> global local-M
    int pA[2], pB[2];
    pA[0] = (m0 + gA) * lda + sEl;                     // A-lo
    pA[1] = (m0 + gA + 32) * lda + sEl;                // A-hi
    pB[0] = (n0 + gA) * ldb + sEl;                     // B-lo (same row pattern)
    pB[1] = (n0 + gA + 32) * ldb + sEl;                // B-hi
    const int jA = 128 * lda;                          // A issue-1 delta (+128 global rows)

    auto stageA = [&](int buf, int mh, int k0) {       // 2 instr (16 KB region)
        u16* d = &LA[buf][mh][wave * 512];
        async_cp16(Ag + pA[mh] + k0, d);
        async_cp16(Ag + pA[mh] + jA + k0, d + 4096);
    };
    auto stageBB = [&](int buf, int k0) {              // 2 instr (both 8 KB B regions)
        async_cp16(Bg + pB[0] + k0, &LB[buf][0][wave * 512]);
        async_cp16(Bg + pB[1] + k0, &LB[buf][1][wave * 512]);
    };

    f32x4 acc[4][4];
#pragma unroll
    for (int i = 0; i < 4; i++)
#pragma unroll
        for (int j = 0; j < 4; j++) acc[i][j] = f32x4{0.f, 0.f, 0.f, 0.f};

    s16x8 fa[2][2], fblo[2][2], fbhi[2][2];

    const int arow_u = (wm * 32 + l15) * 64;           // + mf*16*64
    const int brow_u = (wn * 32 + l15) * 64;           // + nf*16*64

    const int NT = K >> 6;                             // 32 for PV

    // prologue: B(0), A-lo(0), A-hi(0), B(1); retire through A-lo(0) -> WAITV(4)
    stageBB(0, 0);
    stageA(0, 0, 0);
    stageA(0, 1, 0);
    if (NT > 1) stageBB(1, 64);
    WAITV(4); SB0();
    BARR(); SB0();

    for (int t = 0; t < NT; t++) {
        const int buf = t & 1;
        const int k1 = (t + 1) << 6, k2 = (t + 2) << 6;
        // ---- phase 1: (mh=0, nh=0) — reads A-lo(t), B-lo(t)
        {
            const u16* Ar = &LA[buf][0][0];
            const u16* Br = &LB[buf][0][0];
#pragma unroll
            for (int mf = 0; mf < 2; mf++)
#pragma unroll
                for (int ks = 0; ks < 2; ks++)
                    fa[mf][ks] = *reinterpret_cast<const s16x8*>(Ar + arow_u + mf * 1024 + (ks ? slt1 : slt0));
#pragma unroll
            for (int nf = 0; nf < 2; nf++)
#pragma unroll
                for (int ks = 0; ks < 2; ks++)
                    fblo[nf][ks] = *reinterpret_cast<const s16x8*>(Br + brow_u + nf * 1024 + (ks ? slt1 : slt0));
            if (t + 1 < NT) stageA(buf ^ 1, 0, k1);    // A-lo(t+1)
            __builtin_amdgcn_s_setprio(1);
#pragma unroll
            for (int mf = 0; mf < 2; mf++)
#pragma unroll
                for (int nf = 0; nf < 2; nf++)
#pragma unroll
                    for (int ks = 0; ks < 2; ks++)
                        acc[mf][nf] = __builtin_amdgcn_mfma_f32_16x16x32_bf16(fa[mf][ks], fblo[nf][ks], acc[mf][nf], 0, 0, 0);
            __builtin_amdgcn_s_setprio(0);
            if (t == NT - 1) { WAITV(0); } else { WAITV(4); }   // retire A-hi(t) for p3
            SB0();
            BARR(); SB0();
        }
        // ---- phase 2: (mh=0, nh=1) — reads B-hi(t)
        {
            const u16* Br = &LB[buf][1][0];
#pragma unroll
            for (int nf = 0; nf < 2; nf++)
#pragma unroll
                for (int ks = 0; ks < 2; ks++)
                    fbhi[nf][ks] = *reinterpret_cast<const s16x8*>(Br + brow_u + nf * 1024 + (ks ? slt1 : slt0));
            if (t + 1 < NT) stageA(buf ^ 1, 1, k1);    // A-hi(t+1)
            __builtin_amdgcn_s_setprio(1);
#pragma unroll
            for (int mf = 0; mf < 2; mf++)
#pragma unroll
                for (int nf = 0; nf < 2; nf++)
#pragma unroll
                    for (int ks = 0; ks < 2; ks++)
                        acc[mf][2 + nf] = __builtin_amdgcn_mfma_f32_16x16x32_bf16(fa[mf][ks], fbhi[nf][ks], acc[mf][2 + nf], 0, 0, 0);
            __builtin_amdgcn_s_setprio(0);
            BARR(); SB0();
        }
        // ---- phase 3: (mh=1, nh=1) — reads A-hi(t) (retired by p1's WAITV)
        {
            const u16* Ar = &LA[buf][1][0];
#pragma unroll
            for (int mf = 0; mf < 2; mf++)
#pragma unroll
                for (int ks = 0; ks < 2; ks++)
                    fa[mf][ks] = *reinterpret_cast<const s16x8*>(Ar + arow_u + mf * 1024 + (ks ? slt1 : slt0));
            if (t + 2 < NT) stageBB(buf, k2);          // B(t+2) (WAR: B(t) last read p2, barrier between)
            __builtin_amdgcn_s_setprio(1);
#pragma unroll
            for (int mf = 0; mf < 2; mf++)
#pragma unroll
                for (int nf = 0; nf < 2; nf++)
#pragma unroll
                    for (int ks = 0; ks < 2; ks++)
                        acc[2 + mf][2 + nf] = __builtin_amdgcn_mfma_f32_16x16x32_bf16(fa[mf][ks], fbhi[nf][ks], acc[2 + mf][2 + nf], 0, 0, 0);
            __builtin_amdgcn_s_setprio(0);
            BARR(); SB0();
        }
        // ---- phase 4: (mh=1, nh=0) — regs only; WAITV retires B(t+1)+A-lo(t+1) for next p1
        {
            __builtin_amdgcn_s_setprio(1);
#pragma unroll
            for (int mf = 0; mf < 2; mf++)
#pragma unroll
                for (int nf = 0; nf < 2; nf++)
#pragma unroll
                    for (int ks = 0; ks < 2; ks++)
                        acc[2 + mf][nf] = __builtin_amdgcn_mfma_f32_16x16x32_bf16(fa[mf][ks], fblo[nf][ks], acc[2 + mf][nf], 0, 0, 0);
            __builtin_amdgcn_s_setprio(0);
            if (t == NT - 2) { WAITV(2); } else if (t < NT - 2) { WAITV(4); }
            SB0();
            BARR(); SB0();
        }
    }

    // epilogue: row = m0 + wm*64 + mi*16 + quad*4 + r; col = n0 + wn*64 + ni*16 + l15
    const int orow = m0 + wm * 64 + quad * 4;
    const int ocol = n0 + wn * 64 + l15;
#pragma unroll
    for (int mi = 0; mi < 4; mi++)
#pragma unroll
        for (int ni = 0; ni < 4; ni++) {
            const long rb = (long)(orow + mi * 16) * ldo + ocol + ni * 16;
#pragma unroll
            for (int r = 0; r < 4; r++)
                O[rb + (long)r * ldo] = f2bf(acc[mi][ni][r] * scale);
        }
}

// ===================== ASYNC 3-deep counted-vmcnt MFMA GEMM (bf16 operands) =====================
template <int EPI, int SWIZ>
__global__ __launch_bounds__(256) void gemm_tn_a(const u16* __restrict__ Ag, long sA,
                                                 const u16* __restrict__ Bg, long sB,
                                                 const float* __restrict__ bias,
                                                 const float* __restrict__ Xg, long sX,
                                                 void* __restrict__ Ogv, long sO,
                                                 int K, int lda, int ldb, int ldo,
                                                 float scale) {
    const int b = blockIdx.z;
    Ag += (long)b * sA;
    Bg += (long)b * sB;
    int tx, ty;
    if (SWIZ == 1) {
        const int xcd = blockIdx.x & 7, s = blockIdx.x >> 3;
        ty = xcd + 8 * (s >> 2);
        tx = s & 3;
    } else if (SWIZ == 2) {
        const int xcd = blockIdx.x & 7, s = blockIdx.x >> 3;
        ty = (xcd & 3) * 4 + (s & 3);
        tx = (xcd >> 2) * 8 + (s >> 2);
    } else {
        tx = blockIdx.x; ty = blockIdx.y;
    }
    const int m0 = ty * BM;
    const int n0 = tx * BN;

    __shared__ __align__(16) u16 As[3][BM * BK];
    __shared__ __align__(16) u16 Bs[3][BN * BK];

    const int tid = threadIdx.x;
    const int wave = tid >> 6;
    const int lane = tid & 63;
    const int quad = lane >> 4;
    const int l16 = lane & 15;
    const int wm = (wave >> 1) * 64;
    const int wn = (wave & 1) * 64;
    const int rl = lane >> 2;
    const int cl = (lane & 3) * 8;

    f32x4 acc[4][4];
#pragma unroll
    for (int i = 0; i < 4; i++)
#pragma unroll
        for (int j = 0; j < 4; j++) acc[i][j] = f32x4{0.f, 0.f, 0.f, 0.f};

    auto stage = [&](int buf, int k0) {
#pragma unroll
        for (int j = 0; j < 2; j++) {
            const int rbase = wave * 32 + j * 16;
            async_cp16(Ag + (long)(m0 + rbase + rl) * lda + k0 + cl, &As[buf][rbase * BK]);
            async_cp16(Bg + (long)(n0 + rbase + rl) * ldb + k0 + cl, &Bs[buf][rbase * BK]);
        }
    };
    auto compute = [&](int buf) {
        s16x8 af[4], bfr[4];
#pragma unroll
        for (int i = 0; i < 4; i++)
            af[i] = *reinterpret_cast<const s16x8*>(&As[buf][(wm + i * 16 + l16) * BK + quad * 8]);
#pragma unroll
        for (int j = 0; j < 4; j++)
            bfr[j] = *reinterpret_cast<const s16x8*>(&Bs[buf][(wn + j * 16 + l16) * BK + quad * 8]);
#pragma unroll
        for (int i = 0; i < 4; i++)
#pragma unroll
            for (int j = 0; j < 4; j++)
                acc[i][j] = __builtin_amdgcn_mfma_f32_16x16x32_bf16(af[i], bfr[j], acc[i][j], 0, 0, 0);
    };

    const int nsteps = K / BK;
    stage(0, 0);
    stage(1, BK);
    int t = 0;
    for (; t < nsteps - 1; t++) {
        asm volatile("s_waitcnt vmcnt(4)" ::: "memory");
        asm volatile("s_barrier" ::: "memory");
        if (t + 2 < nsteps) stage((t + 2) % 3, (t + 2) * BK);
        compute(t % 3);
    }
    asm volatile("s_waitcnt vmcnt(0)" ::: "memory");
    asm volatile("s_barrier" ::: "memory");
    compute(t % 3);

#pragma unroll
    for (int i = 0; i < 4; i++) {
        const int mb = m0 + wm + i * 16 + quad * 4;
#pragma unroll
        for (int j = 0; j < 4; j++) {
            const int n = n0 + wn + j * 16 + l16;
            if (EPI == 0) {
                u16* O = (u16*)Ogv + (long)b * sO;
#pragma unroll
                for (int r = 0; r < 4; r++) {
                    float vv = acc[i][j][r] * scale;
                    if (bias) vv += bias[mb + r];
                    O[(long)(mb + r) * ldo + n] = f2bf(vv);
                }
            } else if (EPI == 1) {
                u16* O = (u16*)Ogv + (long)b * sO;
                ushort4 pk;
                pk.x = f2bf(acc[i][j][0] + bias[mb + 0]);
                pk.y = f2bf(acc[i][j][1] + bias[mb + 1]);
                pk.z = f2bf(acc[i][j][2] + bias[mb + 2]);
                pk.w = f2bf(acc[i][j][3] + bias[mb + 3]);
                *reinterpret_cast<ushort4*>(&O[(long)n * ldo + mb]) = pk;
            } else {
                float* O = (float*)Ogv + (long)b * sO;
                const float* X = Xg + (long)b * sX;
                const float bn = bias[n];
                const float4 xv = *reinterpret_cast<const float4*>(&X[(long)n * ldo + mb]);
                float4 pk;
                pk.x = acc[i][j][0] + bn + xv.x;
                pk.y = acc[i][j][1] + bn + xv.y;
                pk.z = acc[i][j][2] + bn + xv.z;
                pk.w = acc[i][j][3] + bn + xv.w;
                *reinterpret_cast<float4*>(&O[(long)n * ldo + mb]) = pk;
            }
        }
    }
}

// ===================== merged QKV GEMM, XCD-swizzled, 3-deep counted-vmcnt =====================
__global__ __launch_bounds__(256) void qkv_a(const u16* __restrict__ wb3,
                                             const u16* __restrict__ hnT,
                                             const float* __restrict__ bq,
                                             const float* __restrict__ bk,
                                             const float* __restrict__ bv,
                                             u16* __restrict__ qT, u16* __restrict__ kT,
                                             u16* __restrict__ vv) {
    const long HC = 1048576;
    const int b = blockIdx.z;
    const int xcd = blockIdx.x & 7, s = blockIdx.x >> 3;   // s in [0,24)
    const int hi = (s >= 12) ? 1 : 0;
    const int yy = s - hi * 12;                            // [0,12)
    const int x = xcd + 8 * hi;                            // n-tile [0,16)
    const int which = yy >> 2;                             // 0=q 1=k 2=v
    const int my = yy & 3;                                 // m-tile [0,4)
    const u16* Ag = wb3 + which * 262144;
    const u16* Bg = hnT + (long)b * HC;
    const int m0 = my * BM;
    const int n0 = x * BN;

    __shared__ __align__(16) u16 As[3][BM * BK];
    __shared__ __align__(16) u16 Bs[3][BN * BK];

    const int tid = threadIdx.x;
    const int wave = tid >> 6;
    const int lane = tid & 63;
    const int quad = lane >> 4;
    const int l16 = lane & 15;
    const int wm = (wave >> 1) * 64;
    const int wn = (wave & 1) * 64;
    const int rl = lane >> 2;
    const int cl = (lane & 3) * 8;

    f32x4 acc[4][4];
#pragma unroll
    for (int i = 0; i < 4; i++)
#pragma unroll
        for (int j = 0; j < 4; j++) acc[i][j] = f32x4{0.f, 0.f, 0.f, 0.f};

    auto stage = [&](int buf, int k0) {
#pragma unroll
        for (int j = 0; j < 2; j++) {
            const int rbase = wave * 32 + j * 16;
            async_cp16(Ag + (long)(m0 + rbase + rl) * 512 + k0 + cl, &As[buf][rbase * BK]);
            async_cp16(Bg + (long)(n0 + rbase + rl) * 512 + k0 + cl, &Bs[buf][rbase * BK]);
        }
    };
    auto compute = [&](int buf) {
        s16x8 af[4], bfr[4];
#pragma unroll
        for (int i = 0; i < 4; i++)
            af[i] = *reinterpret_cast<const s16x8*>(&As[buf][(wm + i * 16 + l16) * BK + quad * 8]);
#pragma unroll
        for (int j = 0; j < 4; j++)
            bfr[j] = *reinterpret_cast<const s16x8*>(&Bs[buf][(wn + j * 16 + l16) * BK + quad * 8]);
#pragma unroll
        for (int i = 0; i < 4; i++)
#pragma unroll
            for (int j = 0; j < 4; j++)
                acc[i][j] = __builtin_amdgcn_mfma_f32_16x16x32_bf16(af[i], bfr[j], acc[i][j], 0, 0, 0);
    };

    const int nsteps = 512 / BK;   // 16
    stage(0, 0);
    stage(1, BK);
    int t = 0;
    for (; t < nsteps - 1; t++) {
        asm volatile("s_waitcnt vmcnt(4)" ::: "memory");
        asm volatile("s_barrier" ::: "memory");
        if (t + 2 < nsteps) stage((t + 2) % 3, (t + 2) * BK);
        compute(t % 3);
    }
    asm volatile("s_waitcnt vmcnt(0)" ::: "memory");
    asm volatile("s_barrier" ::: "memory");
    compute(t % 3);

    if (which == 2) {
        u16* O = vv + (long)b * HC;
#pragma unroll
        for (int i = 0; i < 4; i++) {
            const int mb = m0 + wm + i * 16 + quad * 4;
#pragma unroll
            for (int j = 0; j < 4; j++) {
                const int n = n0 + wn + j * 16 + l16;
#pragma unroll
                for (int r = 0; r < 4; r++)
                    O[(long)(mb + r) * 2048 + n] = f2bf(acc[i][j][r] + bv[mb + r]);
            }
        }
    } else {
        const float* bias = which ? bk : bq;
        u16* O = (which ? kT : qT) + (long)b * HC;
#pragma unroll
        for (int i = 0; i < 4; i++) {
            const int mb = m0 + wm + i * 16 + quad * 4;
#pragma unroll
            for (int j = 0; j < 4; j++) {
                const int n = n0 + wn + j * 16 + l16;
                ushort4 pk;
                pk.x = f2bf(acc[i][j][0] + bias[mb + 0]);
                pk.y = f2bf(acc[i][j][1] + bias[mb + 1]);
                pk.z = f2bf(acc[i][j][2] + bias[mb + 2]);
                pk.w = f2bf(acc[i][j][3] + bias[mb + 3]);
                *reinterpret_cast<ushort4*>(&O[(long)n * 512 + mb]) = pk;
            }
        }
    }
}

// ===================== legacy padded GEMM (fallback tiers, fp32-capable) =====================
template <int F32>
__device__ __forceinline__ void stage_tile(const char* G, int ld, int r0, int k0,
                                           u16* __restrict__ lds, int tid) {
    if (F32) {
        const float* g = (const float*)G;
#pragma unroll
        for (int s = 0; s < 4; s++) {
            const int c = tid + s * 256;
            const int row = c >> 3, col = (c & 7) * 4;
            const float4 v = *reinterpret_cast<const float4*>(g + (long)(r0 + row) * ld + k0 + col);
            ushort4 pk;
            pk.x = f2bf(v.x); pk.y = f2bf(v.y); pk.z = f2bf(v.z); pk.w = f2bf(v.w);
            *reinterpret_cast<ushort4*>(&lds[row * KPAD + col]) = pk;
        }
    } else {
        const u16* g = (const u16*)G;
#pragma unroll
        for (int s = 0; s < 2; s++) {
            const int c = tid + s * 256;
            const int row = c >> 2, col = (c & 3) * 8;
            const uint4 v = *reinterpret_cast<const uint4*>(g + (long)(r0 + row) * ld + k0 + col);
            *reinterpret_cast<uint4*>(&lds[row * KPAD + col]) = v;
        }
    }
}

template <int EPI, int AF32, int BF32>
__global__ __launch_bounds__(256) void gemm_tn(const void* __restrict__ Agv, long sA,
                                               const void* __restrict__ Bgv, long sB,
                                               const float* __restrict__ bias,
                                               const float* __restrict__ Xg, long sX,
                                               void* __restrict__ Ogv, long sO,
                                               int K, int lda, int ldb, int ldo,
                                               float scale) {
    const int b = blockIdx.z;
    const char* A8 = (const char*)Agv + (long)b * sA * (AF32 ? 4 : 2);
    const char* B8 = (const char*)Bgv + (long)b * sB * (BF32 ? 4 : 2);
    const int m0 = blockIdx.y * BM;
    const int n0 = blockIdx.x * BN;

    __shared__ __align__(16) u16 As[BM * KPAD];
    __shared__ __align__(16) u16 Bs[BN * KPAD];

    const int tid = threadIdx.x;
    const int wave = tid >> 6;
    const int lane = tid & 63;
    const int quad = lane >> 4;
    const int l16 = lane & 15;
    const int wm = (wave >> 1) * 64;
    const int wn = (wave & 1) * 64;

    f32x4 acc[4][4];
#pragma unroll
    for (int i = 0; i < 4; i++)
#pragma unroll
        for (int j = 0; j < 4; j++) acc[i][j] = f32x4{0.f, 0.f, 0.f, 0.f};

    for (int k0 = 0; k0 < K; k0 += BK) {
        __syncthreads();
        stage_tile<AF32>(A8, lda, m0, k0, As, tid);
        stage_tile<BF32>(B8, ldb, n0, k0, Bs, tid);
        __syncthreads();
        s16x8 af[4], bfr[4];
#pragma unroll
        for (int i = 0; i < 4; i++)
            af[i] = *reinterpret_cast<const s16x8*>(&As[(wm + i * 16 + l16) * KPAD + quad * 8]);
#pragma unroll
        for (int j = 0; j < 4; j++)
            bfr[j] = *reinterpret_cast<const s16x8*>(&Bs[(wn + j * 16 + l16) * KPAD + quad * 8]);
#pragma unroll
        for (int i = 0; i < 4; i++)
#pragma unroll
            for (int j = 0; j < 4; j++)
                acc[i][j] = __builtin_amdgcn_mfma_f32_16x16x32_bf16(af[i], bfr[j], acc[i][j], 0, 0, 0);
    }

#pragma unroll
    for (int i = 0; i < 4; i++) {
        const int mb = m0 + wm + i * 16 + quad * 4;
#pragma unroll
        for (int j = 0; j < 4; j++) {
            const int n = n0 + wn + j * 16 + l16;
            if (EPI == 0) {
                u16* O = (u16*)Ogv + (long)b * sO;
#pragma unroll
                for (int r = 0; r < 4; r++) {
                    float vv = acc[i][j][r] * scale;
                    if (bias) vv += bias[mb + r];
                    O[(long)(mb + r) * ldo + n] = f2bf(vv);
                }
            } else if (EPI == 1) {
                u16* O = (u16*)Ogv + (long)b * sO;
                ushort4 pk;
                pk.x = f2bf(acc[i][j][0] + bias[mb + 0]);
                pk.y = f2bf(acc[i][j][1] + bias[mb + 1]);
                pk.z = f2bf(acc[i][j][2] + bias[mb + 2]);
                pk.w = f2bf(acc[i][j][3] + bias[mb + 3]);
                *reinterpret_cast<ushort4*>(&O[(long)n * ldo + mb]) = pk;
            } else {
                float* O = (float*)Ogv + (long)b * sO;
                const float* X = Xg + (long)b * sX;
                const float bn = bias[n];
                const float4 xv = *reinterpret_cast<const float4*>(&X[(long)n * ldo + mb]);
                float4 pk;
                pk.x = acc[i][j][0] + bn + xv.x;
                pk.y = acc[i][j][1] + bn + xv.y;
                pk.z = acc[i][j][2] + bn + xv.z;
                pk.w = acc[i][j][3] + bn + xv.w;
                *reinterpret_cast<float4*>(&O[(long)n * ldo + mb]) = pk;
            }
        }
    }
}

extern "C" void kernel_launch(void* const* d_in, const int* in_sizes, int n_in,
                              void* d_out, int out_size, void* d_ws, size_t ws_size,
                              hipStream_t stream) {
    const float* x     = (const float*)d_in[0];
    const float* gamma = (const float*)d_in[1];
    const float* beta  = (const float*)d_in[2];
    const float* wq    = (const float*)d_in[3];
    const float* bq    = (const float*)d_in[4];
    const float* wk    = (const float*)d_in[5];
    const float* bk    = (const float*)d_in[6];
    const float* wv    = (const float*)d_in[7];
    const float* bv    = (const float*)d_in[8];
    const float* wp    = (const float*)d_in[9];
    const float* bp    = (const float*)d_in[10];
    float* out = (float*)d_out;

    const long HC = (long)2048 * 512;
    const long HH = (long)2048 * 2048;
    const long WSZ = 512 * 512;
    const float scl = 0.044194173824159216f;   // 1/sqrt(512)

    char* ws = (char*)d_ws;
    float* meanb = (float*)ws;
    float* rstdb = (float*)(ws + 1024);
    u16* base = (u16*)(ws + 4096);

    const size_t FULL_NEED   = 4096 + 2 * (size_t)(24 * HC + 8 * HH);     // 117,444,608
    const size_t MED_NEED    = 4096 + 2 * (size_t)(32 * HC + HH);         //  75,501,568
    const size_t SMALL_NEED  = 4096 + 2 * (size_t)(4 * HC + HH);          //  16,781,312
    const size_t CHUNK512    = 4096 + 2 * (size_t)(4 * HC + 512 * 2048);  //  10,489,856

    gn_stats<<<256, 256, 0, stream>>>(x, meanb, rstdb);

    if (ws_size >= FULL_NEED) {
        // ---- FULL: all-batched; S on 256^2 4-phase; PV on 256x128 4-phase ----
        u16* qT  = base;                       // [B,H,C]
        u16* kT  = qT + 8 * HC;                // [B,H,C]
        u16* vv  = kT + 8 * HC;                // [B,C,H]
        u16* Sb  = vv + 8 * HC;                // [B,H,H]
        u16* hnT = Sb;                         // overlay: dead before S written
        u16* wb3 = Sb + 8 * HH - 3 * WSZ;      // overlay: wq|wk|wv bf16, dead after QKV
        u16* hT  = qT;                         // overlay: qT dead after S-GEMM
        u16* wpb = vv;                         // overlay: vv dead after PV

        w2bf<<<dim3(256, 3), 256, 0, stream>>>(wq, wk, wv, wb3);
        gn_apply_t<<<dim3(32, 8, 8), 256, 0, stream>>>(x, gamma, beta, meanb, rstdb, hnT);
        qkv_a<<<dim3(192, 1, 8), 256, 0, stream>>>(wb3, hnT, bq, bk, bv, qT, kT, vv);
        gemm256_s<<<dim3(512), 512, 0, stream>>>(qT, HC, kT, HC, Sb, HH,
                                                 512, 512, 512, 2048, scl);
        softmax_rows<<<16384, 256, 0, stream>>>(Sb);
        gemm256_pv<0><<<dim3(256), 512, 0, stream>>>(Sb, HH, vv, HC, hT, HC,
                                                     2048, 2048, 2048, 512, 1.f);
        w2bf<<<dim3(256, 1), 256, 0, stream>>>(wp, wp, wp, wpb);
        gemm_tn_a<2, 1><<<dim3(64, 1, 8), 256, 0, stream>>>(hT, HC, wpb, 0, bp, x, HC,
                                                            out, HC, 512, 512, 512, 2048, 1.f);
    } else if (ws_size >= MED_NEED) {
        u16* hnT = base;
        u16* qT  = hnT + 8 * HC;
        u16* kT  = qT + 8 * HC;
        u16* vv  = kT + 8 * HC;
        u16* Sb  = vv + 8 * HC;
        u16* hT  = hnT;
        gn_apply_t<<<dim3(32, 8, 8), 256, 0, stream>>>(x, gamma, beta, meanb, rstdb, hnT);
        gemm_tn<1, 1, 0><<<dim3(16, 4, 8), 256, 0, stream>>>(wq, 0, hnT, HC, bq, nullptr, 0,
                                                             qT, HC, 512, 512, 512, 512, 1.f);
        gemm_tn<1, 1, 0><<<dim3(16, 4, 8), 256, 0, stream>>>(wk, 0, hnT, HC, bk, nullptr, 0,
                                                             kT, HC, 512, 512, 512, 512, 1.f);
        gemm_tn<0, 1, 0><<<dim3(16, 4, 8), 256, 0, stream>>>(wv, 0, hnT, HC, bv, nullptr, 0,
                                                             vv, HC, 512, 512, 512, 2048, 1.f);
        for (int b = 0; b < 8; b++) {
            gemm_tn<0, 0, 0><<<dim3(16, 16, 1), 256, 0, stream>>>(qT + b * HC, 0, kT + b * HC, 0,
                                                                  nullptr, nullptr, 0, Sb, 0,
                                                                  512, 512, 512, 2048, scl);
            softmax_rows<<<2048, 256, 0, stream>>>(Sb);
            gemm_tn<0, 0, 0><<<dim3(4, 16, 1), 256, 0, stream>>>(Sb, 0, vv + b * HC, 0,
                                                                 nullptr, nullptr, 0, hT + b * HC, 0,
                                                                 2048, 2048, 2048, 512, 1.f);
        }
        gemm_tn<2, 0, 1><<<dim3(4, 16, 8), 256, 0, stream>>>(hT, HC, wp, 0, bp, x, HC,
                                                             out, HC, 512, 512, 512, 2048, 1.f);
    } else {
        const int CH = (ws_size >= SMALL_NEED) ? 2048 : ((ws_size >= CHUNK512) ? 512 : 128);
        u16* hn = base;
        u16* q  = hn + HC;
        u16* k  = q + HC;
        u16* v  = k + HC;
        u16* Sc = v + HC;
        u16* hT = hn;
        for (int b = 0; b < 8; b++) {
            const float* xb = x + (long)b * HC;
            gn_apply_t<<<dim3(32, 8, 1), 256, 0, stream>>>(xb, gamma, beta,
                                                           meanb + b * 32, rstdb + b * 32, hn);
            gemm_tn<1, 1, 0><<<dim3(16, 4, 1), 256, 0, stream>>>(wq, 0, hn, 0, bq, nullptr, 0,
                                                                 q, 0, 512, 512, 512, 512, 1.f);
            gemm_tn<1, 1, 0><<<dim3(16, 4, 1), 256, 0, stream>>>(wk, 0, hn, 0, bk, nullptr, 0,
                                                                 k, 0, 512, 512, 512, 512, 1.f);
            gemm_tn<0, 1, 0><<<dim3(16, 4, 1), 256, 0, stream>>>(wv, 0, hn, 0, bv, nullptr, 0,
                                                                 v, 0, 512, 512, 512, 2048, 1.f);
            for (int i0 = 0; i0 < 2048; i0 += CH) {
                gemm_tn<0, 0, 0><<<dim3(16, CH / 128, 1), 256, 0, stream>>>(
                    q + (long)i0 * 512, 0, k, 0, nullptr, nullptr, 0, Sc, 0,
                    512, 512, 512, 2048, scl);
                softmax_rows<<<CH, 256, 0, stream>>>(Sc);
                gemm_tn<0, 0, 0><<<dim3(4, CH / 128, 1), 256, 0, stream>>>(
                    Sc, 0, v, 0, nullptr, nullptr, 0, hT + (long)i0 * 512, 0,
                    2048, 2048, 2048, 512, 1.f);
            }
            gemm_tn<2, 0, 1><<<dim3(4, 16, 1), 256, 0, stream>>>(hT, 0, wp, 0, bp, xb, 0,
                                                                 out + (long)b * HC, 0,
                                                                 512, 512, 512, 2048, 1.f);
        }
    }
}

// Round 8
// 274.657 us; speedup vs baseline: 1.1633x; 1.0365x over previous
//
#include <hip/hip_runtime.h>
#include <stdint.h>

typedef unsigned short u16;
typedef short s16x8 __attribute__((ext_vector_type(8)));
typedef float f32x4 __attribute__((ext_vector_type(4)));

#define BM 128
#define BN 128
#define BK 32
#define KPAD 40   // padded LDS row stride for the legacy (non-async) kernel

#define WAITV(n) asm volatile("s_waitcnt vmcnt(" #n ")" ::: "memory")
#define BARR()   asm volatile("s_barrier" ::: "memory")
#define SB0()    __builtin_amdgcn_sched_barrier(0)

__device__ __forceinline__ float bf2f(u16 b) {
    union { unsigned int u; float f; } v; v.u = ((unsigned int)b) << 16; return v.f;
}
__device__ __forceinline__ u16 f2bf(float f) {
    union { float f; unsigned int u; } v; v.f = f;
    unsigned int u = v.u;
    u += 0x7fffu + ((u >> 16) & 1u);   // RNE
    return (u16)(u >> 16);
}
__device__ __forceinline__ void async_cp16(const u16* g, u16* l) {
    // global -> LDS direct copy, 16 B per lane; LDS dest = wave-uniform base + lane*16
    __builtin_amdgcn_global_load_lds((const __attribute__((address_space(1))) void*)g,
                                     (__attribute__((address_space(3))) void*)l, 16, 0, 0);
}

// ---------------- GroupNorm statistics: one block per (b,g), fp32 input ----------------
__global__ __launch_bounds__(256) void gn_stats(const float* __restrict__ x,
                                                float* __restrict__ mean,
                                                float* __restrict__ rstd) {
    const int bg = blockIdx.x;
    const float* p = x + (long)bg * 16 * 2048;     // 32768 fp32 per group
    float s = 0.f, ss = 0.f;
    for (int it = 0; it < 32; it++) {
        const float4 v = *reinterpret_cast<const float4*>(p + ((it * 256 + threadIdx.x) << 2));
        s += v.x + v.y + v.z + v.w;
        ss += v.x * v.x + v.y * v.y + v.z * v.z + v.w * v.w;
    }
    const int lane = threadIdx.x & 63, wave = threadIdx.x >> 6;
#pragma unroll
    for (int o = 32; o > 0; o >>= 1) { s += __shfl_down(s, o, 64); ss += __shfl_down(ss, o, 64); }
    __shared__ float rb[8];
    if (lane == 0) { rb[wave] = s; rb[4 + wave] = ss; }
    __syncthreads();
    if (threadIdx.x == 0) {
        float S = rb[0] + rb[1] + rb[2] + rb[3];
        float SS = rb[4] + rb[5] + rb[6] + rb[7];
        float mu = S * (1.f / 32768.f);
        float var = SS * (1.f / 32768.f) - mu * mu;
        mean[bg] = mu;
        rstd[bg] = rsqrtf(var + 1e-6f);
    }
}

// ---------- GroupNorm apply + transpose: fp32 x -> bf16 hnT[h, c] ----------
__global__ __launch_bounds__(256) void gn_apply_t(const float* __restrict__ x,
                                                  const float* __restrict__ gamma,
                                                  const float* __restrict__ beta,
                                                  const float* __restrict__ mean,
                                                  const float* __restrict__ rstd,
                                                  u16* __restrict__ hnT) {
    const int b = blockIdx.z, c0 = blockIdx.y * 64, h0 = blockIdx.x * 64;
    __shared__ __align__(16) u16 T[64][72];
    const int tid = threadIdx.x;
#pragma unroll
    for (int sidx = 0; sidx < 4; sidx++) {
        int ch = tid + sidx * 256;                 // 1024 float4-chunks
        int cc = ch >> 4, h4 = (ch & 15) * 4;
        int c = c0 + cc;
        float mu = mean[b * 32 + (c >> 4)], rs = rstd[b * 32 + (c >> 4)];
        float ga = gamma[c], be = beta[c];
        const float4 v = *reinterpret_cast<const float4*>(x + ((long)b * 512 + c) * 2048 + h0 + h4);
        ushort4 pk;
        pk.x = f2bf((v.x - mu) * rs * ga + be);
        pk.y = f2bf((v.y - mu) * rs * ga + be);
        pk.z = f2bf((v.z - mu) * rs * ga + be);
        pk.w = f2bf((v.w - mu) * rs * ga + be);
        *reinterpret_cast<ushort4*>(&T[cc][h4]) = pk;
    }
    __syncthreads();
#pragma unroll
    for (int sidx = 0; sidx < 2; sidx++) {
        int ch = tid + sidx * 256;                 // 512 uint4-chunks
        int hh = ch >> 3, c8 = (ch & 7) * 8;
        unsigned int o[4];
#pragma unroll
        for (int i = 0; i < 4; i++) {
            u16 lo = T[c8 + 2 * i][hh];
            u16 hi = T[c8 + 2 * i + 1][hh];
            o[i] = (unsigned int)lo | ((unsigned int)hi << 16);
        }
        *reinterpret_cast<uint4*>(hnT + ((long)b * 2048 + h0 + hh) * 512 + c0 + c8) =
            uint4{o[0], o[1], o[2], o[3]};
    }
}

// ---------------- fp32 -> bf16 weight conversion (512x512 each, y selects src) ----------------
__global__ __launch_bounds__(256) void w2bf(const float* __restrict__ a,
                                            const float* __restrict__ b,
                                            const float* __restrict__ c,
                                            u16* __restrict__ dst) {
    const float* s = (blockIdx.y == 0) ? a : (blockIdx.y == 1) ? b : c;
    const int i = (blockIdx.x * 256 + threadIdx.x) * 4;
    const float4 v = *reinterpret_cast<const float4*>(s + i);
    ushort4 p;
    p.x = f2bf(v.x); p.y = f2bf(v.y); p.z = f2bf(v.z); p.w = f2bf(v.w);
    *reinterpret_cast<ushort4*>(dst + (long)blockIdx.y * 262144 + i) = p;
}

// ------------------ softmax over rows of S[i, :] (bf16) in place ------------------
__global__ __launch_bounds__(256) void softmax_rows(u16* __restrict__ S) {
    u16* p = S + (long)blockIdx.x * 2048;
    const int tid = threadIdx.x;
    uint4 v = *reinterpret_cast<const uint4*>(p + (tid << 3));
    unsigned int w[4] = {v.x, v.y, v.z, v.w};
    float f[8];
#pragma unroll
    for (int i = 0; i < 4; i++) {
        f[2 * i]     = bf2f((u16)(w[i] & 0xffffu));
        f[2 * i + 1] = bf2f((u16)(w[i] >> 16));
    }
    float m = f[0];
#pragma unroll
    for (int i = 1; i < 8; i++) m = fmaxf(m, f[i]);
    const int lane = tid & 63, wave = tid >> 6;
#pragma unroll
    for (int o = 32; o > 0; o >>= 1) m = fmaxf(m, __shfl_down(m, o, 64));
    __shared__ float rb[4];
    __shared__ float bc;
    if (lane == 0) rb[wave] = m;
    __syncthreads();
    if (tid == 0) bc = fmaxf(fmaxf(rb[0], rb[1]), fmaxf(rb[2], rb[3]));
    __syncthreads();
    m = bc;
    float s = 0.f;
#pragma unroll
    for (int i = 0; i < 8; i++) { f[i] = __expf(f[i] - m); s += f[i]; }
#pragma unroll
    for (int o = 32; o > 0; o >>= 1) s += __shfl_down(s, o, 64);
    __syncthreads();
    if (lane == 0) rb[wave] = s;
    __syncthreads();
    if (tid == 0) bc = 1.f / (rb[0] + rb[1] + rb[2] + rb[3]);
    __syncthreads();
    const float inv = bc;
#pragma unroll
    for (int i = 0; i < 4; i++)
        w[i] = (unsigned int)f2bf(f[2 * i] * inv) | ((unsigned int)f2bf(f[2 * i + 1] * inv) << 16);
    *reinterpret_cast<uint4*>(p + (tid << 3)) = uint4{w[0], w[1], w[2], w[3]};
}

// ===================== 256x256-tile 8-wave 4-phase GEMM (S-GEMM) =====================
// Structure as r5/r6 (harness-verified); r7 3-bit XOR swizzle (harness-verified).
__global__ __launch_bounds__(512, 1) void gemm256_s(const u16* __restrict__ Ag, long sA,
                                                    const u16* __restrict__ Bg, long sB,
                                                    u16* __restrict__ Og, long sO,
                                                    int K, int lda, int ldb, int ldo,
                                                    float scale) {
    const int bx = blockIdx.x;
    const int b = bx & 7, s = bx >> 3;
    const int ty = s & 7, tx = s >> 3;
    const int m0 = ty * 256, n0 = tx * 256;
    Ag += (long)b * sA;
    Bg += (long)b * sB;
    u16* O = Og + (long)b * sO;

    __shared__ __align__(16) u16 LA[2][2][128 * 64];   // [buf][region mh][row*64+k] 64 KiB
    __shared__ __align__(16) u16 LB[2][2][128 * 64];   // [buf][region nh]           64 KiB

    const int tid = threadIdx.x;
    const int lane = tid & 63, wave = tid >> 6;
    const int wm = wave >> 2, w4 = wave & 3;
    const int l15 = lane & 15, quad = lane >> 4;

    // 3-bit XOR swizzle read slots (u16 units): bits[5:3] = {ks,q1,q0} ^ (row&7)
    const int sw   = (l15 & 7) << 3;
    const int slt0 = ((quad << 3)) ^ sw;          // ks=0
    const int slt1 = (32 + (quad << 3)) ^ sw;     // ks=1 (32 u16 = 64 B)
    const int arow_u = (wm * 64 + l15) * 64;
    const int brow_u = (w4 * 32 + l15) * 64;

    // staging: lane covers LDS row (wave*8 + lane/8), phys slot lane&7; global col-block
    // pre-swizzled by the SAME involution: (lane&7) ^ (LDSrow&7), LDSrow&7 = (lane>>3)&7
    const int l8 = lane >> 3;
    const int lrow0 = wave * 8 + l8;                               // region row, issue 0 (0..63)
    const int sEl = (((lane & 7) ^ ((lane >> 3) & 7)) << 3);       // pre-swizzled col (u16)
    int pA[2], pB[2];
    pA[0] = (m0 + lrow0) * lda + sEl;
    pA[1] = (m0 + 64 + lrow0) * lda + sEl;
    {
        const int gb = (lrow0 >> 5) * 64 + (lrow0 & 31);
        pB[0] = (n0 + gb) * ldb + sEl;
        pB[1] = (n0 + gb + 32) * ldb + sEl;
    }
    const int jA = 128 * lda;
    const int jB = 128 * ldb;

    auto stageA = [&](int buf, int mh, int k0) {
        u16* d = &LA[buf][mh][wave * 512];
        async_cp16(Ag + pA[mh] + k0, d);
        async_cp16(Ag + pA[mh] + jA + k0, d + 4096);
    };
    auto stageB = [&](int buf, int nh, int k0) {
        u16* d = &LB[buf][nh][wave * 512];
        async_cp16(Bg + pB[nh] + k0, d);
        async_cp16(Bg + pB[nh] + jB + k0, d + 4096);
    };

    f32x4 acc[8][4];
#pragma unroll
    for (int i = 0; i < 8; i++)
#pragma unroll
        for (int j = 0; j < 4; j++) acc[i][j] = f32x4{0.f, 0.f, 0.f, 0.f};

    s16x8 fa[4][2], fblo[2][2], fbhi[2][2];

    const int NT = K >> 6;

    stageA(0, 0, 0);
    stageB(0, 0, 0);
    stageB(0, 1, 0);
    stageA(0, 1, 0);
    if (NT > 1) {
        stageA(1, 0, 64);
        stageB(1, 0, 64);
        stageB(1, 1, 64);
    }
    WAITV(8); SB0();
    BARR(); SB0();

    for (int t = 0; t < NT; t++) {
        const int buf = t & 1;
        const int k2 = (t + 2) << 6;
        // phase 1: (mh=0, nh=0)
        {
            const u16* Ar = &LA[buf][0][0];
            const u16* Br = &LB[buf][0][0];
#pragma unroll
            for (int mf = 0; mf < 4; mf++)
#pragma unroll
                for (int ks = 0; ks < 2; ks++)
                    fa[mf][ks] = *reinterpret_cast<const s16x8*>(Ar + arow_u + mf * 1024 + (ks ? slt1 : slt0));
#pragma unroll
            for (int nf = 0; nf < 2; nf++)
#pragma unroll
                for (int ks = 0; ks < 2; ks++)
                    fblo[nf][ks] = *reinterpret_cast<const s16x8*>(Br + brow_u + nf * 1024 + (ks ? slt1 : slt0));
            if (t + 1 < NT) stageA(buf ^ 1, 1, (t + 1) << 6);
            if (t == NT - 1) { WAITV(2); } else { WAITV(8); }
            SB0();
            BARR(); SB0();
            __builtin_amdgcn_s_setprio(1);
#pragma unroll
            for (int mf = 0; mf < 4; mf++)
#pragma unroll
                for (int nf = 0; nf < 2; nf++)
#pragma unroll
                    for (int ks = 0; ks < 2; ks++)
                        acc[mf][nf] = __builtin_amdgcn_mfma_f32_16x16x32_bf16(fa[mf][ks], fblo[nf][ks], acc[mf][nf], 0, 0, 0);
            __builtin_amdgcn_s_setprio(0);
            BARR(); SB0();
        }
        // phase 2: (mh=0, nh=1)
        {
            const u16* Br = &LB[buf][1][0];
#pragma unroll
            for (int nf = 0; nf < 2; nf++)
#pragma unroll
                for (int ks = 0; ks < 2; ks++)
                    fbhi[nf][ks] = *reinterpret_cast<const s16x8*>(Br + brow_u + nf * 1024 + (ks ? slt1 : slt0));
            if (t + 2 < NT) stageA(buf, 0, k2);
            if (t == NT - 1) { WAITV(0); } else { WAITV(8); }
            SB0();
            BARR(); SB0();
            __builtin_amdgcn_s_setprio(1);
#pragma unroll
            for (int mf = 0; mf < 4; mf++)
#pragma unroll
                for (int nf = 0; nf < 2; nf++)
#pragma unroll
                    for (int ks = 0; ks < 2; ks++)
                        acc[mf][2 + nf] = __builtin_amdgcn_mfma_f32_16x16x32_bf16(fa[mf][ks], fbhi[nf][ks], acc[mf][2 + nf], 0, 0, 0);
            __builtin_amdgcn_s_setprio(0);
            BARR(); SB0();
        }
        // phase 3: (mh=1, nh=1)
        {
            const u16* Ar = &LA[buf][1][0];
#pragma unroll
            for (int mf = 0; mf < 4; mf++)
#pragma unroll
                for (int ks = 0; ks < 2; ks++)
                    fa[mf][ks] = *reinterpret_cast<const s16x8*>(Ar + arow_u + mf * 1024 + (ks ? slt1 : slt0));
            if (t + 2 < NT) stageB(buf, 0, k2);
            WAITV(8); SB0();
            BARR(); SB0();
            __builtin_amdgcn_s_setprio(1);
#pragma unroll
            for (int mf = 0; mf < 4; mf++)
#pragma unroll
                for (int nf = 0; nf < 2; nf++)
#pragma unroll
                    for (int ks = 0; ks < 2; ks++)
                        acc[4 + mf][2 + nf] = __builtin_amdgcn_mfma_f32_16x16x32_bf16(fa[mf][ks], fbhi[nf][ks], acc[4 + mf][2 + nf], 0, 0, 0);
            __builtin_amdgcn_s_setprio(0);
            BARR(); SB0();
        }
        // phase 4: (mh=1, nh=0)
        {
            if (t + 2 < NT) stageB(buf, 1, k2);
            if (t == NT - 2) { WAITV(4); } else { WAITV(8); }
            SB0();
            BARR(); SB0();
            __builtin_amdgcn_s_setprio(1);
#pragma unroll
            for (int mf = 0; mf < 4; mf++)
#pragma unroll
                for (int nf = 0; nf < 2; nf++)
#pragma unroll
                    for (int ks = 0; ks < 2; ks++)
                        acc[4 + mf][nf] = __builtin_amdgcn_mfma_f32_16x16x32_bf16(fa[mf][ks], fblo[nf][ks], acc[4 + mf][nf], 0, 0, 0);
            __builtin_amdgcn_s_setprio(0);
            BARR(); SB0();
        }
    }

    const int orow = m0 + wm * 128 + quad * 4;
    const int ocol = n0 + w4 * 64 + l15;
#pragma unroll
    for (int mi = 0; mi < 8; mi++)
#pragma unroll
        for (int ni = 0; ni < 4; ni++) {
            const long rb = (long)(orow + mi * 16) * ldo + ocol + ni * 16;
#pragma unroll
            for (int r = 0; r < 4; r++)
                O[rb + (long)r * ldo] = f2bf(acc[mi][ni][r] * scale);
        }
}

// ===================== 256x128-tile 8-wave 4-phase GEMM (PV) =====================
// Structure as r6 (harness-verified); r7 3-bit XOR swizzle (harness-verified).
template <int EPI>
__global__ __launch_bounds__(512, 1) void gemm256_pv(const u16* __restrict__ Ag, long sA,
                                                     const u16* __restrict__ Bg, long sB,
                                                     u16* __restrict__ Og, long sO,
                                                     int K, int lda, int ldb, int ldo,
                                                     float scale) {
    const int bx = blockIdx.x;
    const int b = bx & 7, s = bx >> 3;      // s in [0,32)
    const int mt = s >> 2, nt = s & 3;
    const int m0 = mt * 256, n0 = nt * 128;
    Ag += (long)b * sA;
    Bg += (long)b * sB;
    u16* O = Og + (long)b * sO;

    __shared__ __align__(16) u16 LA[2][2][128 * 64];   // 64 KiB
    __shared__ __align__(16) u16 LB[2][2][64 * 64];    // 32 KiB

    const int tid = threadIdx.x;
    const int lane = tid & 63, wave = tid >> 6;
    const int wm = wave >> 1, wn = wave & 1;           // 4(M) x 2(N)
    const int l15 = lane & 15, quad = lane >> 4;

    // 3-bit XOR swizzle read slots (u16 units)
    const int sw   = (l15 & 7) << 3;
    const int slt0 = ((quad << 3)) ^ sw;
    const int slt1 = (32 + (quad << 3)) ^ sw;

    // staging: thread covers region row r0 = tid>>3; phys slot lane&7;
    // global col-block pre-swizzled by (lane&7) ^ ((lane>>3)&7) (= slot ^ LDSrow&7)
    const int r0 = tid >> 3;
    const int sEl = (((lane & 7) ^ ((lane >> 3) & 7)) << 3);
    const int gA = (r0 >> 5) * 64 + (r0 & 31);         // A region row -> global local-M
    int pA[2], pB[2];
    pA[0] = (m0 + gA) * lda + sEl;                     // A-lo
    pA[1] = (m0 + gA + 32) * lda + sEl;                // A-hi
    pB[0] = (n0 + gA) * ldb + sEl;                     // B-lo (same row pattern)
    pB[1] = (n0 + gA + 32) * ldb + sEl;                // B-hi
    const int jA = 128 * lda;                          // A issue-1 delta (+128 global rows)

    auto stageA = [&](int buf, int mh, int k0) {       // 2 instr (16 KB region)
        u16* d = &LA[buf][mh][wave * 512];
        async_cp16(Ag + pA[mh] + k0, d);
        async_cp16(Ag + pA[mh] + jA + k0, d + 4096);
    };
    auto stageBB = [&](int buf, int k0) {              // 2 instr (both 8 KB B regions)
        async_cp16(Bg + pB[0] + k0, &LB[buf][0][wave * 512]);
        async_cp16(Bg + pB[1] + k0, &LB[buf][1][wave * 512]);
    };

    f32x4 acc[4][4];
#pragma unroll
    for (int i = 0; i < 4; i++)
#pragma unroll
        for (int j = 0; j < 4; j++) acc[i][j] = f32x4{0.f, 0.f, 0.f, 0.f};

    s16x8 fa[2][2], fblo[2][2], fbhi[2][2];

    const int arow_u = (wm * 32 + l15) * 64;           // + mf*16*64
    const int brow_u = (wn * 32 + l15) * 64;           // + nf*16*64

    const int NT = K >> 6;                             // 32 for PV

    // prologue: B(0), A-lo(0), A-hi(0), B(1); retire through A-lo(0) -> WAITV(4)
    stageBB(0, 0);
    stageA(0, 0, 0);
    stageA(0, 1, 0);
    if (NT > 1) stageBB(1, 64);
    WAITV(4); SB0();
    BARR(); SB0();

    for (int t = 0; t < NT; t++) {
        const int buf = t & 1;
        const int k1 = (t + 1) << 6, k2 = (t + 2) << 6;
        // ---- phase 1: (mh=0, nh=0) — reads A-lo(t), B-lo(t)
        {
            const u16* Ar = &LA[buf][0][0];
            const u16* Br = &LB[buf][0][0];
#pragma unroll
            for (int mf = 0; mf < 2; mf++)
#pragma unroll
                for (int ks = 0; ks < 2; ks++)
                    fa[mf][ks] = *reinterpret_cast<const s16x8*>(Ar + arow_u + mf * 1024 + (ks ? slt1 : slt0));
#pragma unroll
            for (int nf = 0; nf < 2; nf++)
#pragma unroll
                for (int ks = 0; ks < 2; ks++)
                    fblo[nf][ks] = *reinterpret_cast<const s16x8*>(Br + brow_u + nf * 1024 + (ks ? slt1 : slt0));
            if (t + 1 < NT) stageA(buf ^ 1, 0, k1);    // A-lo(t+1)
            __builtin_amdgcn_s_setprio(1);
#pragma unroll
            for (int mf = 0; mf < 2; mf++)
#pragma unroll
                for (int nf = 0; nf < 2; nf++)
#pragma unroll
                    for (int ks = 0; ks < 2; ks++)
                        acc[mf][nf] = __builtin_amdgcn_mfma_f32_16x16x32_bf16(fa[mf][ks], fblo[nf][ks], acc[mf][nf], 0, 0, 0);
            __builtin_amdgcn_s_setprio(0);
            if (t == NT - 1) { WAITV(0); } else { WAITV(4); }   // retire A-hi(t) for p3
            SB0();
            BARR(); SB0();
        }
        // ---- phase 2: (mh=0, nh=1) — reads B-hi(t)
        {
            const u16* Br = &LB[buf][1][0];
#pragma unroll
            for (int nf = 0; nf < 2; nf++)
#pragma unroll
                for (int ks = 0; ks < 2; ks++)
                    fbhi[nf][ks] = *reinterpret_cast<const s16x8*>(Br + brow_u + nf * 1024 + (ks ? slt1 : slt0));
            if (t + 1 < NT) stageA(buf ^ 1, 1, k1);    // A-hi(t+1)
            __builtin_amdgcn_s_setprio(1);
#pragma unroll
            for (int mf = 0; mf < 2; mf++)
#pragma unroll
                for (int nf = 0; nf < 2; nf++)
#pragma unroll
                    for (int ks = 0; ks < 2; ks++)
                        acc[mf][2 + nf] = __builtin_amdgcn_mfma_f32_16x16x32_bf16(fa[mf][ks], fbhi[nf][ks], acc[mf][2 + nf], 0, 0, 0);
            __builtin_amdgcn_s_setprio(0);
            BARR(); SB0();
        }
        // ---- phase 3: (mh=1, nh=1) — reads A-hi(t) (retired by p1's WAITV)
        {
            const u16* Ar = &LA[buf][1][0];
#pragma unroll
            for (int mf = 0; mf < 2; mf++)
#pragma unroll
                for (int ks = 0; ks < 2; ks++)
                    fa[mf][ks] = *reinterpret_cast<const s16x8*>(Ar + arow_u + mf * 1024 + (ks ? slt1 : slt0));
            if (t + 2 < NT) stageBB(buf, k2);          // B(t+2) (WAR: B(t) last read p2, barrier between)
            __builtin_amdgcn_s_setprio(1);
#pragma unroll
            for (int mf = 0; mf < 2; mf++)
#pragma unroll
                for (int nf = 0; nf < 2; nf++)
#pragma unroll
                    for (int ks = 0; ks < 2; ks++)
                        acc[2 + mf][2 + nf] = __builtin_amdgcn_mfma_f32_16x16x32_bf16(fa[mf][ks], fbhi[nf][ks], acc[2 + mf][2 + nf], 0, 0, 0);
            __builtin_amdgcn_s_setprio(0);
            BARR(); SB0();
        }
        // ---- phase 4: (mh=1, nh=0) — regs only; WAITV retires B(t+1)+A-lo(t+1) for next p1
        {
            __builtin_amdgcn_s_setprio(1);
#pragma unroll
            for (int mf = 0; mf < 2; mf++)
#pragma unroll
                for (int nf = 0; nf < 2; nf++)
#pragma unroll
                    for (int ks = 0; ks < 2; ks++)
                        acc[2 + mf][nf] = __builtin_amdgcn_mfma_f32_16x16x32_bf16(fa[mf][ks], fblo[nf][ks], acc[2 + mf][nf], 0, 0, 0);
            __builtin_amdgcn_s_setprio(0);
            if (t == NT - 2) { WAITV(2); } else if (t < NT - 2) { WAITV(4); }
            SB0();
            BARR(); SB0();
        }
    }

    // epilogue: row = m0 + wm*64 + mi*16 + quad*4 + r; col = n0 + wn*64 + ni*16 + l15
    const int orow = m0 + wm * 64 + quad * 4;
    const int ocol = n0 + wn * 64 + l15;
#pragma unroll
    for (int mi = 0; mi < 4; mi++)
#pragma unroll
        for (int ni = 0; ni < 4; ni++) {
            const long rb = (long)(orow + mi * 16) * ldo + ocol + ni * 16;
#pragma unroll
            for (int r = 0; r < 4; r++)
                O[rb + (long)r * ldo] = f2bf(acc[mi][ni][r] * scale);
        }
}

// ===================== merged QKV on the 256x128 4-phase template =====================
// C[m,n] = sum_k A[m,k] B[n,k]; A = wb3 [1536][512] (NO batch stride), B = hnT[b] [2048][512].
// Tile 256(M) x 128(N); grid 768 = 8 batches x (6 mt x 16 nt) = exactly 3 full dispatch
// rounds at 1 block/CU (96 KiB LDS). b = bx&7 (batch per XCD -> hnT[b] 2MB L2-resident);
// 16 consecutive blocks share one A-strip (weights 256KB). s = bx>>3: nt = s&15, mt = s>>4.
// which = mt>>1 is BLOCK-UNIFORM (256-tile never straddles a 512-row weight boundary).
// Same sync/ledger/swizzle as gemm256_pv (harness-verified); K=512 -> NT=8 (tail conds valid).
// Epilogue: which<2 -> qT/kT transposed bf16 [n][512] ushort4; which==2 -> vv [m][2048] scalar.
__global__ __launch_bounds__(512, 1) void qkv256(const u16* __restrict__ wb3,
                                                 const u16* __restrict__ hnT,
                                                 const float* __restrict__ bq,
                                                 const float* __restrict__ bk,
                                                 const float* __restrict__ bv,
                                                 u16* __restrict__ qT, u16* __restrict__ kT,
                                                 u16* __restrict__ vv) {
    const long HC = 1048576;
    const int bx = blockIdx.x;
    const int b = bx & 7, s = bx >> 3;      // s in [0,96)
    const int nt = s & 15, mt = s >> 4;     // nt [0,16), mt [0,6)
    const int m0 = mt * 256, n0 = nt * 128;
    const u16* Ag = wb3;
    const u16* Bg = hnT + (long)b * HC;
    const int which = mt >> 1;              // 0=q 1=k 2=v (block-uniform)
    const float* bias = (which == 0) ? bq : (which == 1) ? bk : bv;
    const int mbase = m0 & 511;             // local row base within the 512-row weight block
    const int lda = 512, ldb = 512;

    __shared__ __align__(16) u16 LA[2][2][128 * 64];   // 64 KiB
    __shared__ __align__(16) u16 LB[2][2][64 * 64];    // 32 KiB

    const int tid = threadIdx.x;
    const int lane = tid & 63, wave = tid >> 6;
    const int wm = wave >> 1, wn = wave & 1;           // 4(M) x 2(N)
    const int l15 = lane & 15, quad = lane >> 4;

    const int sw   = (l15 & 7) << 3;
    const int slt0 = ((quad << 3)) ^ sw;
    const int slt1 = (32 + (quad << 3)) ^ sw;

    const int r0 = tid >> 3;
    const int sEl = (((lane & 7) ^ ((lane >> 3) & 7)) << 3);
    const int gA = (r0 >> 5) * 64 + (r0 & 31);
    int pA[2], pB[2];
    pA[0] = (m0 + gA) * lda + sEl;
    pA[1] = (m0 + gA + 32) * lda + sEl;
    pB[0] = (n0 + gA) * ldb + sEl;
    pB[1] = (n0 + gA + 32) * ldb + sEl;
    const int jA = 128 * lda;

    auto stageA = [&](int buf, int mh, int k0) {
        u16* d = &LA[buf][mh][wave * 512];
        async_cp16(Ag + pA[mh] + k0, d);
        async_cp16(Ag + pA[mh] + jA + k0, d + 4096);
    };
    auto stageBB = [&](int buf, int k0) {
        async_cp16(Bg + pB[0] + k0, &LB[buf][0][wave * 512]);
        async_cp16(Bg + pB[1] + k0, &LB[buf][1][wave * 512]);
    };

    f32x4 acc[4][4];
#pragma unroll
    for (int i = 0; i < 4; i++)
#pragma unroll
        for (int j = 0; j < 4; j++) acc[i][j] = f32x4{0.f, 0.f, 0.f, 0.f};

    s16x8 fa[2][2], fblo[2][2], fbhi[2][2];

    const int arow_u = (wm * 32 + l15) * 64;
    const int brow_u = (wn * 32 + l15) * 64;

    const int NT = 8;                                  // K=512

    stageBB(0, 0);
    stageA(0, 0, 0);
    stageA(0, 1, 0);
    stageBB(1, 64);
    WAITV(4); SB0();
    BARR(); SB0();

    for (int t = 0; t < NT; t++) {
        const int buf = t & 1;
        const int k1 = (t + 1) << 6, k2 = (t + 2) << 6;
        // ---- phase 1: (mh=0, nh=0)
        {
            const u16* Ar = &LA[buf][0][0];
            const u16* Br = &LB[buf][0][0];
#pragma unroll
            for (int mf = 0; mf < 2; mf++)
#pragma unroll
                for (int ks = 0; ks < 2; ks++)
                    fa[mf][ks] = *reinterpret_cast<const s16x8*>(Ar + arow_u + mf * 1024 + (ks ? slt1 : slt0));
#pragma unroll
            for (int nf = 0; nf < 2; nf++)
#pragma unroll
                for (int ks = 0; ks < 2; ks++)
                    fblo[nf][ks] = *reinterpret_cast<const s16x8*>(Br + brow_u + nf * 1024 + (ks ? slt1 : slt0));
            if (t + 1 < NT) stageA(buf ^ 1, 0, k1);
            __builtin_amdgcn_s_setprio(1);
#pragma unroll
            for (int mf = 0; mf < 2; mf++)
#pragma unroll
                for (int nf = 0; nf < 2; nf++)
#pragma unroll
                    for (int ks = 0; ks < 2; ks++)
                        acc[mf][nf] = __builtin_amdgcn_mfma_f32_16x16x32_bf16(fa[mf][ks], fblo[nf][ks], acc[mf][nf], 0, 0, 0);
            __builtin_amdgcn_s_setprio(0);
            if (t == NT - 1) { WAITV(0); } else { WAITV(4); }
            SB0();
            BARR(); SB0();
        }
        // ---- phase 2: (mh=0, nh=1)
        {
            const u16* Br = &LB[buf][1][0];
#pragma unroll
            for (int nf = 0; nf < 2; nf++)
#pragma unroll
                for (int ks = 0; ks < 2; ks++)
                    fbhi[nf][ks] = *reinterpret_cast<const s16x8*>(Br + brow_u + nf * 1024 + (ks ? slt1 : slt0));
            if (t + 1 < NT) stageA(buf ^ 1, 1, k1);
            __builtin_amdgcn_s_setprio(1);
#pragma unroll
            for (int mf = 0; mf < 2; mf++)
#pragma unroll
                for (int nf = 0; nf < 2; nf++)
#pragma unroll
                    for (int ks = 0; ks < 2; ks++)
                        acc[mf][2 + nf] = __builtin_amdgcn_mfma_f32_16x16x32_bf16(fa[mf][ks], fbhi[nf][ks], acc[mf][2 + nf], 0, 0, 0);
            __builtin_amdgcn_s_setprio(0);
            BARR(); SB0();
        }
        // ---- phase 3: (mh=1, nh=1)
        {
            const u16* Ar = &LA[buf][1][0];
#pragma unroll
            for (int mf = 0; mf < 2; mf++)
#pragma unroll
                for (int ks = 0; ks < 2; ks++)
                    fa[mf][ks] = *reinterpret_cast<const s16x8*>(Ar + arow_u + mf * 1024 + (ks ? slt1 : slt0));
            if (t + 2 < NT) stageBB(buf, k2);
            __builtin_amdgcn_s_setprio(1);
#pragma unroll
            for (int mf = 0; mf < 2; mf++)
#pragma unroll
                for (int nf = 0; nf < 2; nf++)
#pragma unroll
                    for (int ks = 0; ks < 2; ks++)
                        acc[2 + mf][2 + nf] = __builtin_amdgcn_mfma_f32_16x16x32_bf16(fa[mf][ks], fbhi[nf][ks], acc[2 + mf][2 + nf], 0, 0, 0);
            __builtin_amdgcn_s_setprio(0);
            BARR(); SB0();
        }
        // ---- phase 4: (mh=1, nh=0)
        {
            __builtin_amdgcn_s_setprio(1);
#pragma unroll
            for (int mf = 0; mf < 2; mf++)
#pragma unroll
                for (int nf = 0; nf < 2; nf++)
#pragma unroll
                    for (int ks = 0; ks < 2; ks++)
                        acc[2 + mf][nf] = __builtin_amdgcn_mfma_f32_16x16x32_bf16(fa[mf][ks], fblo[nf][ks], acc[2 + mf][nf], 0, 0, 0);
            __builtin_amdgcn_s_setprio(0);
            if (t == NT - 2) { WAITV(2); } else if (t < NT - 2) { WAITV(4); }
            SB0();
            BARR(); SB0();
        }
    }

    // epilogue: local row = mbase + wm*64 + mi*16 + quad*4 + r in [0,512); col in [0,2048)
    const int orow = mbase + wm * 64 + quad * 4;
    const int ocol = n0 + wn * 64 + l15;
    if (which < 2) {
        u16* O = (which ? kT : qT) + (long)b * HC;
#pragma unroll
        for (int mi = 0; mi < 4; mi++) {
            const int rowb = orow + mi * 16;
#pragma unroll
            for (int ni = 0; ni < 4; ni++) {
                const int n = ocol + ni * 16;
                ushort4 pk;
                pk.x = f2bf(acc[mi][ni][0] + bias[rowb + 0]);
                pk.y = f2bf(acc[mi][ni][1] + bias[rowb + 1]);
                pk.z = f2bf(acc[mi][ni][2] + bias[rowb + 2]);
                pk.w = f2bf(acc[mi][ni][3] + bias[rowb + 3]);
                *reinterpret_cast<ushort4*>(&O[(long)n * 512 + rowb]) = pk;
            }
        }
    } else {
        u16* O = vv + (long)b * HC;
#pragma unroll
        for (int mi = 0; mi < 4; mi++) {
            const int rowb = orow + mi * 16;
#pragma unroll
            for (int ni = 0; ni < 4; ni++) {
                const int n = ocol + ni * 16;
#pragma unroll
                for (int r = 0; r < 4; r++)
                    O[(long)(rowb + r) * 2048 + n] = f2bf(acc[mi][ni][r] + bias[rowb + r]);
            }
        }
    }
}

// ===================== ASYNC 3-deep counted-vmcnt MFMA GEMM (bf16 operands) =====================
template <int EPI, int SWIZ>
__global__ __launch_bounds__(256) void gemm_tn_a(const u16* __restrict__ Ag, long sA,
                                                 const u16* __restrict__ Bg, long sB,
                                                 const float* __restrict__ bias,
                                                 const float* __restrict__ Xg, long sX,
                                                 void* __restrict__ Ogv, long sO,
                                                 int K, int lda, int ldb, int ldo,
                                                 float scale) {
    const int b = blockIdx.z;
    Ag += (long)b * sA;
    Bg += (long)b * sB;
    int tx, ty;
    if (SWIZ == 1) {
        const int xcd = blockIdx.x & 7, s = blockIdx.x >> 3;
        ty = xcd + 8 * (s >> 2);
        tx = s & 3;
    } else if (SWIZ == 2) {
        const int xcd = blockIdx.x & 7, s = blockIdx.x >> 3;
        ty = (xcd & 3) * 4 + (s & 3);
        tx = (xcd >> 2) * 8 + (s >> 2);
    } else {
        tx = blockIdx.x; ty = blockIdx.y;
    }
    const int m0 = ty * BM;
    const int n0 = tx * BN;

    __shared__ __align__(16) u16 As[3][BM * BK];
    __shared__ __align__(16) u16 Bs[3][BN * BK];

    const int tid = threadIdx.x;
    const int wave = tid >> 6;
    const int lane = tid & 63;
    const int quad = lane >> 4;
    const int l16 = lane & 15;
    const int wm = (wave >> 1) * 64;
    const int wn = (wave & 1) * 64;
    const int rl = lane >> 2;
    const int cl = (lane & 3) * 8;

    f32x4 acc[4][4];
#pragma unroll
    for (int i = 0; i < 4; i++)
#pragma unroll
        for (int j = 0; j < 4; j++) acc[i][j] = f32x4{0.f, 0.f, 0.f, 0.f};

    auto stage = [&](int buf, int k0) {
#pragma unroll
        for (int j = 0; j < 2; j++) {
            const int rbase = wave * 32 + j * 16;
            async_cp16(Ag + (long)(m0 + rbase + rl) * lda + k0 + cl, &As[buf][rbase * BK]);
            async_cp16(Bg + (long)(n0 + rbase + rl) * ldb + k0 + cl, &Bs[buf][rbase * BK]);
        }
    };
    auto compute = [&](int buf) {
        s16x8 af[4], bfr[4];
#pragma unroll
        for (int i = 0; i < 4; i++)
            af[i] = *reinterpret_cast<const s16x8*>(&As[buf][(wm + i * 16 + l16) * BK + quad * 8]);
#pragma unroll
        for (int j = 0; j < 4; j++)
            bfr[j] = *reinterpret_cast<const s16x8*>(&Bs[buf][(wn + j * 16 + l16) * BK + quad * 8]);
#pragma unroll
        for (int i = 0; i < 4; i++)
#pragma unroll
            for (int j = 0; j < 4; j++)
                acc[i][j] = __builtin_amdgcn_mfma_f32_16x16x32_bf16(af[i], bfr[j], acc[i][j], 0, 0, 0);
    };

    const int nsteps = K / BK;
    stage(0, 0);
    stage(1, BK);
    int t = 0;
    for (; t < nsteps - 1; t++) {
        asm volatile("s_waitcnt vmcnt(4)" ::: "memory");
        asm volatile("s_barrier" ::: "memory");
        if (t + 2 < nsteps) stage((t + 2) % 3, (t + 2) * BK);
        compute(t % 3);
    }
    asm volatile("s_waitcnt vmcnt(0)" ::: "memory");
    asm volatile("s_barrier" ::: "memory");
    compute(t % 3);

#pragma unroll
    for (int i = 0; i < 4; i++) {
        const int mb = m0 + wm + i * 16 + quad * 4;
#pragma unroll
        for (int j = 0; j < 4; j++) {
            const int n = n0 + wn + j * 16 + l16;
            if (EPI == 0) {
                u16* O = (u16*)Ogv + (long)b * sO;
#pragma unroll
                for (int r = 0; r < 4; r++) {
                    float vv = acc[i][j][r] * scale;
                    if (bias) vv += bias[mb + r];
                    O[(long)(mb + r) * ldo + n] = f2bf(vv);
                }
            } else if (EPI == 1) {
                u16* O = (u16*)Ogv + (long)b * sO;
                ushort4 pk;
                pk.x = f2bf(acc[i][j][0] + bias[mb + 0]);
                pk.y = f2bf(acc[i][j][1] + bias[mb + 1]);
                pk.z = f2bf(acc[i][j][2] + bias[mb + 2]);
                pk.w = f2bf(acc[i][j][3] + bias[mb + 3]);
                *reinterpret_cast<ushort4*>(&O[(long)n * ldo + mb]) = pk;
            } else {
                float* O = (float*)Ogv + (long)b * sO;
                const float* X = Xg + (long)b * sX;
                const float bn = bias[n];
                const float4 xv = *reinterpret_cast<const float4*>(&X[(long)n * ldo + mb]);
                float4 pk;
                pk.x = acc[i][j][0] + bn + xv.x;
                pk.y = acc[i][j][1] + bn + xv.y;
                pk.z = acc[i][j][2] + bn + xv.z;
                pk.w = acc[i][j][3] + bn + xv.w;
                *reinterpret_cast<float4*>(&O[(long)n * ldo + mb]) = pk;
            }
        }
    }
}

// ===================== legacy padded GEMM (fallback tiers, fp32-capable) =====================
template <int F32>
__device__ __forceinline__ void stage_tile(const char* G, int ld, int r0, int k0,
                                           u16* __restrict__ lds, int tid) {
    if (F32) {
        const float* g = (const float*)G;
#pragma unroll
        for (int s = 0; s < 4; s++) {
            const int c = tid + s * 256;
            const int row = c >> 3, col = (c & 7) * 4;
            const float4 v = *reinterpret_cast<const float4*>(g + (long)(r0 + row) * ld + k0 + col);
            ushort4 pk;
            pk.x = f2bf(v.x); pk.y = f2bf(v.y); pk.z = f2bf(v.z); pk.w = f2bf(v.w);
            *reinterpret_cast<ushort4*>(&lds[row * KPAD + col]) = pk;
        }
    } else {
        const u16* g = (const u16*)G;
#pragma unroll
        for (int s = 0; s < 2; s++) {
            const int c = tid + s * 256;
            const int row = c >> 2, col = (c & 3) * 8;
            const uint4 v = *reinterpret_cast<const uint4*>(g + (long)(r0 + row) * ld + k0 + col);
            *reinterpret_cast<uint4*>(&lds[row * KPAD + col]) = v;
        }
    }
}

template <int EPI, int AF32, int BF32>
__global__ __launch_bounds__(256) void gemm_tn(const void* __restrict__ Agv, long sA,
                                               const void* __restrict__ Bgv, long sB,
                                               const float* __restrict__ bias,
                                               const float* __restrict__ Xg, long sX,
                                               void* __restrict__ Ogv, long sO,
                                               int K, int lda, int ldb, int ldo,
                                               float scale) {
    const int b = blockIdx.z;
    const char* A8 = (const char*)Agv + (long)b * sA * (AF32 ? 4 : 2);
    const char* B8 = (const char*)Bgv + (long)b * sB * (BF32 ? 4 : 2);
    const int m0 = blockIdx.y * BM;
    const int n0 = blockIdx.x * BN;

    __shared__ __align__(16) u16 As[BM * KPAD];
    __shared__ __align__(16) u16 Bs[BN * KPAD];

    const int tid = threadIdx.x;
    const int wave = tid >> 6;
    const int lane = tid & 63;
    const int quad = lane >> 4;
    const int l16 = lane & 15;
    const int wm = (wave >> 1) * 64;
    const int wn = (wave & 1) * 64;

    f32x4 acc[4][4];
#pragma unroll
    for (int i = 0; i < 4; i++)
#pragma unroll
        for (int j = 0; j < 4; j++) acc[i][j] = f32x4{0.f, 0.f, 0.f, 0.f};

    for (int k0 = 0; k0 < K; k0 += BK) {
        __syncthreads();
        stage_tile<AF32>(A8, lda, m0, k0, As, tid);
        stage_tile<BF32>(B8, ldb, n0, k0, Bs, tid);
        __syncthreads();
        s16x8 af[4], bfr[4];
#pragma unroll
        for (int i = 0; i < 4; i++)
            af[i] = *reinterpret_cast<const s16x8*>(&As[(wm + i * 16 + l16) * KPAD + quad * 8]);
#pragma unroll
        for (int j = 0; j < 4; j++)
            bfr[j] = *reinterpret_cast<const s16x8*>(&Bs[(wn + j * 16 + l16) * KPAD + quad * 8]);
#pragma unroll
        for (int i = 0; i < 4; i++)
#pragma unroll
            for (int j = 0; j < 4; j++)
                acc[i][j] = __builtin_amdgcn_mfma_f32_16x16x32_bf16(af[i], bfr[j], acc[i][j], 0, 0, 0);
    }

#pragma unroll
    for (int i = 0; i < 4; i++) {
        const int mb = m0 + wm + i * 16 + quad * 4;
#pragma unroll
        for (int j = 0; j < 4; j++) {
            const int n = n0 + wn + j * 16 + l16;
            if (EPI == 0) {
                u16* O = (u16*)Ogv + (long)b * sO;
#pragma unroll
                for (int r = 0; r < 4; r++) {
                    float vv = acc[i][j][r] * scale;
                    if (bias) vv += bias[mb + r];
                    O[(long)(mb + r) * ldo + n] = f2bf(vv);
                }
            } else if (EPI == 1) {
                u16* O = (u16*)Ogv + (long)b * sO;
                ushort4 pk;
                pk.x = f2bf(acc[i][j][0] + bias[mb + 0]);
                pk.y = f2bf(acc[i][j][1] + bias[mb + 1]);
                pk.z = f2bf(acc[i][j][2] + bias[mb + 2]);
                pk.w = f2bf(acc[i][j][3] + bias[mb + 3]);
                *reinterpret_cast<ushort4*>(&O[(long)n * ldo + mb]) = pk;
            } else {
                float* O = (float*)Ogv + (long)b * sO;
                const float* X = Xg + (long)b * sX;
                const float bn = bias[n];
                const float4 xv = *reinterpret_cast<const float4*>(&X[(long)n * ldo + mb]);
                float4 pk;
                pk.x = acc[i][j][0] + bn + xv.x;
                pk.y = acc[i][j][1] + bn + xv.y;
                pk.z = acc[i][j][2] + bn + xv.z;
                pk.w = acc[i][j][3] + bn + xv.w;
                *reinterpret_cast<float4*>(&O[(long)n * ldo + mb]) = pk;
            }
        }
    }
}

extern "C" void kernel_launch(void* const* d_in, const int* in_sizes, int n_in,
                              void* d_out, int out_size, void* d_ws, size_t ws_size,
                              hipStream_t stream) {
    const float* x     = (const float*)d_in[0];
    const float* gamma = (const float*)d_in[1];
    const float* beta  = (const float*)d_in[2];
    const float* wq    = (const float*)d_in[3];
    const float* bq    = (const float*)d_in[4];
    const float* wk    = (const float*)d_in[5];
    const float* bk    = (const float*)d_in[6];
    const float* wv    = (const float*)d_in[7];
    const float* bv    = (const float*)d_in[8];
    const float* wp    = (const float*)d_in[9];
    const float* bp    = (const float*)d_in[10];
    float* out = (float*)d_out;

    const long HC = (long)2048 * 512;
    const long HH = (long)2048 * 2048;
    const long WSZ = 512 * 512;
    const float scl = 0.044194173824159216f;   // 1/sqrt(512)

    char* ws = (char*)d_ws;
    float* meanb = (float*)ws;
    float* rstdb = (float*)(ws + 1024);
    u16* base = (u16*)(ws + 4096);

    const size_t FULL_NEED   = 4096 + 2 * (size_t)(24 * HC + 8 * HH);     // 117,444,608
    const size_t MED_NEED    = 4096 + 2 * (size_t)(32 * HC + HH);         //  75,501,568
    const size_t SMALL_NEED  = 4096 + 2 * (size_t)(4 * HC + HH);          //  16,781,312
    const size_t CHUNK512    = 4096 + 2 * (size_t)(4 * HC + 512 * 2048);  //  10,489,856

    gn_stats<<<256, 256, 0, stream>>>(x, meanb, rstdb);

    if (ws_size >= FULL_NEED) {
        // ---- FULL: all-batched; QKV/S/PV all on the 4-phase templates ----
        u16* qT  = base;                       // [B,H,C]
        u16* kT  = qT + 8 * HC;                // [B,H,C]
        u16* vv  = kT + 8 * HC;                // [B,C,H]
        u16* Sb  = vv + 8 * HC;                // [B,H,H]
        u16* hnT = Sb;                         // overlay: dead before S written
        u16* wb3 = Sb + 8 * HH - 3 * WSZ;      // overlay: wq|wk|wv bf16, dead after QKV
        u16* hT  = qT;                         // overlay: qT dead after S-GEMM
        u16* wpb = vv;                         // overlay: vv dead after PV

        w2bf<<<dim3(256, 3), 256, 0, stream>>>(wq, wk, wv, wb3);
        gn_apply_t<<<dim3(32, 8, 8), 256, 0, stream>>>(x, gamma, beta, meanb, rstdb, hnT);
        qkv256<<<dim3(768), 512, 0, stream>>>(wb3, hnT, bq, bk, bv, qT, kT, vv);
        gemm256_s<<<dim3(512), 512, 0, stream>>>(qT, HC, kT, HC, Sb, HH,
                                                 512, 512, 512, 2048, scl);
        softmax_rows<<<16384, 256, 0, stream>>>(Sb);
        gemm256_pv<0><<<dim3(256), 512, 0, stream>>>(Sb, HH, vv, HC, hT, HC,
                                                     2048, 2048, 2048, 512, 1.f);
        w2bf<<<dim3(256, 1), 256, 0, stream>>>(wp, wp, wp, wpb);
        gemm_tn_a<2, 1><<<dim3(64, 1, 8), 256, 0, stream>>>(hT, HC, wpb, 0, bp, x, HC,
                                                            out, HC, 512, 512, 512, 2048, 1.f);
    } else if (ws_size >= MED_NEED) {
        u16* hnT = base;
        u16* qT  = hnT + 8 * HC;
        u16* kT  = qT + 8 * HC;
        u16* vv  = kT + 8 * HC;
        u16* Sb  = vv + 8 * HC;
        u16* hT  = hnT;
        gn_apply_t<<<dim3(32, 8, 8), 256, 0, stream>>>(x, gamma, beta, meanb, rstdb, hnT);
        gemm_tn<1, 1, 0><<<dim3(16, 4, 8), 256, 0, stream>>>(wq, 0, hnT, HC, bq, nullptr, 0,
                                                             qT, HC, 512, 512, 512, 512, 1.f);
        gemm_tn<1, 1, 0><<<dim3(16, 4, 8), 256, 0, stream>>>(wk, 0, hnT, HC, bk, nullptr, 0,
                                                             kT, HC, 512, 512, 512, 512, 1.f);
        gemm_tn<0, 1, 0><<<dim3(16, 4, 8), 256, 0, stream>>>(wv, 0, hnT, HC, bv, nullptr, 0,
                                                             vv, HC, 512, 512, 512, 2048, 1.f);
        for (int b = 0; b < 8; b++) {
            gemm_tn<0, 0, 0><<<dim3(16, 16, 1), 256, 0, stream>>>(qT + b * HC, 0, kT + b * HC, 0,
                                                                  nullptr, nullptr, 0, Sb, 0,
                                                                  512, 512, 512, 2048, scl);
            softmax_rows<<<2048, 256, 0, stream>>>(Sb);
            gemm_tn<0, 0, 0><<<dim3(4, 16, 1), 256, 0, stream>>>(Sb, 0, vv + b * HC, 0,
                                                                 nullptr, nullptr, 0, hT + b * HC, 0,
                                                                 2048, 2048, 2048, 512, 1.f);
        }
        gemm_tn<2, 0, 1><<<dim3(4, 16, 8), 256, 0, stream>>>(hT, HC, wp, 0, bp, x, HC,
                                                             out, HC, 512, 512, 512, 2048, 1.f);
    } else {
        const int CH = (ws_size >= SMALL_NEED) ? 2048 : ((ws_size >= CHUNK512) ? 512 : 128);
        u16* hn = base;
        u16* q  = hn + HC;
        u16* k  = q + HC;
        u16* v  = k + HC;
        u16* Sc = v + HC;
        u16* hT = hn;
        for (int b = 0; b < 8; b++) {
            const float* xb = x + (long)b * HC;
            gn_apply_t<<<dim3(32, 8, 1), 256, 0, stream>>>(xb, gamma, beta,
                                                           meanb + b * 32, rstdb + b * 32, hn);
            gemm_tn<1, 1, 0><<<dim3(16, 4, 1), 256, 0, stream>>>(wq, 0, hn, 0, bq, nullptr, 0,
                                                                 q, 0, 512, 512, 512, 512, 1.f);
            gemm_tn<1, 1, 0><<<dim3(16, 4, 1), 256, 0, stream>>>(wk, 0, hn, 0, bk, nullptr, 0,
                                                                 k, 0, 512, 512, 512, 512, 1.f);
            gemm_tn<0, 1, 0><<<dim3(16, 4, 1), 256, 0, stream>>>(wv, 0, hn, 0, bv, nullptr, 0,
                                                                 v, 0, 512, 512, 512, 2048, 1.f);
            for (int i0 = 0; i0 < 2048; i0 += CH) {
                gemm_tn<0, 0, 0><<<dim3(16, CH / 128, 1), 256, 0, stream>>>(
                    q + (long)i0 * 512, 0, k, 0, nullptr, nullptr, 0, Sc, 0,
                    512, 512, 512, 2048, scl);
                softmax_rows<<<CH, 256, 0, stream>>>(Sc);
                gemm_tn<0, 0, 0><<<dim3(4, CH / 128, 1), 256, 0, stream>>>(
                    Sc, 0, v, 0, nullptr, nullptr, 0, hT + (long)i0 * 512, 0,
                    2048, 2048, 2048, 512, 1.f);
            }
            gemm_tn<2, 0, 1><<<dim3(4, 16, 1), 256, 0, stream>>>(hT, 0, wp, 0, bp, xb, 0,
                                                                 out + (long)b * HC, 0,
                                                                 512, 512, 512, 2048, 1.f);
        }
    }
}